// Round 3
// baseline (388.448 us; speedup 1.0000x reference)
//
#include <hip/hip_runtime.h>
#include <cstdint>

// Problem constants (fixed by reference: B=4, S=2048)
#define TOK  8192   // B*S
#define DEMB 1024   // N_EMBD
#define HID  4096   // HIDDEN
#define ADP  256    // ADAPT
#define NEXP 8
#define KAUG 4352   // HID + ADP (K-augmented out-proj)

typedef __bf16 bf16x8 __attribute__((ext_vector_type(8)));
typedef float  f32x4  __attribute__((ext_vector_type(4)));

__device__ __forceinline__ unsigned short f2bf(float f) {
  // round-to-nearest-even fp32 -> bf16 (matches numpy/jax cast for normal values)
  unsigned int u = __float_as_uint(f);
  u += 0x7fffu + ((u >> 16) & 1u);
  return (unsigned short)(u >> 16);
}
__device__ __forceinline__ float bf2f(unsigned short b) {
  return __uint_as_float(((unsigned int)b) << 16);
}

// ---------------------------------------------------------------------------
// fp32 -> bf16 conversion for x and weights + routing + Wproj transpose, one
// kernel (block-range dispatch). Blocks:
//   [0,8960)    : 2048-elem conversion chunks (x, wup, wout->strided, wadapt, wexp)
//   [8960,8992) : routing (last active expert, -1 if none)
//   [8992,9248) : transpose-convert W_proj [4096,256] fp32 -> wpT [256,4096] bf16
// ---------------------------------------------------------------------------
__global__ __launch_bounds__(256) void convert_all(
    const float* __restrict__ x, const float* __restrict__ wup,
    const float* __restrict__ wout, const float* __restrict__ wadapt,
    const float* __restrict__ wexp, const float* __restrict__ ew,
    const float* __restrict__ wp,
    unsigned short* __restrict__ xb, unsigned short* __restrict__ wub,
    unsigned short* __restrict__ wob, unsigned short* __restrict__ wab,
    unsigned short* __restrict__ web, int* __restrict__ route,
    unsigned short* __restrict__ wpT) {
  __shared__ float tile[64][65];  // only used by transpose blocks
  int b = blockIdx.x;
  if (b >= 8992) {  // Wproj transpose: 64x64 LDS tiles, pad 65 (2-way = free)
    int wli = b - 8992;
    const int h0 = (wli & 63) * 64;  // over 4096
    const int a0 = (wli >> 6) * 64;  // over 256
    const int t = threadIdx.x;
    const int r = t >> 4;            // 0..15
    const int c = (t & 15) * 4;      // 0..60
#pragma unroll
    for (int p = 0; p < 4; ++p) {
      int row = p * 16 + r;
      float4 v = *(const float4*)(wp + (size_t)(h0 + row) * ADP + a0 + c);
      tile[c + 0][row] = v.x;
      tile[c + 1][row] = v.y;
      tile[c + 2][row] = v.z;
      tile[c + 3][row] = v.w;
    }
    __syncthreads();
#pragma unroll
    for (int q = 0; q < 2; ++q) {
      int idx = q * 256 + t;
      int al = idx >> 3;             // a local 0..63
      int hg = (idx & 7) * 8;        // h local 0,8,..,56
      unsigned int w0 = (unsigned int)f2bf(tile[al][hg + 0]) |
                        ((unsigned int)f2bf(tile[al][hg + 1]) << 16);
      unsigned int w1 = (unsigned int)f2bf(tile[al][hg + 2]) |
                        ((unsigned int)f2bf(tile[al][hg + 3]) << 16);
      unsigned int w2 = (unsigned int)f2bf(tile[al][hg + 4]) |
                        ((unsigned int)f2bf(tile[al][hg + 5]) << 16);
      unsigned int w3 = (unsigned int)f2bf(tile[al][hg + 6]) |
                        ((unsigned int)f2bf(tile[al][hg + 7]) << 16);
      *(uint4*)(wpT + (size_t)(a0 + al) * HID + h0 + hg) =
          make_uint4(w0, w1, w2, w3);
    }
    return;
  }
  if (b >= 8960) {  // routing
    int t = (b - 8960) * 256 + threadIdx.x;
    const float* p = ew + (size_t)t * NEXP;
    int r = -1;
#pragma unroll
    for (int e = 0; e < NEXP; ++e)
      if (p[e] > 0.f) r = e;
    route[t] = r;
    return;
  }
  const float* src; unsigned short* dst; int lb; bool strided = false;
  if      (b < 4096) { src = x;      dst = xb;  lb = b; }
  else if (b < 6144) { src = wup;    dst = wub; lb = b - 4096; }
  else if (b < 8192) { src = wout;   dst = wob; lb = b - 6144; strided = true; }
  else if (b < 8704) { src = wadapt; dst = wab; lb = b - 8192; }
  else               { src = wexp;   dst = web; lb = b - 8704; }
  size_t base = (size_t)lb * 2048;
#pragma unroll
  for (int h = 0; h < 2; ++h) {
    size_t off = base + (size_t)h * 1024 + (size_t)threadIdx.x * 4;
    float4 v = *(const float4*)(src + off);
    ushort4 o;
    o.x = f2bf(v.x); o.y = f2bf(v.y); o.z = f2bf(v.z); o.w = f2bf(v.w);
    size_t doff = strided ? (off >> 12) * KAUG + (off & 4095) : off;
    *(ushort4*)(dst + doff) = o;
  }
}

// XCD-aware remap: raw round-robin puts one N-strip per XCD and streams all
// of A through every XCD. Remap gives each XCD a contiguous band of gy/8
// row-tiles with all col-tiles co-resident (requires (gx*gy) % 8 == 0).
__device__ __forceinline__ void remap_xcd(int li, int gx, int gy,
                                          int& bx, int& by) {
  int xcd = li & 7;
  int slot = li >> 3;
  bx = slot % gx;
  by = xcd * (gy >> 3) + slot / gx;
}

#define PHASE_MID()                                       \
  __builtin_amdgcn_s_barrier();                           \
  asm volatile("s_waitcnt lgkmcnt(0)" ::: "memory");      \
  __builtin_amdgcn_sched_barrier(0);                      \
  __builtin_amdgcn_s_setprio(1)

#define PHASE_END()                                       \
  __builtin_amdgcn_s_setprio(0);                          \
  __builtin_amdgcn_sched_barrier(0);                      \
  __builtin_amdgcn_s_barrier()

#define PHASE_END_VM(N)                                   \
  __builtin_amdgcn_s_setprio(0);                          \
  __builtin_amdgcn_sched_barrier(0);                      \
  asm volatile("s_waitcnt vmcnt(" #N ")" ::: "memory");   \
  __builtin_amdgcn_s_barrier()

// ===========================================================================
// gemm256: 256x256x(BK=64) bf16 MFMA GEMM, C = A @ B^T, DEEP-PIPELINED.
// 8 waves (2M x 4N), per-wave 128x64 output (acc[8][4]), 16 MFMA per phase,
// LDS 128 KiB = double-buffered A[256x64] + B[256x64] (XOR source-swizzle,
// bank-conflict-free), staged as HALF-tiles (128 rows = 16 chunks, 2/wave).
//
// Region lifecycle per tile t (buf b=t&1), reads pinned by per-phase
// lgkmcnt(0) + double barriers:
//   B0[b]  read P3(t-1) -> restage at P0(t)     B1[b]  read P0(t) -> P1(t)
//   A1[b]  read P1(t)   -> restage at P2(t)     A0[b^1] read P2(t) -> P3(t)
// Stage schedule (ONE half-tile = 2 loads/thread per phase):
//   P0: B0(t+2)  P1: B1(t+2)  P2: A1(t+2)  P3: A0(t+3)
// Every stage lands 7 phases before its read; the covering wait is a uniform
// vmcnt(12) at EVERY phase end (exactly 6 stages x 2 loads issued after the
// needed one -> issue-to-forced-land = 6 phases, ~4000 cyc >> HBM latency).
// Tail: parity-preserving clamped re-stages (same data into an already-
// consumed region) keep the vmcnt counting uniform. Requires NT >= 4.
// Prologue: tiles 0,1 staged + drain; A0(2) staged only after the pre-read
// of A0(0) completes (its region overlaps).
// EPI: 0 = silu->bf16, 1 = fp32, 3 = expert-select fp32.
// ===========================================================================
template <int MB, int NB>
__device__ __forceinline__ void mfmaQ(const bf16x8 af[4][2], const bf16x8 bf[2][2],
                                      f32x4 acc[8][4]) {
#pragma unroll
  for (int mt = 0; mt < 4; ++mt)
#pragma unroll
    for (int nt = 0; nt < 2; ++nt)
#pragma unroll
      for (int kk = 0; kk < 2; ++kk)
        acc[MB + mt][NB + nt] = __builtin_amdgcn_mfma_f32_16x16x32_bf16(
            af[mt][kk], bf[nt][kk], acc[MB + mt][NB + nt], 0, 0, 0);
}

template <int EPI>
__global__ __launch_bounds__(512, 2) void gemm256(
    const unsigned short* __restrict__ A, int lda,
    const unsigned short* __restrict__ B, int ldb,
    void* __restrict__ C, int ldc, const int* __restrict__ route, int kLen) {
  __shared__ unsigned short As[2][256 * 64];
  __shared__ unsigned short Bs[2][256 * 64];
  const int lane = threadIdx.x & 63;
  const int wave = threadIdx.x >> 6;      // 0..7
  const int wm = wave >> 2, wn = wave & 3;
  int li = blockIdx.x + gridDim.x * blockIdx.y;
  int bx, by;
  remap_xcd(li, gridDim.x, gridDim.y, bx, by);
  const long rowBase = (long)by * 256;
  const long colBase = (long)bx * 256;
  const int srow = lane >> 3;
  const int scol = ((lane & 7) ^ (srow & 7)) * 8;  // pre-swizzled global src
  const unsigned short* Ag = A + (rowBase + srow) * (long)lda + scol;
  const unsigned short* Bg = B + (colBase + srow) * (long)ldb + scol;
  const int NT = kLen >> 6;  // REQUIRES NT >= 4

  auto st2 = [&](unsigned short* lds, const unsigned short* g, long ld, int t,
                 int half) {  // one half-tile (128 rows): 16 chunks, 2/wave
#pragma unroll
    for (int c = 0; c < 2; ++c) {
      int chunk = half * 16 + wave * 2 + c;
      __builtin_amdgcn_global_load_lds(
          (const __attribute__((address_space(1))) unsigned int*)(uintptr_t)(
              g + (size_t)chunk * 8 * ld + (size_t)t * 64),
          (__attribute__((address_space(3))) unsigned int*)(uintptr_t)(
              lds + chunk * 512),
          16, 0, 0);
    }
  };
  auto rdA = [&](const unsigned short* base, int mhalf, bf16x8 dst[4][2]) {
#pragma unroll
    for (int mt = 0; mt < 4; ++mt)
#pragma unroll
      for (int kk = 0; kk < 2; ++kk) {
        int rr = mhalf * 128 + wm * 64 + mt * 16 + (lane & 15);
        int sw = (kk * 4 + (lane >> 4)) ^ (lane & 7);  // rr&7 == lane&7
        dst[mt][kk] = *(const bf16x8*)&base[rr * 64 + sw * 8];
      }
  };
  auto rdB = [&](const unsigned short* base, int nhalf, bf16x8 dst[2][2]) {
#pragma unroll
    for (int nt = 0; nt < 2; ++nt)
#pragma unroll
      for (int kk = 0; kk < 2; ++kk) {
        int rr = nhalf * 128 + wn * 32 + nt * 16 + (lane & 15);
        int sw = (kk * 4 + (lane >> 4)) ^ (lane & 7);
        dst[nt][kk] = *(const bf16x8*)&base[rr * 64 + sw * 8];
      }
  };

  f32x4 acc[8][4] = {};
  bf16x8 afA[4][2], afB[4][2], bfA[2][2], bfB[2][2];

  // prologue: stage tiles 0 and 1 fully; drain; pre-read A0(0)/B0(0).
  st2(As[0], Ag, lda, 0, 0);
  st2(Bs[0], Bg, ldb, 0, 0);
  st2(Bs[0], Bg, ldb, 0, 1);
  st2(As[0], Ag, lda, 0, 1);
  if (NT > 1) {
    st2(As[1], Ag, lda, 1, 0);
    st2(Bs[1], Bg, ldb, 1, 0);
    st2(Bs[1], Bg, ldb, 1, 1);
    st2(As[1], Ag, lda, 1, 1);
  }
  asm volatile("s_waitcnt vmcnt(0)" ::: "memory");
  __builtin_amdgcn_s_barrier();
  rdA(As[0], 0, afA);
  rdB(Bs[0], 0, bfA);
  if (NT > 2) {
    // A0(2) overwrites the region holding A0(0): wait for ALL waves' pre-reads.
    asm volatile("s_waitcnt lgkmcnt(0)" ::: "memory");
    __builtin_amdgcn_s_barrier();
    st2(As[0], Ag, lda, 2, 0);  // read at P2(1); exactly covered by vmcnt(12)
  }

  for (int t = 0; t < NT; ++t) {
    const int b = t & 1;
    unsigned short* Asn = As[b ^ 1];
    unsigned short* Bsn = Bs[b ^ 1];
    // clamped stage sources (parity-preserving; rewrite same data at tail)
    const int s2 = (t + 2 < NT) ? t + 2 : t;
    const int s3 = (t + 3 < NT) ? t + 3 : ((t + 1 < NT) ? t + 1 : t - 1);
    // ---- P0: read B1(t); stage B0(s2); MFMA Q(m0,n0)
    rdB(Bs[b], 1, bfB);
    if (NT > 1) st2(Bs[b], Bg, ldb, s2, 0);
    PHASE_MID();
    mfmaQ<0, 0>(afA, bfA, acc);
    PHASE_END_VM(12);
    // ---- P1: read A1(t); stage B1(s2); MFMA Q(m0,n1)
    rdA(As[b], 1, afB);
    if (NT > 1) st2(Bs[b], Bg, ldb, s2, 1);
    PHASE_MID();
    mfmaQ<0, 2>(afA, bfB, acc);
    PHASE_END_VM(12);
    // ---- P2: read A0(t+1); stage A1(s2); MFMA Q(m1,n0)
    if (t + 1 < NT) rdA(Asn, 0, afA);
    if (NT > 1) st2(As[b], Ag, lda, s2, 1);
    PHASE_MID();
    mfmaQ<4, 0>(afB, bfA, acc);
    PHASE_END_VM(12);
    // ---- P3: read B0(t+1); stage A0(s3); MFMA Q(m1,n1)
    if (t + 1 < NT) rdB(Bsn, 0, bfA);
    if (NT > 2) st2(Asn, Ag, lda, s3, 0);
    PHASE_MID();
    mfmaQ<4, 2>(afB, bfB, acc);
    if (t + 1 < NT) { PHASE_END_VM(12); } else { PHASE_END_VM(0); }
  }

  // Epilogue. Frag C/D layout (m89): col=lane&15, row=(lane>>4)*4+r.
  // acc[mt][nt]: row = (mt>>2)*128 + wm*64 + (mt&3)*16, col = (nt>>1)*128 + wn*32 + (nt&1)*16.
  const int rsub = (lane >> 4) * 4;
  const int csub = lane & 15;
#pragma unroll
  for (int mt = 0; mt < 8; ++mt) {
#pragma unroll
    for (int nt = 0; nt < 4; ++nt) {
      long col = colBase + (nt >> 1) * 128 + wn * 32 + (nt & 1) * 16 + csub;
#pragma unroll
      for (int r = 0; r < 4; ++r) {
        long row = rowBase + (mt >> 2) * 128 + wm * 64 + (mt & 3) * 16 + rsub + r;
        float v = acc[mt][nt][r];
        if (EPI == 0) {
          float s = __fdividef(v, 1.0f + __expf(-v));  // silu
          ((unsigned short*)C)[row * ldc + col] = f2bf(s);
        } else if (EPI == 1) {
          ((float*)C)[row * ldc + col] = v;
        } else {  // EPI == 3: expert-select store into a_sel [TOK][ADP] fp32
          if (route[row] == (int)(col >> 8))
            ((float*)C)[row * ADP + (col & 255)] = v;
        }
      }
    }
  }
}

// ===========================================================================
// gemm8p: BM=128/BN=256 8-phase kernel (kept for the N=1024 out-proj where a
// 256-wide N tile would leave half the grid idle). Measured ~1100 TF @K=4352.
// ===========================================================================
__device__ __forceinline__ void read_frag4(const unsigned short* base, int lane,
                                           int rowoff, int kk, bf16x8* dst) {
#pragma unroll
  for (int i = 0; i < 4; ++i) {
    int rr = rowoff + i * 16 + (lane & 15);
    int sw = ((kk >> 3) + (lane >> 4)) ^ (lane & 7);  // rr&7 == lane&7
    dst[i] = *(const bf16x8*)&base[rr * 64 + sw * 8];
  }
}

template <int NH>
__device__ __forceinline__ void mfma8(const bf16x8* af, const bf16x8* bf,
                                      f32x4 acc[4][4]) {
#pragma unroll
  for (int mt = 0; mt < 4; ++mt)
#pragma unroll
    for (int q = 0; q < 2; ++q)
      acc[mt][NH * 2 + q] = __builtin_amdgcn_mfma_f32_16x16x32_bf16(
          af[mt], bf[NH * 2 + q], acc[mt][NH * 2 + q], 0, 0, 0);
}

template <int EPI>
__global__ __launch_bounds__(512, 2) void gemm8p(
    const unsigned short* __restrict__ A, int lda,
    const unsigned short* __restrict__ B, int ldb,
    void* __restrict__ C, int ldc, const int* __restrict__ route, int kLen) {
  __shared__ unsigned short As[2][128 * 64];
  __shared__ unsigned short Bs[2][256 * 64];
  const int lane = threadIdx.x & 63;
  const int wave = threadIdx.x >> 6;      // 0..7
  const int wm = wave >> 2, wn = wave & 3;
  int li = blockIdx.x + gridDim.x * blockIdx.y;
  int bx, by;
  remap_xcd(li, gridDim.x, gridDim.y, bx, by);
  const long rowBase = (long)by * 128;
  const long colBase = (long)bx * 256;
  const int srow = lane >> 3;
  const int scol = ((lane & 7) ^ (srow & 7)) * 8;  // pre-swizzled global src
  const unsigned short* Ag = A + (rowBase + srow) * (long)lda + scol;
  const unsigned short* Bg = B + (colBase + srow) * (long)ldb + scol;
  const int NT = kLen >> 6;

  auto stA = [&](int buf, int t) {  // whole A tile: 16 chunks, 2/wave
#pragma unroll
    for (int c = 0; c < 2; ++c) {
      int chunk = wave * 2 + c;
      __builtin_amdgcn_global_load_lds(
          (const __attribute__((address_space(1))) unsigned int*)(uintptr_t)(
              Ag + (size_t)chunk * 8 * lda + (size_t)t * 64),
          (__attribute__((address_space(3))) unsigned int*)(uintptr_t)(
              &As[buf][chunk * 512]),
          16, 0, 0);
    }
  };
  auto stB = [&](int buf, int t, int h) {  // B half-tile: 16 chunks, 2/wave
#pragma unroll
    for (int c = 0; c < 2; ++c) {
      int chunk = h * 16 + wave * 2 + c;
      __builtin_amdgcn_global_load_lds(
          (const __attribute__((address_space(1))) unsigned int*)(uintptr_t)(
              Bg + (size_t)chunk * 8 * ldb + (size_t)t * 64),
          (__attribute__((address_space(3))) unsigned int*)(uintptr_t)(
              &Bs[buf][chunk * 512]),
          16, 0, 0);
    }
  };

  f32x4 acc[4][4] = {};
  bf16x8 af0[4], af1[4], bf0[4], bf1[4];

  // prologue: tile0 (B halves + A), then the D(-1) stages for tile1
  stB(0, 0, 0);
  stB(0, 0, 1);
  stA(0, 0);
  if (NT > 1) {
    stA(1, 1);
    stB(1, 1, 0);
    asm volatile("s_waitcnt vmcnt(4)" ::: "memory");  // tile0 landed
  } else {
    asm volatile("s_waitcnt vmcnt(0)" ::: "memory");
  }
  __builtin_amdgcn_s_barrier();
  read_frag4(&As[0][0], lane, wm * 64, 0, af0);

  for (int t = 0; t < NT; ++t) {
    const int b = t & 1;
    // ---- phase A: bfr[t,kk0]; stage Bh[t+1][1]
    read_frag4(&Bs[b][0], lane, wn * 64, 0, bf0);
    if (t + 1 < NT) stB(b ^ 1, t + 1, 1);
    PHASE_MID();
    mfma8<0>(af0, bf0, acc);
    PHASE_END();
    // ---- phase B: af[t,kk1]
    read_frag4(&As[b][0], lane, wm * 64, 32, af1);
    PHASE_MID();
    mfma8<1>(af0, bf0, acc);
    PHASE_END();
    // ---- phase C: bfr[t,kk1]; vmcnt(4) -> A[t+1] landed for phase D's read
    read_frag4(&Bs[b][0], lane, wn * 64, 32, bf1);
    PHASE_MID();
    mfma8<0>(af1, bf1, acc);
    PHASE_END_VM(4);
    // ---- phase D: af[t+1,kk0]; stage A[t+2] + Bh[t+2][0];
    //      vmcnt(4) -> Bh[t+1][0,1] landed for next phase A's read
    if (t + 1 < NT) read_frag4(&As[b ^ 1][0], lane, wm * 64, 0, af0);
    if (t + 2 < NT) { stA(b, t + 2); stB(b, t + 2, 0); }
    PHASE_MID();
    mfma8<1>(af1, bf1, acc);
    PHASE_END_VM(4);
  }

  // Epilogue. C/D layout (m89-verified): col = lane&15, row = (lane>>4)*4 + r.
  const int rsub = (lane >> 4) * 4;
  const int csub = lane & 15;
#pragma unroll
  for (int mt = 0; mt < 4; ++mt) {
#pragma unroll
    for (int nt = 0; nt < 4; ++nt) {
      long col = colBase + wn * 64 + nt * 16 + csub;
#pragma unroll
      for (int r = 0; r < 4; ++r) {
        long row = rowBase + wm * 64 + mt * 16 + rsub + r;
        float v = acc[mt][nt][r];
        if (EPI == 0) {
          float s = __fdividef(v, 1.0f + __expf(-v));  // silu
          ((unsigned short*)C)[row * ldc + col] = f2bf(s);
        } else if (EPI == 1) {
          ((float*)C)[row * ldc + col] = v;
        } else {  // EPI == 3
          if (route[row] == (int)(col >> 8))
            ((float*)C)[row * ADP + (col & 255)] = v;
        }
      }
    }
  }
}

// ---------------------------------------------------------------------------
// Legacy 128x128x(BK=64) m97-structure GEMM body — retained for the dual
// split-K launch only (small K-slices, needs split-K parallelism).
// ---------------------------------------------------------------------------
__device__ __forceinline__ void stage_tile(const unsigned short* __restrict__ g,
                                           int ldg, unsigned short* lds,
                                           int wave, int lane) {
  int srow = lane >> 3;
  int scol = ((lane & 7) ^ (srow & 7)) * 8;
#pragma unroll
  for (int c = 0; c < 4; ++c) {
    int chunk = wave * 4 + c;
    const unsigned short* gp = g + (size_t)(chunk * 8 + srow) * ldg + scol;
    unsigned short* lp = lds + chunk * 512;
    __builtin_amdgcn_global_load_lds(
        (const __attribute__((address_space(1))) unsigned int*)(uintptr_t)gp,
        (__attribute__((address_space(3))) unsigned int*)(uintptr_t)lp,
        16, 0, 0);
  }
}

__device__ __forceinline__ void gemm_body1(
    int bxr, int byr, int bz,
    const unsigned short* __restrict__ A, int lda,
    const unsigned short* __restrict__ B, int ldb,
    float* __restrict__ C, int ldc, int kLen, long splitStride,
    unsigned short* As, unsigned short* Bs) {
  const int lane = threadIdx.x & 63;
  const int wave = threadIdx.x >> 6;
  const int wm = wave >> 1, wn = wave & 1;
  const long rowBase = (long)byr * 128;
  const long colBase = (long)bxr * 128;
  const int ks = bz * kLen;
  const unsigned short* Ap = A + rowBase * lda + ks;
  const unsigned short* Bp = B + colBase * ldb + ks;
  f32x4 acc[4][4] = {};

  for (int kt = 0; kt < kLen; kt += 64) {
    stage_tile(Ap + kt, lda, As, wave, lane);
    stage_tile(Bp + kt, ldb, Bs, wave, lane);
    __syncthreads();
#pragma unroll
    for (int kk = 0; kk < 64; kk += 32) {
      const int kb = (kk >> 3) + (lane >> 4);
      const int sw = kb ^ (lane & 7);
      bf16x8 af[4], bfr[4];
#pragma unroll
      for (int mt = 0; mt < 4; ++mt) {
        int m = wm * 64 + mt * 16 + (lane & 15);
        af[mt] = *(const bf16x8*)&As[m * 64 + sw * 8];
      }
#pragma unroll
      for (int nt = 0; nt < 4; ++nt) {
        int n = wn * 64 + nt * 16 + (lane & 15);
        bfr[nt] = *(const bf16x8*)&Bs[n * 64 + sw * 8];
      }
#pragma unroll
      for (int mt = 0; mt < 4; ++mt)
#pragma unroll
        for (int nt = 0; nt < 4; ++nt)
          acc[mt][nt] = __builtin_amdgcn_mfma_f32_16x16x32_bf16(
              af[mt], bfr[nt], acc[mt][nt], 0, 0, 0);
    }
    __syncthreads();
  }

  const int rsub = (lane >> 4) * 4;
  const int csub = lane & 15;
#pragma unroll
  for (int mt = 0; mt < 4; ++mt) {
#pragma unroll
    for (int nt = 0; nt < 4; ++nt) {
      long col = colBase + wn * 64 + nt * 16 + csub;
#pragma unroll
      for (int r = 0; r < 4; ++r) {
        long row = rowBase + wm * 64 + mt * 16 + rsub + r;
        (C + splitStride * bz)[row * ldc + col] = acc[mt][nt][r];
      }
    }
  }
}

// ---------------------------------------------------------------------------
// Dual GEMM launch (both split-K fp32): blocks [0,nb0) run grid0, rest grid1.
// Hides the tiny Wcomb split-K GEMM inside the adapt split-K launch.
// ---------------------------------------------------------------------------
__global__ __launch_bounds__(256, 3) void gemm_dual(
    const unsigned short* __restrict__ A0, int lda0,
    const unsigned short* __restrict__ B0, int ldb0,
    float* __restrict__ C0, int ldc0, int kLen0, long ss0, int gx0, int gy0,
    int nb0,
    const unsigned short* __restrict__ A1, int lda1,
    const unsigned short* __restrict__ B1, int ldb1,
    float* __restrict__ C1, int ldc1, int kLen1, long ss1, int gx1, int gy1) {
  __shared__ unsigned short As[128 * 64];
  __shared__ unsigned short Bs[128 * 64];
  int li = blockIdx.x;
  if (li < nb0) {
    int per = gx0 * gy0;
    int z = li / per, rem = li % per;
    int bx, by;
    remap_xcd(rem, gx0, gy0, bx, by);
    gemm_body1(bx, by, z, A0, lda0, B0, ldb0, C0, ldc0, kLen0, ss0, As, Bs);
  } else {
    int wli = li - nb0;
    int per = gx1 * gy1;
    int z = wli / per, rem = wli % per;
    int bx, by;
    remap_xcd(rem, gx1, gy1, bx, by);
    gemm_body1(bx, by, z, A1, lda1, B1, ldb1, C1, ldc1, kLen1, ss1, As, Bs);
  }
}

// ---------------------------------------------------------------------------
// Merged elementwise reductions (block-range dispatch):
//   [0,2048)    : sum 4 split-K fp32 partials of A -> bf16 ab
//   [2048,2304) : sum 8 split-K fp32 partials of Wcomb, x0.1 -> bf16 tail of wob
// ---------------------------------------------------------------------------
__global__ __launch_bounds__(256) void reduce_both(
    const float* __restrict__ P, unsigned short* __restrict__ ab,
    const float* __restrict__ Pw, unsigned short* __restrict__ wob) {
  int b = blockIdx.x;
  if (b < 2048) {
    size_t i = ((size_t)b * 256 + threadIdx.x) * 4;
    const size_t stride = (size_t)TOK * ADP;
    float4 p0 = *(const float4*)(P + i);
    float4 p1 = *(const float4*)(P + stride + i);
    float4 p2 = *(const float4*)(P + 2 * stride + i);
    float4 p3 = *(const float4*)(P + 3 * stride + i);
    ushort4 o;
    o.x = f2bf(p0.x + p1.x + p2.x + p3.x);
    o.y = f2bf(p0.y + p1.y + p2.y + p3.y);
    o.z = f2bf(p0.z + p1.z + p2.z + p3.z);
    o.w = f2bf(p0.w + p1.w + p2.w + p3.w);
    *(ushort4*)(ab + i) = o;
  } else {
    size_t i = ((size_t)(b - 2048) * 256 + threadIdx.x) * 4;  // over 1024*256
    const size_t stride = (size_t)DEMB * ADP;
    float4 s = *(const float4*)(Pw + i);
#pragma unroll
    for (int k = 1; k < 8; ++k) {
      float4 p = *(const float4*)(Pw + k * stride + i);
      s.x += p.x; s.y += p.y; s.z += p.z; s.w += p.w;
    }
    size_t d = i >> 8, a = i & 255;
    ushort4 o;
    o.x = f2bf(0.1f * s.x); o.y = f2bf(0.1f * s.y);
    o.z = f2bf(0.1f * s.z); o.w = f2bf(0.1f * s.w);
    *(ushort4*)(wob + d * KAUG + HID + a) = o;
  }
}

// ---------------------------------------------------------------------------
// LayerNorm over a_sel rows: one WAVE per token (4 tokens / 256-thread block).
// Writes bf16 a_norm into the tail columns [4096..4351] of H_aug (0 for
// inactive tokens); the 0.1 combine scale is folded into Wcomb.
// ---------------------------------------------------------------------------
__global__ __launch_bounds__(256) void ln_kernel(
    const float* __restrict__ asel, const int* __restrict__ route,
    const float* __restrict__ gamma, const float* __restrict__ beta,
    unsigned short* __restrict__ haug) {
  const int lane = threadIdx.x & 63;
  const int t = blockIdx.x * 4 + (threadIdx.x >> 6);
  const int e = route[t];
  float4 v = *(const float4*)(asel + (size_t)t * ADP + lane * 4);
  float s1 = v.x + v.y + v.z + v.w;
  float s2 = v.x * v.x + v.y * v.y + v.z * v.z + v.w * v.w;
#pragma unroll
  for (int off = 32; off > 0; off >>= 1) {
    s1 += __shfl_down(s1, off);
    s2 += __shfl_down(s2, off);
  }
  s1 = __shfl(s1, 0);
  s2 = __shfl(s2, 0);
  float mu = s1 * (1.0f / ADP);
  float var = s2 * (1.0f / ADP) - mu * mu;
  float rstd = rsqrtf(var + 1e-5f);
  ushort4 o;
  if (e >= 0) {
    float4 g = *(const float4*)(gamma + (size_t)e * ADP + lane * 4);
    float4 b = *(const float4*)(beta + (size_t)e * ADP + lane * 4);
    o.x = f2bf((v.x - mu) * rstd * g.x + b.x);
    o.y = f2bf((v.y - mu) * rstd * g.y + b.y);
    o.z = f2bf((v.z - mu) * rstd * g.z + b.z);
    o.w = f2bf((v.w - mu) * rstd * g.w + b.w);
  } else {
    o.x = o.y = o.z = o.w = 0;
  }
  *(ushort4*)(haug + (size_t)t * KAUG + HID + lane * 4) = o;
}

// ---------------------------------------------------------------------------
extern "C" void kernel_launch(void* const* d_in, const int* in_sizes, int n_in,
                              void* d_out, int out_size, void* d_ws, size_t ws_size,
                              hipStream_t stream) {
  const float* x     = (const float*)d_in[0];
  const float* ew    = (const float*)d_in[1];
  const float* W_up  = (const float*)d_in[2];
  const float* W_ad  = (const float*)d_in[3];
  const float* W_ex  = (const float*)d_in[4];
  const float* gam   = (const float*)d_in[5];
  const float* bet   = (const float*)d_in[6];
  const float* W_pr  = (const float*)d_in[7];
  const float* W_out = (const float*)d_in[8];
  float* out = (float*)d_out;

  // workspace layout (~150 MiB total)
  char* ws = (char*)d_ws;
  size_t off = 0;
  auto alloc = [&](size_t n) {
    char* p = ws + off;
    off += (n + 255) & ~(size_t)255;
    return p;
  };
  unsigned short* xb   = (unsigned short*)alloc((size_t)TOK * DEMB * 2);
  unsigned short* wub  = (unsigned short*)alloc((size_t)HID * DEMB * 2);
  unsigned short* wob  = (unsigned short*)alloc((size_t)DEMB * KAUG * 2);  // [Wout | Wcomb]
  unsigned short* wab  = (unsigned short*)alloc((size_t)ADP * HID * 2);
  unsigned short* web  = (unsigned short*)alloc((size_t)NEXP * ADP * ADP * 2);
  unsigned short* wpT  = (unsigned short*)alloc((size_t)ADP * HID * 2);    // Wproj^T bf16
  unsigned short* Haug = (unsigned short*)alloc((size_t)TOK * KAUG * 2);   // [H | anorm]
  float*          P    = (float*)alloc((size_t)4 * TOK * ADP * 4);
  float*          Pw   = (float*)alloc((size_t)8 * DEMB * ADP * 4);
  unsigned short* ab   = (unsigned short*)alloc((size_t)TOK * ADP * 2);
  int*          route  = (int*)alloc((size_t)TOK * 4);
  // a_sel aliases P: P fully consumed by reduce_both before gemm256<3> writes.
  float* asel = P;

  // 1) bf16 conversion of x + weights + routing + Wproj^T  (one launch)
  convert_all<<<9248, 256, 0, stream>>>(x, W_up, W_out, W_ad, W_ex, ew, W_pr,
                                        xb, wub, wob, wab, web, route, wpT);
  // 2) H = silu(x @ W_up^T) into cols [0,4096) of H_aug  (deep 256^2, NT=16)
  gemm256<0><<<dim3(HID / 256, TOK / 256, 1), 512, 0, stream>>>(
      xb, DEMB, wub, DEMB, Haug, KAUG, nullptr, DEMB);
  // 3) dual: A = H @ W_adapt^T (split-K=4, 512 blocks)
  //        + Wcomb = W_out @ W_proj (split-K=8, 128 blocks) in one launch
  gemm_dual<<<640, 256, 0, stream>>>(
      Haug, KAUG, wab, HID, P, ADP, HID / 4, (long)TOK * ADP, 2, 64, 512,
      wob, KAUG, wpT, HID, Pw, ADP, HID / 8, (long)DEMB * ADP, 2, 8);
  // 4) merged reductions: a partials -> bf16 ab; Wcomb partials -> wob tail
  reduce_both<<<2304, 256, 0, stream>>>(P, ab, Pw, wob);
  // 5) a_all = a @ W_all^T for all 8 experts; keep winning slice -> a_sel
  //    (deep 256^2, NT=4)
  gemm256<3><<<dim3(NEXP * ADP / 256, TOK / 256, 1), 512, 0, stream>>>(
      ab, ADP, web, ADP, asel, ADP, route, ADP);
  // 6) LayerNorm per token -> bf16 into tail cols of H_aug
  ln_kernel<<<TOK / 4, 256, 0, stream>>>(asel, route, gam, bet, Haug);
  // 7) out = H_aug @ [Wout | Wcomb]^T, K=4352  (8-phase, 256 blocks = 1/CU)
  gemm8p<1><<<dim3(DEMB / 256, TOK / 128, 1), 512, 0, stream>>>(
      Haug, KAUG, wob, KAUG, out, DEMB, nullptr, KAUG);
}

// Round 4
// 387.304 us; speedup vs baseline: 1.0030x; 1.0030x over previous
//
#include <hip/hip_runtime.h>
#include <cstdint>

// Problem constants (fixed by reference: B=4, S=2048)
#define TOK  8192   // B*S
#define DEMB 1024   // N_EMBD
#define HID  4096   // HIDDEN
#define ADP  256    // ADAPT
#define NEXP 8
#define KAUG 4352   // HID + ADP (K-augmented out-proj)

typedef __bf16 bf16x8 __attribute__((ext_vector_type(8)));
typedef float  f32x4  __attribute__((ext_vector_type(4)));

__device__ __forceinline__ unsigned short f2bf(float f) {
  // round-to-nearest-even fp32 -> bf16 (matches numpy/jax cast for normal values)
  unsigned int u = __float_as_uint(f);
  u += 0x7fffu + ((u >> 16) & 1u);
  return (unsigned short)(u >> 16);
}
__device__ __forceinline__ float bf2f(unsigned short b) {
  return __uint_as_float(((unsigned int)b) << 16);
}

// ---------------------------------------------------------------------------
// fp32 -> bf16 conversion for x and weights + routing + Wproj transpose, one
// kernel (block-range dispatch). Blocks:
//   [0,8960)    : 2048-elem conversion chunks (x, wup, wout->strided, wadapt, wexp)
//   [8960,8992) : routing (last active expert, -1 if none)
//   [8992,9248) : transpose-convert W_proj [4096,256] fp32 -> wpT [256,4096] bf16
// ---------------------------------------------------------------------------
__global__ __launch_bounds__(256) void convert_all(
    const float* __restrict__ x, const float* __restrict__ wup,
    const float* __restrict__ wout, const float* __restrict__ wadapt,
    const float* __restrict__ wexp, const float* __restrict__ ew,
    const float* __restrict__ wp,
    unsigned short* __restrict__ xb, unsigned short* __restrict__ wub,
    unsigned short* __restrict__ wob, unsigned short* __restrict__ wab,
    unsigned short* __restrict__ web, int* __restrict__ route,
    unsigned short* __restrict__ wpT) {
  __shared__ float tile[64][65];  // only used by transpose blocks
  int b = blockIdx.x;
  if (b >= 8992) {  // Wproj transpose: 64x64 LDS tiles, pad 65 (2-way = free)
    int wli = b - 8992;
    const int h0 = (wli & 63) * 64;  // over 4096
    const int a0 = (wli >> 6) * 64;  // over 256
    const int t = threadIdx.x;
    const int r = t >> 4;            // 0..15
    const int c = (t & 15) * 4;      // 0..60
#pragma unroll
    for (int p = 0; p < 4; ++p) {
      int row = p * 16 + r;
      float4 v = *(const float4*)(wp + (size_t)(h0 + row) * ADP + a0 + c);
      tile[c + 0][row] = v.x;
      tile[c + 1][row] = v.y;
      tile[c + 2][row] = v.z;
      tile[c + 3][row] = v.w;
    }
    __syncthreads();
#pragma unroll
    for (int q = 0; q < 2; ++q) {
      int idx = q * 256 + t;
      int al = idx >> 3;             // a local 0..63
      int hg = (idx & 7) * 8;        // h local 0,8,..,56
      unsigned int w0 = (unsigned int)f2bf(tile[al][hg + 0]) |
                        ((unsigned int)f2bf(tile[al][hg + 1]) << 16);
      unsigned int w1 = (unsigned int)f2bf(tile[al][hg + 2]) |
                        ((unsigned int)f2bf(tile[al][hg + 3]) << 16);
      unsigned int w2 = (unsigned int)f2bf(tile[al][hg + 4]) |
                        ((unsigned int)f2bf(tile[al][hg + 5]) << 16);
      unsigned int w3 = (unsigned int)f2bf(tile[al][hg + 6]) |
                        ((unsigned int)f2bf(tile[al][hg + 7]) << 16);
      *(uint4*)(wpT + (size_t)(a0 + al) * HID + h0 + hg) =
          make_uint4(w0, w1, w2, w3);
    }
    return;
  }
  if (b >= 8960) {  // routing
    int t = (b - 8960) * 256 + threadIdx.x;
    const float* p = ew + (size_t)t * NEXP;
    int r = -1;
#pragma unroll
    for (int e = 0; e < NEXP; ++e)
      if (p[e] > 0.f) r = e;
    route[t] = r;
    return;
  }
  const float* src; unsigned short* dst; int lb; bool strided = false;
  if      (b < 4096) { src = x;      dst = xb;  lb = b; }
  else if (b < 6144) { src = wup;    dst = wub; lb = b - 4096; }
  else if (b < 8192) { src = wout;   dst = wob; lb = b - 6144; strided = true; }
  else if (b < 8704) { src = wadapt; dst = wab; lb = b - 8192; }
  else               { src = wexp;   dst = web; lb = b - 8704; }
  size_t base = (size_t)lb * 2048;
#pragma unroll
  for (int h = 0; h < 2; ++h) {
    size_t off = base + (size_t)h * 1024 + (size_t)threadIdx.x * 4;
    float4 v = *(const float4*)(src + off);
    ushort4 o;
    o.x = f2bf(v.x); o.y = f2bf(v.y); o.z = f2bf(v.z); o.w = f2bf(v.w);
    size_t doff = strided ? (off >> 12) * KAUG + (off & 4095) : off;
    *(ushort4*)(dst + doff) = o;
  }
}

// XCD-aware remap: raw round-robin puts one N-strip per XCD and streams all
// of A through every XCD. Remap gives each XCD a contiguous band of gy/8
// row-tiles with all col-tiles co-resident (requires (gx*gy) % 8 == 0).
__device__ __forceinline__ void remap_xcd(int li, int gx, int gy,
                                          int& bx, int& by) {
  int xcd = li & 7;
  int slot = li >> 3;
  bx = slot % gx;
  by = xcd * (gy >> 3) + slot / gx;
}

#define PHASE_MID()                                       \
  __builtin_amdgcn_s_barrier();                           \
  asm volatile("s_waitcnt lgkmcnt(0)" ::: "memory");      \
  __builtin_amdgcn_sched_barrier(0);                      \
  __builtin_amdgcn_s_setprio(1)

#define PHASE_END()                                       \
  __builtin_amdgcn_s_setprio(0);                          \
  __builtin_amdgcn_sched_barrier(0);                      \
  __builtin_amdgcn_s_barrier()

#define PHASE_END_VM(N)                                   \
  __builtin_amdgcn_s_setprio(0);                          \
  __builtin_amdgcn_sched_barrier(0);                      \
  asm volatile("s_waitcnt vmcnt(" #N ")" ::: "memory");   \
  __builtin_amdgcn_s_barrier()

// ===========================================================================
// gemm256: 256x256x(BK=64) bf16 MFMA GEMM, C = A @ B^T, v2 schedule.
// 8 waves (2M x 4N), per-wave 128x64 output (acc[8][4]), 16 MFMA per phase,
// LDS 128 KiB = double-buffered A[256x64] + B[256x64] (XOR source-swizzle,
// conflict-free), half-tile staging (128 rows = 16 chunks, 2 loads/thread).
//
// v2: reads + stages are issued INSIDE the MFMA region (after lgkmcnt(0) +
// sched_barrier), one phase ahead of use, so LDS latency and address VALU
// overlap MFMA issue. They drain at the NEXT phase's lgkmcnt(0) (~600 cyc
// later -> free). 2-K-tile unrolled loop gives compile-time buffer parity.
//
// Lifecycle invariant: a read in region(Pk) drains at MID(Pk+1).lgkmcnt(0),
// all waves sync at END(Pk+1).barrier -> region safely overwritable from
// region(Pk+2). Reads: P0:B1[b](t)  P1:A1[b](t)  P2:A0[b^1](t+1)
// P3:B0[b^1](t+1). Stage slots (each exactly at min-safe, all -> buf
// (t+2)&1 = b): P0:A0(t+2)  P1:B0(t+2)  P2:B1(t+2)  P3:A1(t+2).
// Uniform vmcnt(10) at every phase end: each stage has exactly 5 later
// stages (10 loads) when its read's preceding phase-end enforces it ->
// issue-to-forced-drain = 6 phase-ends (~4000 cyc >> HBM latency), and each
// stage is proven landed one full barrier before its ds_read.
// Tail: s=(t+2<NT)?t+2:t -> parity-preserving rewrite of consumed regions.
// Prologue: tiles 0,1 staged; vmcnt(8) (tile-0 landed); pre-read A0/B0(0);
// lgkmcnt(0)+barrier (pre-reads done before P0(0) overwrites A0-region).
// Requires NT even, >= 4. EPI: 0 = silu->bf16, 1 = fp32, 3 = expert-select.
// ===========================================================================
template <int MB, int NB>
__device__ __forceinline__ void mfmaQ(const bf16x8 af[4][2], const bf16x8 bf[2][2],
                                      f32x4 acc[8][4]) {
#pragma unroll
  for (int mt = 0; mt < 4; ++mt)
#pragma unroll
    for (int nt = 0; nt < 2; ++nt)
#pragma unroll
      for (int kk = 0; kk < 2; ++kk)
        acc[MB + mt][NB + nt] = __builtin_amdgcn_mfma_f32_16x16x32_bf16(
            af[mt][kk], bf[nt][kk], acc[MB + mt][NB + nt], 0, 0, 0);
}

template <int EPI>
__global__ __launch_bounds__(512, 2) void gemm256(
    const unsigned short* __restrict__ A, int lda,
    const unsigned short* __restrict__ B, int ldb,
    void* __restrict__ C, int ldc, const int* __restrict__ route, int kLen) {
  __shared__ unsigned short As[2][256 * 64];
  __shared__ unsigned short Bs[2][256 * 64];
  const int lane = threadIdx.x & 63;
  const int wave = threadIdx.x >> 6;      // 0..7
  const int wm = wave >> 2, wn = wave & 3;
  int li = blockIdx.x + gridDim.x * blockIdx.y;
  int bx, by;
  remap_xcd(li, gridDim.x, gridDim.y, bx, by);
  const long rowBase = (long)by * 256;
  const long colBase = (long)bx * 256;
  const int srow = lane >> 3;
  const int scol = ((lane & 7) ^ (srow & 7)) * 8;  // pre-swizzled global src
  const unsigned short* Ag = A + (rowBase + srow) * (long)lda + scol;
  const unsigned short* Bg = B + (colBase + srow) * (long)ldb + scol;
  const int NT = kLen >> 6;  // REQUIRES NT even, >= 4

  auto st2 = [&](unsigned short* lds, const unsigned short* g, long ld, int t,
                 int half) {  // one half-tile (128 rows): 16 chunks, 2/wave
#pragma unroll
    for (int c = 0; c < 2; ++c) {
      int chunk = half * 16 + wave * 2 + c;
      __builtin_amdgcn_global_load_lds(
          (const __attribute__((address_space(1))) unsigned int*)(uintptr_t)(
              g + (size_t)chunk * 8 * ld + (size_t)t * 64),
          (__attribute__((address_space(3))) unsigned int*)(uintptr_t)(
              lds + chunk * 512),
          16, 0, 0);
    }
  };
  auto rdA = [&](const unsigned short* base, int mhalf, bf16x8 dst[4][2]) {
#pragma unroll
    for (int mt = 0; mt < 4; ++mt)
#pragma unroll
      for (int kk = 0; kk < 2; ++kk) {
        int rr = mhalf * 128 + wm * 64 + mt * 16 + (lane & 15);
        int sw = (kk * 4 + (lane >> 4)) ^ (lane & 7);  // rr&7 == lane&7
        dst[mt][kk] = *(const bf16x8*)&base[rr * 64 + sw * 8];
      }
  };
  auto rdB = [&](const unsigned short* base, int nhalf, bf16x8 dst[2][2]) {
#pragma unroll
    for (int nt = 0; nt < 2; ++nt)
#pragma unroll
      for (int kk = 0; kk < 2; ++kk) {
        int rr = nhalf * 128 + wn * 32 + nt * 16 + (lane & 15);
        int sw = (kk * 4 + (lane >> 4)) ^ (lane & 7);
        dst[nt][kk] = *(const bf16x8*)&base[rr * 64 + sw * 8];
      }
  };

  f32x4 acc[8][4] = {};
  bf16x8 afA[4][2], afB[4][2], bfA[2][2], bfB[2][2];

  // prologue: stage tiles 0 and 1; partial drain (tile-0 only); pre-read.
  st2(As[0], Ag, lda, 0, 0);
  st2(Bs[0], Bg, ldb, 0, 0);
  st2(Bs[0], Bg, ldb, 0, 1);
  st2(As[0], Ag, lda, 0, 1);
  if (NT > 1) {
    st2(As[1], Ag, lda, 1, 0);
    st2(Bs[1], Bg, ldb, 1, 0);
    st2(Bs[1], Bg, ldb, 1, 1);
    st2(As[1], Ag, lda, 1, 1);
    asm volatile("s_waitcnt vmcnt(8)" ::: "memory");  // tile-0 landed
  } else {
    asm volatile("s_waitcnt vmcnt(0)" ::: "memory");
  }
  __builtin_amdgcn_s_barrier();
  rdA(As[0], 0, afA);
  rdB(Bs[0], 0, bfA);
  // pre-reads must complete in ALL waves before P0(0) stages into A0[0] h0.
  asm volatile("s_waitcnt lgkmcnt(0)" ::: "memory");
  __builtin_amdgcn_s_barrier();

  // One K-tile body: 4 phases; reads/stages inside the MFMA region.
#define TBODY(T, AsC, BsC, AsN, BsN)                                         \
  {                                                                          \
    const int t_ = (T);                                                      \
    const int s_ = (t_ + 2 < NT) ? t_ + 2 : t_;                              \
    /* P0: Q(m0,n0); read B1(t); stage A0(t+2) */                            \
    PHASE_MID();                                                             \
    rdB(BsC, 1, bfB);                                                        \
    st2(AsC, Ag, lda, s_, 0);                                                \
    mfmaQ<0, 0>(afA, bfA, acc);                                              \
    PHASE_END_VM(10);                                                        \
    /* P1: Q(m0,n1); read A1(t); stage B0(t+2) */                            \
    PHASE_MID();                                                             \
    rdA(AsC, 1, afB);                                                        \
    st2(BsC, Bg, ldb, s_, 0);                                                \
    mfmaQ<0, 2>(afA, bfB, acc);                                              \
    PHASE_END_VM(10);                                                        \
    /* P2: Q(m1,n0); read A0(t+1); stage B1(t+2) */                          \
    PHASE_MID();                                                             \
    if (t_ + 1 < NT) rdA(AsN, 0, afA);                                       \
    st2(BsC, Bg, ldb, s_, 1);                                                \
    mfmaQ<4, 0>(afB, bfA, acc);                                              \
    PHASE_END_VM(10);                                                        \
    /* P3: Q(m1,n1); read B0(t+1); stage A1(t+2) */                          \
    PHASE_MID();                                                             \
    if (t_ + 1 < NT) rdB(BsN, 0, bfA);                                       \
    st2(AsC, Ag, lda, s_, 1);                                                \
    mfmaQ<4, 2>(afB, bfB, acc);                                              \
    PHASE_END_VM(10);                                                        \
  }

  for (int t = 0; t < NT; t += 2) {
    TBODY(t, As[0], Bs[0], As[1], Bs[1]);
    TBODY(t + 1, As[1], Bs[1], As[0], Bs[0]);
  }
#undef TBODY
  asm volatile("s_waitcnt vmcnt(0)" ::: "memory");

  // Epilogue. Frag C/D layout (m89): col=lane&15, row=(lane>>4)*4+r.
  // acc[mt][nt]: row = (mt>>2)*128 + wm*64 + (mt&3)*16, col = (nt>>1)*128 + wn*32 + (nt&1)*16.
  const int rsub = (lane >> 4) * 4;
  const int csub = lane & 15;
#pragma unroll
  for (int mt = 0; mt < 8; ++mt) {
#pragma unroll
    for (int nt = 0; nt < 4; ++nt) {
      long col = colBase + (nt >> 1) * 128 + wn * 32 + (nt & 1) * 16 + csub;
#pragma unroll
      for (int r = 0; r < 4; ++r) {
        long row = rowBase + (mt >> 2) * 128 + wm * 64 + (mt & 3) * 16 + rsub + r;
        float v = acc[mt][nt][r];
        if (EPI == 0) {
          float s = __fdividef(v, 1.0f + __expf(-v));  // silu
          ((unsigned short*)C)[row * ldc + col] = f2bf(s);
        } else if (EPI == 1) {
          ((float*)C)[row * ldc + col] = v;
        } else {  // EPI == 3: expert-select store into a_sel [TOK][ADP] fp32
          if (route[row] == (int)(col >> 8))
            ((float*)C)[row * ADP + (col & 255)] = v;
        }
      }
    }
  }
}

// ===========================================================================
// gemm8p: BM=128/BN=256 8-phase kernel (N=1024 out-proj: 256 blocks = 1/CU).
// Proven ~75 us @ K=4352 in round 1. Unchanged.
// ===========================================================================
__device__ __forceinline__ void read_frag4(const unsigned short* base, int lane,
                                           int rowoff, int kk, bf16x8* dst) {
#pragma unroll
  for (int i = 0; i < 4; ++i) {
    int rr = rowoff + i * 16 + (lane & 15);
    int sw = ((kk >> 3) + (lane >> 4)) ^ (lane & 7);  // rr&7 == lane&7
    dst[i] = *(const bf16x8*)&base[rr * 64 + sw * 8];
  }
}

template <int NH>
__device__ __forceinline__ void mfma8(const bf16x8* af, const bf16x8* bf,
                                      f32x4 acc[4][4]) {
#pragma unroll
  for (int mt = 0; mt < 4; ++mt)
#pragma unroll
    for (int q = 0; q < 2; ++q)
      acc[mt][NH * 2 + q] = __builtin_amdgcn_mfma_f32_16x16x32_bf16(
          af[mt], bf[NH * 2 + q], acc[mt][NH * 2 + q], 0, 0, 0);
}

template <int EPI>
__global__ __launch_bounds__(512, 2) void gemm8p(
    const unsigned short* __restrict__ A, int lda,
    const unsigned short* __restrict__ B, int ldb,
    void* __restrict__ C, int ldc, const int* __restrict__ route, int kLen) {
  __shared__ unsigned short As[2][128 * 64];
  __shared__ unsigned short Bs[2][256 * 64];
  const int lane = threadIdx.x & 63;
  const int wave = threadIdx.x >> 6;      // 0..7
  const int wm = wave >> 2, wn = wave & 3;
  int li = blockIdx.x + gridDim.x * blockIdx.y;
  int bx, by;
  remap_xcd(li, gridDim.x, gridDim.y, bx, by);
  const long rowBase = (long)by * 128;
  const long colBase = (long)bx * 256;
  const int srow = lane >> 3;
  const int scol = ((lane & 7) ^ (srow & 7)) * 8;  // pre-swizzled global src
  const unsigned short* Ag = A + (rowBase + srow) * (long)lda + scol;
  const unsigned short* Bg = B + (colBase + srow) * (long)ldb + scol;
  const int NT = kLen >> 6;

  auto stA = [&](int buf, int t) {
#pragma unroll
    for (int c = 0; c < 2; ++c) {
      int chunk = wave * 2 + c;
      __builtin_amdgcn_global_load_lds(
          (const __attribute__((address_space(1))) unsigned int*)(uintptr_t)(
              Ag + (size_t)chunk * 8 * lda + (size_t)t * 64),
          (__attribute__((address_space(3))) unsigned int*)(uintptr_t)(
              &As[buf][chunk * 512]),
          16, 0, 0);
    }
  };
  auto stB = [&](int buf, int t, int h) {
#pragma unroll
    for (int c = 0; c < 2; ++c) {
      int chunk = h * 16 + wave * 2 + c;
      __builtin_amdgcn_global_load_lds(
          (const __attribute__((address_space(1))) unsigned int*)(uintptr_t)(
              Bg + (size_t)chunk * 8 * ldb + (size_t)t * 64),
          (__attribute__((address_space(3))) unsigned int*)(uintptr_t)(
              &Bs[buf][chunk * 512]),
          16, 0, 0);
    }
  };

  f32x4 acc[4][4] = {};
  bf16x8 af0[4], af1[4], bf0[4], bf1[4];

  stB(0, 0, 0);
  stB(0, 0, 1);
  stA(0, 0);
  if (NT > 1) {
    stA(1, 1);
    stB(1, 1, 0);
    asm volatile("s_waitcnt vmcnt(4)" ::: "memory");
  } else {
    asm volatile("s_waitcnt vmcnt(0)" ::: "memory");
  }
  __builtin_amdgcn_s_barrier();
  read_frag4(&As[0][0], lane, wm * 64, 0, af0);

  for (int t = 0; t < NT; ++t) {
    const int b = t & 1;
    read_frag4(&Bs[b][0], lane, wn * 64, 0, bf0);
    if (t + 1 < NT) stB(b ^ 1, t + 1, 1);
    PHASE_MID();
    mfma8<0>(af0, bf0, acc);
    PHASE_END();
    read_frag4(&As[b][0], lane, wm * 64, 32, af1);
    PHASE_MID();
    mfma8<1>(af0, bf0, acc);
    PHASE_END();
    read_frag4(&Bs[b][0], lane, wn * 64, 32, bf1);
    PHASE_MID();
    mfma8<0>(af1, bf1, acc);
    PHASE_END_VM(4);
    if (t + 1 < NT) read_frag4(&As[b ^ 1][0], lane, wm * 64, 0, af0);
    if (t + 2 < NT) { stA(b, t + 2); stB(b, t + 2, 0); }
    PHASE_MID();
    mfma8<1>(af1, bf1, acc);
    PHASE_END_VM(4);
  }

  const int rsub = (lane >> 4) * 4;
  const int csub = lane & 15;
#pragma unroll
  for (int mt = 0; mt < 4; ++mt) {
#pragma unroll
    for (int nt = 0; nt < 4; ++nt) {
      long col = colBase + wn * 64 + nt * 16 + csub;
#pragma unroll
      for (int r = 0; r < 4; ++r) {
        long row = rowBase + wm * 64 + mt * 16 + rsub + r;
        float v = acc[mt][nt][r];
        if (EPI == 0) {
          float s = __fdividef(v, 1.0f + __expf(-v));
          ((unsigned short*)C)[row * ldc + col] = f2bf(s);
        } else if (EPI == 1) {
          ((float*)C)[row * ldc + col] = v;
        } else {
          if (route[row] == (int)(col >> 8))
            ((float*)C)[row * ADP + (col & 255)] = v;
        }
      }
    }
  }
}

// ---------------------------------------------------------------------------
// 128x128x(BK=64) m97-structure GEMM body (3 blocks/CU, TLP-hidden). Used for
// the short-K expert GEMM (step 5) and the split-K dual launch (step 3).
// EPI: 1 = fp32 store (+split-K offset), 3 = expert-select fp32 store.
// ---------------------------------------------------------------------------
__device__ __forceinline__ void stage_tile(const unsigned short* __restrict__ g,
                                           int ldg, unsigned short* lds,
                                           int wave, int lane) {
  int srow = lane >> 3;
  int scol = ((lane & 7) ^ (srow & 7)) * 8;
#pragma unroll
  for (int c = 0; c < 4; ++c) {
    int chunk = wave * 4 + c;
    const unsigned short* gp = g + (size_t)(chunk * 8 + srow) * ldg + scol;
    unsigned short* lp = lds + chunk * 512;
    __builtin_amdgcn_global_load_lds(
        (const __attribute__((address_space(1))) unsigned int*)(uintptr_t)gp,
        (__attribute__((address_space(3))) unsigned int*)(uintptr_t)lp,
        16, 0, 0);
  }
}

template <int EPI>
__device__ __forceinline__ void gemm_body(
    int bxr, int byr, int bz,
    const unsigned short* __restrict__ A, int lda,
    const unsigned short* __restrict__ B, int ldb,
    void* __restrict__ C, int ldc,
    const int* __restrict__ route, int kLen, long splitStride,
    unsigned short* As, unsigned short* Bs) {
  const int lane = threadIdx.x & 63;
  const int wave = threadIdx.x >> 6;
  const int wm = wave >> 1, wn = wave & 1;
  const long rowBase = (long)byr * 128;
  const long colBase = (long)bxr * 128;
  const int ks = bz * kLen;
  const unsigned short* Ap = A + rowBase * lda + ks;
  const unsigned short* Bp = B + colBase * ldb + ks;
  f32x4 acc[4][4] = {};

  for (int kt = 0; kt < kLen; kt += 64) {
    stage_tile(Ap + kt, lda, As, wave, lane);
    stage_tile(Bp + kt, ldb, Bs, wave, lane);
    __syncthreads();
#pragma unroll
    for (int kk = 0; kk < 64; kk += 32) {
      const int kb = (kk >> 3) + (lane >> 4);
      const int sw = kb ^ (lane & 7);
      bf16x8 af[4], bfr[4];
#pragma unroll
      for (int mt = 0; mt < 4; ++mt) {
        int m = wm * 64 + mt * 16 + (lane & 15);
        af[mt] = *(const bf16x8*)&As[m * 64 + sw * 8];
      }
#pragma unroll
      for (int nt = 0; nt < 4; ++nt) {
        int n = wn * 64 + nt * 16 + (lane & 15);
        bfr[nt] = *(const bf16x8*)&Bs[n * 64 + sw * 8];
      }
#pragma unroll
      for (int mt = 0; mt < 4; ++mt)
#pragma unroll
        for (int nt = 0; nt < 4; ++nt)
          acc[mt][nt] = __builtin_amdgcn_mfma_f32_16x16x32_bf16(
              af[mt], bfr[nt], acc[mt][nt], 0, 0, 0);
    }
    __syncthreads();
  }

  const int rsub = (lane >> 4) * 4;
  const int csub = lane & 15;
#pragma unroll
  for (int mt = 0; mt < 4; ++mt) {
#pragma unroll
    for (int nt = 0; nt < 4; ++nt) {
      long col = colBase + wn * 64 + nt * 16 + csub;
#pragma unroll
      for (int r = 0; r < 4; ++r) {
        long row = rowBase + wm * 64 + mt * 16 + rsub + r;
        float v = acc[mt][nt][r];
        if (EPI == 1) {
          ((float*)C + splitStride * bz)[row * ldc + col] = v;
        } else {  // EPI == 3: expert-select store into a_sel [TOK][ADP] fp32
          if (route[row] == (int)(col >> 8))
            ((float*)C)[row * ADP + (col & 255)] = v;
        }
      }
    }
  }
}

template <int EPI>
__global__ __launch_bounds__(256, 3) void gemm128(
    const unsigned short* __restrict__ A, int lda,
    const unsigned short* __restrict__ B, int ldb,
    void* __restrict__ C, int ldc,
    const int* __restrict__ route, int kLen, long splitStride) {
  __shared__ unsigned short As[128 * 64];
  __shared__ unsigned short Bs[128 * 64];
  int li = blockIdx.x + gridDim.x * blockIdx.y;
  int bx, by;
  remap_xcd(li, gridDim.x, gridDim.y, bx, by);
  gemm_body<EPI>(bx, by, blockIdx.z, A, lda, B, ldb, C, ldc, route, kLen,
                 splitStride, As, Bs);
}

// ---------------------------------------------------------------------------
// Dual GEMM launch (both split-K fp32): blocks [0,nb0) run grid0, rest grid1.
// Hides the tiny Wcomb split-K GEMM inside the adapt split-K launch.
// ---------------------------------------------------------------------------
__global__ __launch_bounds__(256, 3) void gemm_dual(
    const unsigned short* __restrict__ A0, int lda0,
    const unsigned short* __restrict__ B0, int ldb0,
    float* __restrict__ C0, int ldc0, int kLen0, long ss0, int gx0, int gy0,
    int nb0,
    const unsigned short* __restrict__ A1, int lda1,
    const unsigned short* __restrict__ B1, int ldb1,
    float* __restrict__ C1, int ldc1, int kLen1, long ss1, int gx1, int gy1) {
  __shared__ unsigned short As[128 * 64];
  __shared__ unsigned short Bs[128 * 64];
  int li = blockIdx.x;
  if (li < nb0) {
    int per = gx0 * gy0;
    int z = li / per, rem = li % per;
    int bx, by;
    remap_xcd(rem, gx0, gy0, bx, by);
    gemm_body<1>(bx, by, z, A0, lda0, B0, ldb0, C0, ldc0, nullptr, kLen0, ss0,
                 As, Bs);
  } else {
    int wli = li - nb0;
    int per = gx1 * gy1;
    int z = wli / per, rem = wli % per;
    int bx, by;
    remap_xcd(rem, gx1, gy1, bx, by);
    gemm_body<1>(bx, by, z, A1, lda1, B1, ldb1, C1, ldc1, nullptr, kLen1, ss1,
                 As, Bs);
  }
}

// ---------------------------------------------------------------------------
// Merged elementwise reductions (block-range dispatch):
//   [0,2048)    : sum 4 split-K fp32 partials of A -> bf16 ab
//   [2048,2304) : sum 8 split-K fp32 partials of Wcomb, x0.1 -> bf16 tail of wob
// ---------------------------------------------------------------------------
__global__ __launch_bounds__(256) void reduce_both(
    const float* __restrict__ P, unsigned short* __restrict__ ab,
    const float* __restrict__ Pw, unsigned short* __restrict__ wob) {
  int b = blockIdx.x;
  if (b < 2048) {
    size_t i = ((size_t)b * 256 + threadIdx.x) * 4;
    const size_t stride = (size_t)TOK * ADP;
    float4 p0 = *(const float4*)(P + i);
    float4 p1 = *(const float4*)(P + stride + i);
    float4 p2 = *(const float4*)(P + 2 * stride + i);
    float4 p3 = *(const float4*)(P + 3 * stride + i);
    ushort4 o;
    o.x = f2bf(p0.x + p1.x + p2.x + p3.x);
    o.y = f2bf(p0.y + p1.y + p2.y + p3.y);
    o.z = f2bf(p0.z + p1.z + p2.z + p3.z);
    o.w = f2bf(p0.w + p1.w + p2.w + p3.w);
    *(ushort4*)(ab + i) = o;
  } else {
    size_t i = ((size_t)(b - 2048) * 256 + threadIdx.x) * 4;  // over 1024*256
    const size_t stride = (size_t)DEMB * ADP;
    float4 s = *(const float4*)(Pw + i);
#pragma unroll
    for (int k = 1; k < 8; ++k) {
      float4 p = *(const float4*)(Pw + k * stride + i);
      s.x += p.x; s.y += p.y; s.z += p.z; s.w += p.w;
    }
    size_t d = i >> 8, a = i & 255;
    ushort4 o;
    o.x = f2bf(0.1f * s.x); o.y = f2bf(0.1f * s.y);
    o.z = f2bf(0.1f * s.z); o.w = f2bf(0.1f * s.w);
    *(ushort4*)(wob + d * KAUG + HID + a) = o;
  }
}

// ---------------------------------------------------------------------------
// LayerNorm over a_sel rows: one WAVE per token (4 tokens / 256-thread block).
// Writes bf16 a_norm into the tail columns [4096..4351] of H_aug (0 for
// inactive tokens); the 0.1 combine scale is folded into Wcomb.
// ---------------------------------------------------------------------------
__global__ __launch_bounds__(256) void ln_kernel(
    const float* __restrict__ asel, const int* __restrict__ route,
    const float* __restrict__ gamma, const float* __restrict__ beta,
    unsigned short* __restrict__ haug) {
  const int lane = threadIdx.x & 63;
  const int t = blockIdx.x * 4 + (threadIdx.x >> 6);
  const int e = route[t];
  float4 v = *(const float4*)(asel + (size_t)t * ADP + lane * 4);
  float s1 = v.x + v.y + v.z + v.w;
  float s2 = v.x * v.x + v.y * v.y + v.z * v.z + v.w * v.w;
#pragma unroll
  for (int off = 32; off > 0; off >>= 1) {
    s1 += __shfl_down(s1, off);
    s2 += __shfl_down(s2, off);
  }
  s1 = __shfl(s1, 0);
  s2 = __shfl(s2, 0);
  float mu = s1 * (1.0f / ADP);
  float var = s2 * (1.0f / ADP) - mu * mu;
  float rstd = rsqrtf(var + 1e-5f);
  ushort4 o;
  if (e >= 0) {
    float4 g = *(const float4*)(gamma + (size_t)e * ADP + lane * 4);
    float4 b = *(const float4*)(beta + (size_t)e * ADP + lane * 4);
    o.x = f2bf((v.x - mu) * rstd * g.x + b.x);
    o.y = f2bf((v.y - mu) * rstd * g.y + b.y);
    o.z = f2bf((v.z - mu) * rstd * g.z + b.z);
    o.w = f2bf((v.w - mu) * rstd * g.w + b.w);
  } else {
    o.x = o.y = o.z = o.w = 0;
  }
  *(ushort4*)(haug + (size_t)t * KAUG + HID + lane * 4) = o;
}

// ---------------------------------------------------------------------------
extern "C" void kernel_launch(void* const* d_in, const int* in_sizes, int n_in,
                              void* d_out, int out_size, void* d_ws, size_t ws_size,
                              hipStream_t stream) {
  const float* x     = (const float*)d_in[0];
  const float* ew    = (const float*)d_in[1];
  const float* W_up  = (const float*)d_in[2];
  const float* W_ad  = (const float*)d_in[3];
  const float* W_ex  = (const float*)d_in[4];
  const float* gam   = (const float*)d_in[5];
  const float* bet   = (const float*)d_in[6];
  const float* W_pr  = (const float*)d_in[7];
  const float* W_out = (const float*)d_in[8];
  float* out = (float*)d_out;

  // workspace layout (~150 MiB total)
  char* ws = (char*)d_ws;
  size_t off = 0;
  auto alloc = [&](size_t n) {
    char* p = ws + off;
    off += (n + 255) & ~(size_t)255;
    return p;
  };
  unsigned short* xb   = (unsigned short*)alloc((size_t)TOK * DEMB * 2);
  unsigned short* wub  = (unsigned short*)alloc((size_t)HID * DEMB * 2);
  unsigned short* wob  = (unsigned short*)alloc((size_t)DEMB * KAUG * 2);  // [Wout | Wcomb]
  unsigned short* wab  = (unsigned short*)alloc((size_t)ADP * HID * 2);
  unsigned short* web  = (unsigned short*)alloc((size_t)NEXP * ADP * ADP * 2);
  unsigned short* wpT  = (unsigned short*)alloc((size_t)ADP * HID * 2);    // Wproj^T bf16
  unsigned short* Haug = (unsigned short*)alloc((size_t)TOK * KAUG * 2);   // [H | anorm]
  float*          P    = (float*)alloc((size_t)4 * TOK * ADP * 4);
  float*          Pw   = (float*)alloc((size_t)8 * DEMB * ADP * 4);
  unsigned short* ab   = (unsigned short*)alloc((size_t)TOK * ADP * 2);
  int*          route  = (int*)alloc((size_t)TOK * 4);
  // a_sel aliases P: P fully consumed by reduce_both before gemm128<3> writes.
  float* asel = P;

  // 1) bf16 conversion of x + weights + routing + Wproj^T  (one launch)
  convert_all<<<9248, 256, 0, stream>>>(x, W_up, W_out, W_ad, W_ex, ew, W_pr,
                                        xb, wub, wob, wab, web, route, wpT);
  // 2) H = silu(x @ W_up^T) into cols [0,4096) of H_aug  (256^2 v2, NT=16)
  gemm256<0><<<dim3(HID / 256, TOK / 256, 1), 512, 0, stream>>>(
      xb, DEMB, wub, DEMB, Haug, KAUG, nullptr, DEMB);
  // 3) dual: A = H @ W_adapt^T (split-K=4, 512 blocks)
  //        + Wcomb = W_out @ W_proj (split-K=8, 128 blocks) in one launch
  gemm_dual<<<640, 256, 0, stream>>>(
      Haug, KAUG, wab, HID, P, ADP, HID / 4, (long)TOK * ADP, 2, 64, 512,
      wob, KAUG, wpT, HID, Pw, ADP, HID / 8, (long)DEMB * ADP, 2, 8);
  // 4) merged reductions: a partials -> bf16 ab; Wcomb partials -> wob tail
  reduce_both<<<2304, 256, 0, stream>>>(P, ab, Pw, wob);
  // 5) a_all = a @ W_all^T for all 8 experts; keep winning slice -> a_sel
  //    (m97 128^2 structure: short K=256 favors TLP at 3 blocks/CU)
  gemm128<3><<<dim3(NEXP * ADP / 128, TOK / 128, 1), 256, 0, stream>>>(
      ab, ADP, web, ADP, asel, ADP, route, ADP, 0);
  // 6) LayerNorm per token -> bf16 into tail cols of H_aug
  ln_kernel<<<TOK / 4, 256, 0, stream>>>(asel, route, gam, bet, Haug);
  // 7) out = H_aug @ [Wout | Wcomb]^T, K=4352  (8-phase, 256 blocks = 1/CU)
  gemm8p<1><<<dim3(DEMB / 256, TOK / 128, 1), 512, 0, stream>>>(
      Haug, KAUG, wob, KAUG, out, DEMB, nullptr, KAUG);
}

// Round 5
// 340.002 us; speedup vs baseline: 1.1425x; 1.1391x over previous
//
#include <hip/hip_runtime.h>
#include <cstdint>

// Problem constants (fixed by reference: B=4, S=2048)
#define TOK  8192   // B*S
#define DEMB 1024   // N_EMBD
#define HID  4096   // HIDDEN
#define ADP  256    // ADAPT
#define NEXP 8
#define KAUG 4352   // HID + ADP (K-augmented out-proj)

typedef __bf16 bf16x8 __attribute__((ext_vector_type(8)));
typedef float  f32x4  __attribute__((ext_vector_type(4)));

__device__ __forceinline__ unsigned short f2bf(float f) {
  // round-to-nearest-even fp32 -> bf16 (matches numpy/jax cast for normal values)
  unsigned int u = __float_as_uint(f);
  u += 0x7fffu + ((u >> 16) & 1u);
  return (unsigned short)(u >> 16);
}
__device__ __forceinline__ float bf2f(unsigned short b) {
  return __uint_as_float(((unsigned int)b) << 16);
}

// ---------------------------------------------------------------------------
// fp32 -> bf16 conversion for x and weights + routing + Wproj transpose, one
// kernel (block-range dispatch). Blocks:
//   [0,8960)    : 2048-elem conversion chunks (x, wup, wout->strided, wadapt, wexp)
//   [8960,8992) : routing (last active expert, -1 if none)
//   [8992,9248) : transpose-convert W_proj [4096,256] fp32 -> wpT [256,4096] bf16
// ---------------------------------------------------------------------------
__global__ __launch_bounds__(256) void convert_all(
    const float* __restrict__ x, const float* __restrict__ wup,
    const float* __restrict__ wout, const float* __restrict__ wadapt,
    const float* __restrict__ wexp, const float* __restrict__ ew,
    const float* __restrict__ wp,
    unsigned short* __restrict__ xb, unsigned short* __restrict__ wub,
    unsigned short* __restrict__ wob, unsigned short* __restrict__ wab,
    unsigned short* __restrict__ web, int* __restrict__ route,
    unsigned short* __restrict__ wpT) {
  __shared__ float tile[64][65];  // only used by transpose blocks
  int b = blockIdx.x;
  if (b >= 8992) {  // Wproj transpose: 64x64 LDS tiles, pad 65 (2-way = free)
    int wli = b - 8992;
    const int h0 = (wli & 63) * 64;  // over 4096
    const int a0 = (wli >> 6) * 64;  // over 256
    const int t = threadIdx.x;
    const int r = t >> 4;            // 0..15
    const int c = (t & 15) * 4;      // 0..60
#pragma unroll
    for (int p = 0; p < 4; ++p) {
      int row = p * 16 + r;
      float4 v = *(const float4*)(wp + (size_t)(h0 + row) * ADP + a0 + c);
      tile[c + 0][row] = v.x;
      tile[c + 1][row] = v.y;
      tile[c + 2][row] = v.z;
      tile[c + 3][row] = v.w;
    }
    __syncthreads();
#pragma unroll
    for (int q = 0; q < 2; ++q) {
      int idx = q * 256 + t;
      int al = idx >> 3;             // a local 0..63
      int hg = (idx & 7) * 8;        // h local 0,8,..,56
      unsigned int w0 = (unsigned int)f2bf(tile[al][hg + 0]) |
                        ((unsigned int)f2bf(tile[al][hg + 1]) << 16);
      unsigned int w1 = (unsigned int)f2bf(tile[al][hg + 2]) |
                        ((unsigned int)f2bf(tile[al][hg + 3]) << 16);
      unsigned int w2 = (unsigned int)f2bf(tile[al][hg + 4]) |
                        ((unsigned int)f2bf(tile[al][hg + 5]) << 16);
      unsigned int w3 = (unsigned int)f2bf(tile[al][hg + 6]) |
                        ((unsigned int)f2bf(tile[al][hg + 7]) << 16);
      *(uint4*)(wpT + (size_t)(a0 + al) * HID + h0 + hg) =
          make_uint4(w0, w1, w2, w3);
    }
    return;
  }
  if (b >= 8960) {  // routing
    int t = (b - 8960) * 256 + threadIdx.x;
    const float* p = ew + (size_t)t * NEXP;
    int r = -1;
#pragma unroll
    for (int e = 0; e < NEXP; ++e)
      if (p[e] > 0.f) r = e;
    route[t] = r;
    return;
  }
  const float* src; unsigned short* dst; int lb; bool strided = false;
  if      (b < 4096) { src = x;      dst = xb;  lb = b; }
  else if (b < 6144) { src = wup;    dst = wub; lb = b - 4096; }
  else if (b < 8192) { src = wout;   dst = wob; lb = b - 6144; strided = true; }
  else if (b < 8704) { src = wadapt; dst = wab; lb = b - 8192; }
  else               { src = wexp;   dst = web; lb = b - 8704; }
  size_t base = (size_t)lb * 2048;
#pragma unroll
  for (int h = 0; h < 2; ++h) {
    size_t off = base + (size_t)h * 1024 + (size_t)threadIdx.x * 4;
    float4 v = *(const float4*)(src + off);
    ushort4 o;
    o.x = f2bf(v.x); o.y = f2bf(v.y); o.z = f2bf(v.z); o.w = f2bf(v.w);
    size_t doff = strided ? (off >> 12) * KAUG + (off & 4095) : off;
    *(ushort4*)(dst + doff) = o;
  }
}

// XCD-aware remap: raw round-robin puts one N-strip per XCD and streams all
// of A through every XCD. Remap gives each XCD a contiguous band of gy/8
// row-tiles with all col-tiles co-resident (requires gy % 8 == 0).
__device__ __forceinline__ void remap_xcd(int li, int gx, int gy,
                                          int& bx, int& by) {
  int xcd = li & 7;
  int slot = li >> 3;
  bx = slot % gx;
  by = xcd * (gy >> 3) + slot / gx;
}

#define PHASE_MID()                                       \
  __builtin_amdgcn_s_barrier();                           \
  asm volatile("s_waitcnt lgkmcnt(0)" ::: "memory");      \
  __builtin_amdgcn_sched_barrier(0);                      \
  __builtin_amdgcn_s_setprio(1)

#define PHASE_END()                                       \
  __builtin_amdgcn_s_setprio(0);                          \
  __builtin_amdgcn_sched_barrier(0);                      \
  __builtin_amdgcn_s_barrier()

#define PHASE_END_VM(N)                                   \
  __builtin_amdgcn_s_setprio(0);                          \
  __builtin_amdgcn_sched_barrier(0);                      \
  asm volatile("s_waitcnt vmcnt(" #N ")" ::: "memory");   \
  __builtin_amdgcn_s_barrier()

// ---------------------------------------------------------------------------
// 128x128x(BK=64) bf16 MFMA GEMM body, C[m,n] = sum_k A[m,k]*B[n,k] (B^T).
// m97 structure: global_load_lds width-16 staging, XOR-swizzled LDS, 4 waves
// in 2x2 grid, 4x4 16x16x32 tiles/wave, 3 blocks/CU resident (TLP hides the
// barrier drain — measured ~875-980 TF on this problem, R0).
// EPI: 0 = silu -> bf16, 1 = fp32 store (+split-K offset),
//      3 = expert-select fp32 store (keep iff route[row] == col>>8).
// ---------------------------------------------------------------------------
__device__ __forceinline__ void stage_tile(const unsigned short* __restrict__ g,
                                           int ldg, unsigned short* lds,
                                           int wave, int lane) {
  int srow = lane >> 3;
  int scol = ((lane & 7) ^ (srow & 7)) * 8;
#pragma unroll
  for (int c = 0; c < 4; ++c) {
    int chunk = wave * 4 + c;
    const unsigned short* gp = g + (size_t)(chunk * 8 + srow) * ldg + scol;
    unsigned short* lp = lds + chunk * 512;
    __builtin_amdgcn_global_load_lds(
        (const __attribute__((address_space(1))) unsigned int*)(uintptr_t)gp,
        (__attribute__((address_space(3))) unsigned int*)(uintptr_t)lp,
        16, 0, 0);
  }
}

template <int EPI>
__device__ __forceinline__ void gemm_body(
    int bxr, int byr, int bz,
    const unsigned short* __restrict__ A, int lda,
    const unsigned short* __restrict__ B, int ldb,
    void* __restrict__ C, int ldc,
    const int* __restrict__ route, int kLen, long splitStride,
    unsigned short* As, unsigned short* Bs) {
  const int lane = threadIdx.x & 63;
  const int wave = threadIdx.x >> 6;
  const int wm = wave >> 1, wn = wave & 1;
  const long rowBase = (long)byr * 128;
  const long colBase = (long)bxr * 128;
  const int ks = bz * kLen;
  const unsigned short* Ap = A + rowBase * lda + ks;
  const unsigned short* Bp = B + colBase * ldb + ks;
  f32x4 acc[4][4] = {};

  for (int kt = 0; kt < kLen; kt += 64) {
    stage_tile(Ap + kt, lda, As, wave, lane);
    stage_tile(Bp + kt, ldb, Bs, wave, lane);
    __syncthreads();
#pragma unroll
    for (int kk = 0; kk < 64; kk += 32) {
      const int kb = (kk >> 3) + (lane >> 4);   // k-block 0..7
      const int sw = kb ^ (lane & 7);           // swizzled k-block
      bf16x8 af[4], bfr[4];
#pragma unroll
      for (int mt = 0; mt < 4; ++mt) {
        int m = wm * 64 + mt * 16 + (lane & 15);
        af[mt] = *(const bf16x8*)&As[m * 64 + sw * 8];
      }
#pragma unroll
      for (int nt = 0; nt < 4; ++nt) {
        int n = wn * 64 + nt * 16 + (lane & 15);
        bfr[nt] = *(const bf16x8*)&Bs[n * 64 + sw * 8];
      }
#pragma unroll
      for (int mt = 0; mt < 4; ++mt)
#pragma unroll
        for (int nt = 0; nt < 4; ++nt)
          acc[mt][nt] = __builtin_amdgcn_mfma_f32_16x16x32_bf16(
              af[mt], bfr[nt], acc[mt][nt], 0, 0, 0);
    }
    __syncthreads();
  }

  // Epilogue. C/D layout (m89-verified): col = lane&15, row = (lane>>4)*4 + r.
  const int rsub = (lane >> 4) * 4;
  const int csub = lane & 15;
#pragma unroll
  for (int mt = 0; mt < 4; ++mt) {
#pragma unroll
    for (int nt = 0; nt < 4; ++nt) {
      long col = colBase + wn * 64 + nt * 16 + csub;
#pragma unroll
      for (int r = 0; r < 4; ++r) {
        long row = rowBase + wm * 64 + mt * 16 + rsub + r;
        float v = acc[mt][nt][r];
        if (EPI == 0) {
          float s = __fdividef(v, 1.0f + __expf(-v));  // silu
          ((unsigned short*)C)[row * ldc + col] = f2bf(s);
        } else if (EPI == 1) {
          ((float*)C + splitStride * bz)[row * ldc + col] = v;
        } else {  // EPI == 3: expert-select store into a_sel [TOK][ADP] fp32
          if (route[row] == (int)(col >> 8))
            ((float*)C)[row * ADP + (col & 255)] = v;
        }
      }
    }
  }
}

template <int EPI>
__global__ __launch_bounds__(256, 3) void gemm128(
    const unsigned short* __restrict__ A, int lda,
    const unsigned short* __restrict__ B, int ldb,
    void* __restrict__ C, int ldc,
    const int* __restrict__ route, int kLen, long splitStride) {
  __shared__ unsigned short As[128 * 64];
  __shared__ unsigned short Bs[128 * 64];
  int li = blockIdx.x + gridDim.x * blockIdx.y;
  int bx, by;
  remap_xcd(li, gridDim.x, gridDim.y, bx, by);
  gemm_body<EPI>(bx, by, blockIdx.z, A, lda, B, ldb, C, ldc, route, kLen,
                 splitStride, As, Bs);
}

// ---------------------------------------------------------------------------
// Dual GEMM launch (both split-K fp32): blocks [0,nb0) run grid0 (gx0,gy0,z),
// blocks [nb0,..) run grid1. Hides the tiny Wcomb split-K GEMM (128 blocks)
// inside the adapt split-K launch's spare CUs.
// ---------------------------------------------------------------------------
__global__ __launch_bounds__(256, 3) void gemm_dual(
    const unsigned short* __restrict__ A0, int lda0,
    const unsigned short* __restrict__ B0, int ldb0,
    float* __restrict__ C0, int ldc0, int kLen0, long ss0, int gx0, int gy0,
    int nb0,
    const unsigned short* __restrict__ A1, int lda1,
    const unsigned short* __restrict__ B1, int ldb1,
    float* __restrict__ C1, int ldc1, int kLen1, long ss1, int gx1, int gy1) {
  __shared__ unsigned short As[128 * 64];
  __shared__ unsigned short Bs[128 * 64];
  int li = blockIdx.x;
  if (li < nb0) {
    int per = gx0 * gy0;
    int z = li / per, rem = li % per;
    int bx, by;
    remap_xcd(rem, gx0, gy0, bx, by);
    gemm_body<1>(bx, by, z, A0, lda0, B0, ldb0, C0, ldc0, nullptr, kLen0, ss0,
                 As, Bs);
  } else {
    int wli = li - nb0;
    int per = gx1 * gy1;
    int z = wli / per, rem = wli % per;
    int bx, by;
    remap_xcd(rem, gx1, gy1, bx, by);
    gemm_body<1>(bx, by, z, A1, lda1, B1, ldb1, C1, ldc1, nullptr, kLen1, ss1,
                 As, Bs);
  }
}

// ===========================================================================
// gemm8p: BM=128/BN=256 8-wave 4-phase kernel with counted vmcnt — the one
// schedule experiment that beat gemm128 (step 7, K=4352: ~76 us vs 83.4).
// Kept ONLY for the deep-K out-projection.
// ===========================================================================
__device__ __forceinline__ void read_frag4(const unsigned short* base, int lane,
                                           int rowoff, int kk, bf16x8* dst) {
#pragma unroll
  for (int i = 0; i < 4; ++i) {
    int rr = rowoff + i * 16 + (lane & 15);
    int sw = ((kk >> 3) + (lane >> 4)) ^ (lane & 7);  // rr&7 == lane&7
    dst[i] = *(const bf16x8*)&base[rr * 64 + sw * 8];
  }
}

template <int NH>
__device__ __forceinline__ void mfma8(const bf16x8* af, const bf16x8* bf,
                                      f32x4 acc[4][4]) {
#pragma unroll
  for (int mt = 0; mt < 4; ++mt)
#pragma unroll
    for (int q = 0; q < 2; ++q)
      acc[mt][NH * 2 + q] = __builtin_amdgcn_mfma_f32_16x16x32_bf16(
          af[mt], bf[NH * 2 + q], acc[mt][NH * 2 + q], 0, 0, 0);
}

template <int EPI>
__global__ __launch_bounds__(512, 2) void gemm8p(
    const unsigned short* __restrict__ A, int lda,
    const unsigned short* __restrict__ B, int ldb,
    void* __restrict__ C, int ldc, const int* __restrict__ route, int kLen) {
  __shared__ unsigned short As[2][128 * 64];
  __shared__ unsigned short Bs[2][256 * 64];
  const int lane = threadIdx.x & 63;
  const int wave = threadIdx.x >> 6;      // 0..7
  const int wm = wave >> 2, wn = wave & 3;
  int li = blockIdx.x + gridDim.x * blockIdx.y;
  int bx, by;
  remap_xcd(li, gridDim.x, gridDim.y, bx, by);
  const long rowBase = (long)by * 128;
  const long colBase = (long)bx * 256;
  const int srow = lane >> 3;
  const int scol = ((lane & 7) ^ (srow & 7)) * 8;  // pre-swizzled global src
  const unsigned short* Ag = A + (rowBase + srow) * (long)lda + scol;
  const unsigned short* Bg = B + (colBase + srow) * (long)ldb + scol;
  const int NT = kLen >> 6;

  auto stA = [&](int buf, int t) {  // whole A tile: 16 chunks, 2/wave
#pragma unroll
    for (int c = 0; c < 2; ++c) {
      int chunk = wave * 2 + c;
      __builtin_amdgcn_global_load_lds(
          (const __attribute__((address_space(1))) unsigned int*)(uintptr_t)(
              Ag + (size_t)chunk * 8 * lda + (size_t)t * 64),
          (__attribute__((address_space(3))) unsigned int*)(uintptr_t)(
              &As[buf][chunk * 512]),
          16, 0, 0);
    }
  };
  auto stB = [&](int buf, int t, int h) {  // B half-tile: 16 chunks, 2/wave
#pragma unroll
    for (int c = 0; c < 2; ++c) {
      int chunk = h * 16 + wave * 2 + c;
      __builtin_amdgcn_global_load_lds(
          (const __attribute__((address_space(1))) unsigned int*)(uintptr_t)(
              Bg + (size_t)chunk * 8 * ldb + (size_t)t * 64),
          (__attribute__((address_space(3))) unsigned int*)(uintptr_t)(
              &Bs[buf][chunk * 512]),
          16, 0, 0);
    }
  };

  f32x4 acc[4][4] = {};
  bf16x8 af0[4], af1[4], bf0[4], bf1[4];

  // prologue: tile0 (B halves + A), then the D(-1) stages for tile1
  stB(0, 0, 0);
  stB(0, 0, 1);
  stA(0, 0);
  if (NT > 1) {
    stA(1, 1);
    stB(1, 1, 0);
    asm volatile("s_waitcnt vmcnt(4)" ::: "memory");  // tile0 landed
  } else {
    asm volatile("s_waitcnt vmcnt(0)" ::: "memory");
  }
  __builtin_amdgcn_s_barrier();
  read_frag4(&As[0][0], lane, wm * 64, 0, af0);

  for (int t = 0; t < NT; ++t) {
    const int b = t & 1;
    // ---- phase A: bfr[t,kk0]; stage Bh[t+1][1]
    read_frag4(&Bs[b][0], lane, wn * 64, 0, bf0);
    if (t + 1 < NT) stB(b ^ 1, t + 1, 1);
    PHASE_MID();
    mfma8<0>(af0, bf0, acc);
    PHASE_END();
    // ---- phase B: af[t,kk1]
    read_frag4(&As[b][0], lane, wm * 64, 32, af1);
    PHASE_MID();
    mfma8<1>(af0, bf0, acc);
    PHASE_END();
    // ---- phase C: bfr[t,kk1]; vmcnt(4) -> A[t+1] landed for phase D's read
    read_frag4(&Bs[b][0], lane, wn * 64, 32, bf1);
    PHASE_MID();
    mfma8<0>(af1, bf1, acc);
    PHASE_END_VM(4);
    // ---- phase D: af[t+1,kk0]; stage A[t+2] + Bh[t+2][0];
    //      vmcnt(4) -> Bh[t+1][0,1] landed for next phase A's read
    if (t + 1 < NT) read_frag4(&As[b ^ 1][0], lane, wm * 64, 0, af0);
    if (t + 2 < NT) { stA(b, t + 2); stB(b, t + 2, 0); }
    PHASE_MID();
    mfma8<1>(af1, bf1, acc);
    PHASE_END_VM(4);
  }

  // Epilogue. C/D layout (m89-verified): col = lane&15, row = (lane>>4)*4 + r.
  const int rsub = (lane >> 4) * 4;
  const int csub = lane & 15;
#pragma unroll
  for (int mt = 0; mt < 4; ++mt) {
#pragma unroll
    for (int nt = 0; nt < 4; ++nt) {
      long col = colBase + wn * 64 + nt * 16 + csub;
#pragma unroll
      for (int r = 0; r < 4; ++r) {
        long row = rowBase + wm * 64 + mt * 16 + rsub + r;
        float v = acc[mt][nt][r];
        if (EPI == 0) {
          float s = __fdividef(v, 1.0f + __expf(-v));  // silu
          ((unsigned short*)C)[row * ldc + col] = f2bf(s);
        } else if (EPI == 1) {
          ((float*)C)[row * ldc + col] = v;
        } else {  // EPI == 3
          if (route[row] == (int)(col >> 8))
            ((float*)C)[row * ADP + (col & 255)] = v;
        }
      }
    }
  }
}

// ---------------------------------------------------------------------------
// Merged elementwise reductions (block-range dispatch):
//   [0,2048)    : sum 4 split-K fp32 partials of A -> bf16 ab
//   [2048,2304) : sum 8 split-K fp32 partials of Wcomb, x0.1 -> bf16 tail of wob
// ---------------------------------------------------------------------------
__global__ __launch_bounds__(256) void reduce_both(
    const float* __restrict__ P, unsigned short* __restrict__ ab,
    const float* __restrict__ Pw, unsigned short* __restrict__ wob) {
  int b = blockIdx.x;
  if (b < 2048) {
    size_t i = ((size_t)b * 256 + threadIdx.x) * 4;
    const size_t stride = (size_t)TOK * ADP;
    float4 p0 = *(const float4*)(P + i);
    float4 p1 = *(const float4*)(P + stride + i);
    float4 p2 = *(const float4*)(P + 2 * stride + i);
    float4 p3 = *(const float4*)(P + 3 * stride + i);
    ushort4 o;
    o.x = f2bf(p0.x + p1.x + p2.x + p3.x);
    o.y = f2bf(p0.y + p1.y + p2.y + p3.y);
    o.z = f2bf(p0.z + p1.z + p2.z + p3.z);
    o.w = f2bf(p0.w + p1.w + p2.w + p3.w);
    *(ushort4*)(ab + i) = o;
  } else {
    size_t i = ((size_t)(b - 2048) * 256 + threadIdx.x) * 4;  // over 1024*256
    const size_t stride = (size_t)DEMB * ADP;
    float4 s = *(const float4*)(Pw + i);
#pragma unroll
    for (int k = 1; k < 8; ++k) {
      float4 p = *(const float4*)(Pw + k * stride + i);
      s.x += p.x; s.y += p.y; s.z += p.z; s.w += p.w;
    }
    size_t d = i >> 8, a = i & 255;
    ushort4 o;
    o.x = f2bf(0.1f * s.x); o.y = f2bf(0.1f * s.y);
    o.z = f2bf(0.1f * s.z); o.w = f2bf(0.1f * s.w);
    *(ushort4*)(wob + d * KAUG + HID + a) = o;
  }
}

// ---------------------------------------------------------------------------
// LayerNorm over a_sel rows: one WAVE per token (4 tokens / 256-thread block).
// Writes bf16 a_norm into the tail columns [4096..4351] of H_aug (0 for
// inactive tokens); the 0.1 combine scale is folded into Wcomb.
// ---------------------------------------------------------------------------
__global__ __launch_bounds__(256) void ln_kernel(
    const float* __restrict__ asel, const int* __restrict__ route,
    const float* __restrict__ gamma, const float* __restrict__ beta,
    unsigned short* __restrict__ haug) {
  const int lane = threadIdx.x & 63;
  const int t = blockIdx.x * 4 + (threadIdx.x >> 6);
  const int e = route[t];
  float4 v = *(const float4*)(asel + (size_t)t * ADP + lane * 4);
  float s1 = v.x + v.y + v.z + v.w;
  float s2 = v.x * v.x + v.y * v.y + v.z * v.z + v.w * v.w;
#pragma unroll
  for (int off = 32; off > 0; off >>= 1) {
    s1 += __shfl_down(s1, off);
    s2 += __shfl_down(s2, off);
  }
  s1 = __shfl(s1, 0);
  s2 = __shfl(s2, 0);
  float mu = s1 * (1.0f / ADP);
  float var = s2 * (1.0f / ADP) - mu * mu;
  float rstd = rsqrtf(var + 1e-5f);
  ushort4 o;
  if (e >= 0) {
    float4 g = *(const float4*)(gamma + (size_t)e * ADP + lane * 4);
    float4 b = *(const float4*)(beta + (size_t)e * ADP + lane * 4);
    o.x = f2bf((v.x - mu) * rstd * g.x + b.x);
    o.y = f2bf((v.y - mu) * rstd * g.y + b.y);
    o.z = f2bf((v.z - mu) * rstd * g.z + b.z);
    o.w = f2bf((v.w - mu) * rstd * g.w + b.w);
  } else {
    o.x = o.y = o.z = o.w = 0;
  }
  *(ushort4*)(haug + (size_t)t * KAUG + HID + lane * 4) = o;
}

// ---------------------------------------------------------------------------
extern "C" void kernel_launch(void* const* d_in, const int* in_sizes, int n_in,
                              void* d_out, int out_size, void* d_ws, size_t ws_size,
                              hipStream_t stream) {
  const float* x     = (const float*)d_in[0];
  const float* ew    = (const float*)d_in[1];
  const float* W_up  = (const float*)d_in[2];
  const float* W_ad  = (const float*)d_in[3];
  const float* W_ex  = (const float*)d_in[4];
  const float* gam   = (const float*)d_in[5];
  const float* bet   = (const float*)d_in[6];
  const float* W_pr  = (const float*)d_in[7];
  const float* W_out = (const float*)d_in[8];
  float* out = (float*)d_out;

  // workspace layout (~150 MiB total)
  char* ws = (char*)d_ws;
  size_t off = 0;
  auto alloc = [&](size_t n) {
    char* p = ws + off;
    off += (n + 255) & ~(size_t)255;
    return p;
  };
  unsigned short* xb   = (unsigned short*)alloc((size_t)TOK * DEMB * 2);
  unsigned short* wub  = (unsigned short*)alloc((size_t)HID * DEMB * 2);
  unsigned short* wob  = (unsigned short*)alloc((size_t)DEMB * KAUG * 2);  // [Wout | Wcomb]
  unsigned short* wab  = (unsigned short*)alloc((size_t)ADP * HID * 2);
  unsigned short* web  = (unsigned short*)alloc((size_t)NEXP * ADP * ADP * 2);
  unsigned short* wpT  = (unsigned short*)alloc((size_t)ADP * HID * 2);    // Wproj^T bf16
  unsigned short* Haug = (unsigned short*)alloc((size_t)TOK * KAUG * 2);   // [H | anorm]
  float*          P    = (float*)alloc((size_t)4 * TOK * ADP * 4);
  float*          Pw   = (float*)alloc((size_t)8 * DEMB * ADP * 4);
  unsigned short* ab   = (unsigned short*)alloc((size_t)TOK * ADP * 2);
  int*          route  = (int*)alloc((size_t)TOK * 4);
  // a_sel aliases P: P fully consumed by reduce_both before gemm128<3> writes.
  float* asel = P;

  // 1) bf16 conversion of x + weights + routing + Wproj^T  (one launch)
  convert_all<<<9248, 256, 0, stream>>>(x, W_up, W_out, W_ad, W_ex, ew, W_pr,
                                        xb, wub, wob, wab, web, route, wpT);
  // 2) H = silu(x @ W_up^T) into cols [0,4096) of H_aug  (m97 128^2, 3/CU)
  gemm128<0><<<dim3(HID / 128, TOK / 128, 1), 256, 0, stream>>>(
      xb, DEMB, wub, DEMB, Haug, KAUG, nullptr, DEMB, 0);
  // 3) dual: A = H @ W_adapt^T (split-K=4, 512 blocks)
  //        + Wcomb = W_out @ W_proj (split-K=8, 128 blocks) in one launch
  gemm_dual<<<640, 256, 0, stream>>>(
      Haug, KAUG, wab, HID, P, ADP, HID / 4, (long)TOK * ADP, 2, 64, 512,
      wob, KAUG, wpT, HID, Pw, ADP, HID / 8, (long)DEMB * ADP, 2, 8);
  // 4) merged reductions: a partials -> bf16 ab; Wcomb partials -> wob tail
  reduce_both<<<2304, 256, 0, stream>>>(P, ab, Pw, wob);
  // 5) a_all = a @ W_all^T for all 8 experts; keep winning slice -> a_sel
  //    (m97 128^2: short K=256 favors 3-blocks/CU TLP)
  gemm128<3><<<dim3(NEXP * ADP / 128, TOK / 128, 1), 256, 0, stream>>>(
      ab, ADP, web, ADP, asel, ADP, route, ADP, 0);
  // 6) LayerNorm per token -> bf16 into tail cols of H_aug
  ln_kernel<<<TOK / 4, 256, 0, stream>>>(asel, route, gam, bet, Haug);
  // 7) out = H_aug @ [Wout | Wcomb]^T, K=4352  (gemm8p, 256 blocks = 1/CU;
  //    measured faster than gemm128 here: ~76 vs 83.4 us)
  gemm8p<1><<<dim3(DEMB / 256, TOK / 128, 1), 512, 0, stream>>>(
      Haug, KAUG, wob, KAUG, out, DEMB, nullptr, KAUG);
}

// Round 7
// 336.894 us; speedup vs baseline: 1.1530x; 1.0092x over previous
//
#include <hip/hip_runtime.h>
#include <cstdint>

// Problem constants (fixed by reference: B=4, S=2048)
#define TOK  8192   // B*S
#define DEMB 1024   // N_EMBD
#define HID  4096   // HIDDEN
#define ADP  256    // ADAPT
#define NEXP 8
#define KAUG 4352   // HID + ADP (K-augmented out-proj)

typedef __bf16 bf16x8 __attribute__((ext_vector_type(8)));
typedef float  f32x4  __attribute__((ext_vector_type(4)));

__device__ __forceinline__ unsigned short f2bf(float f) {
  // round-to-nearest-even fp32 -> bf16 (matches numpy/jax cast for normal values)
  unsigned int u = __float_as_uint(f);
  u += 0x7fffu + ((u >> 16) & 1u);
  return (unsigned short)(u >> 16);
}
__device__ __forceinline__ float bf2f(unsigned short b) {
  return __uint_as_float(((unsigned int)b) << 16);
}

// ---------------------------------------------------------------------------
// convert_a: the conversions step-2 depends on, nothing else.
//   [0,4096)    : x chunks      [4096,6144) : W_up chunks
//   [6144,6176) : routing (last active expert, -1 if none)
// ---------------------------------------------------------------------------
__global__ __launch_bounds__(256) void convert_a(
    const float* __restrict__ x, const float* __restrict__ wup,
    const float* __restrict__ ew,
    unsigned short* __restrict__ xb, unsigned short* __restrict__ wub,
    int* __restrict__ route) {
  int b = blockIdx.x;
  if (b >= 6144) {  // routing
    int t = (b - 6144) * 256 + threadIdx.x;
    const float* p = ew + (size_t)t * NEXP;
    int r = -1;
#pragma unroll
    for (int e = 0; e < NEXP; ++e)
      if (p[e] > 0.f) r = e;
    route[t] = r;
    return;
  }
  const float* src; unsigned short* dst; int lb;
  if (b < 4096) { src = x;   dst = xb;  lb = b; }
  else          { src = wup; dst = wub; lb = b - 4096; }
  size_t base = (size_t)lb * 2048;
#pragma unroll
  for (int h = 0; h < 2; ++h) {
    size_t off = base + (size_t)h * 1024 + (size_t)threadIdx.x * 4;
    float4 v = *(const float4*)(src + off);
    ushort4 o;
    o.x = f2bf(v.x); o.y = f2bf(v.y); o.z = f2bf(v.z); o.w = f2bf(v.w);
    *(ushort4*)(dst + off) = o;
  }
}

// XCD-aware remap: raw round-robin puts one N-strip per XCD and streams all
// of A through every XCD. Remap gives each XCD a contiguous band of gy/8
// row-tiles with all col-tiles co-resident (requires gy % 8 == 0).
__device__ __forceinline__ void remap_xcd(int li, int gx, int gy,
                                          int& bx, int& by) {
  int xcd = li & 7;
  int slot = li >> 3;
  bx = slot % gx;
  by = xcd * (gy >> 3) + slot / gx;
}

#define PHASE_MID()                                       \
  __builtin_amdgcn_s_barrier();                           \
  asm volatile("s_waitcnt lgkmcnt(0)" ::: "memory");      \
  __builtin_amdgcn_sched_barrier(0);                      \
  __builtin_amdgcn_s_setprio(1)

#define PHASE_END()                                       \
  __builtin_amdgcn_s_setprio(0);                          \
  __builtin_amdgcn_sched_barrier(0);                      \
  __builtin_amdgcn_s_barrier()

#define PHASE_END_VM(N)                                   \
  __builtin_amdgcn_s_setprio(0);                          \
  __builtin_amdgcn_sched_barrier(0);                      \
  asm volatile("s_waitcnt vmcnt(" #N ")" ::: "memory");   \
  __builtin_amdgcn_s_barrier()

// ---------------------------------------------------------------------------
// 128x128x(BK=64) bf16 MFMA GEMM body, C[m,n] = sum_k A[m,k]*B[n,k] (B^T).
// m97 structure: global_load_lds width-16 staging, XOR-swizzled LDS, 4 waves
// in 2x2 grid, 4x4 16x16x32 tiles/wave, multi-block/CU TLP (measured ~875 TF).
// EPI: 0 = silu -> bf16, 1 = fp32 store (+split-K offset).
// ---------------------------------------------------------------------------
__device__ __forceinline__ void stage_tile(const unsigned short* __restrict__ g,
                                           int ldg, unsigned short* lds,
                                           int wave, int lane) {
  int srow = lane >> 3;
  int scol = ((lane & 7) ^ (srow & 7)) * 8;
#pragma unroll
  for (int c = 0; c < 4; ++c) {
    int chunk = wave * 4 + c;
    const unsigned short* gp = g + (size_t)(chunk * 8 + srow) * ldg + scol;
    unsigned short* lp = lds + chunk * 512;
    __builtin_amdgcn_global_load_lds(
        (const __attribute__((address_space(1))) unsigned int*)(uintptr_t)gp,
        (__attribute__((address_space(3))) unsigned int*)(uintptr_t)lp,
        16, 0, 0);
  }
}

template <int EPI>
__device__ __forceinline__ void gemm_body(
    int bxr, int byr, int bz,
    const unsigned short* __restrict__ A, int lda,
    const unsigned short* __restrict__ B, int ldb,
    void* __restrict__ C, int ldc, int kLen, long splitStride,
    unsigned short* As, unsigned short* Bs) {
  const int lane = threadIdx.x & 63;
  const int wave = threadIdx.x >> 6;
  const int wm = wave >> 1, wn = wave & 1;
  const long rowBase = (long)byr * 128;
  const long colBase = (long)bxr * 128;
  const int ks = bz * kLen;
  const unsigned short* Ap = A + rowBase * lda + ks;
  const unsigned short* Bp = B + colBase * ldb + ks;
  f32x4 acc[4][4] = {};

  for (int kt = 0; kt < kLen; kt += 64) {
    stage_tile(Ap + kt, lda, As, wave, lane);
    stage_tile(Bp + kt, ldb, Bs, wave, lane);
    __syncthreads();
#pragma unroll
    for (int kk = 0; kk < 64; kk += 32) {
      const int kb = (kk >> 3) + (lane >> 4);   // k-block 0..7
      const int sw = kb ^ (lane & 7);           // swizzled k-block
      bf16x8 af[4], bfr[4];
#pragma unroll
      for (int mt = 0; mt < 4; ++mt) {
        int m = wm * 64 + mt * 16 + (lane & 15);
        af[mt] = *(const bf16x8*)&As[m * 64 + sw * 8];
      }
#pragma unroll
      for (int nt = 0; nt < 4; ++nt) {
        int n = wn * 64 + nt * 16 + (lane & 15);
        bfr[nt] = *(const bf16x8*)&Bs[n * 64 + sw * 8];
      }
#pragma unroll
      for (int mt = 0; mt < 4; ++mt)
#pragma unroll
        for (int nt = 0; nt < 4; ++nt)
          acc[mt][nt] = __builtin_amdgcn_mfma_f32_16x16x32_bf16(
              af[mt], bfr[nt], acc[mt][nt], 0, 0, 0);
    }
    __syncthreads();
  }

  // Epilogue. C/D layout (m89-verified): col = lane&15, row = (lane>>4)*4 + r.
  const int rsub = (lane >> 4) * 4;
  const int csub = lane & 15;
#pragma unroll
  for (int mt = 0; mt < 4; ++mt) {
#pragma unroll
    for (int nt = 0; nt < 4; ++nt) {
      long col = colBase + wn * 64 + nt * 16 + csub;
#pragma unroll
      for (int r = 0; r < 4; ++r) {
        long row = rowBase + wm * 64 + mt * 16 + rsub + r;
        float v = acc[mt][nt][r];
        if (EPI == 0) {
          float s = __fdividef(v, 1.0f + __expf(-v));  // silu
          ((unsigned short*)C)[row * ldc + col] = f2bf(s);
        } else {
          ((float*)C + splitStride * bz)[row * ldc + col] = v;
        }
      }
    }
  }
}

// ---------------------------------------------------------------------------
// fused2: block-range dispatch, one launch.
//   [0,2048)    : step-2 GEMM  H = silu(x @ W_up^T) -> Haug cols [0,4096)
//   [2048,4096) : W_out fp32 -> bf16 (strided into wob head)
//   [4096,4608) : W_adapt -> wab       [4608,4864) : W_exp -> web
//   [4864,5120) : transpose-convert W_proj -> wpT
// Conversions (~50 MB of traffic) overlap the compute-bound GEMM for free.
// ---------------------------------------------------------------------------
__global__ __launch_bounds__(256, 3) void fused2(
    const unsigned short* __restrict__ xb, const unsigned short* __restrict__ wub,
    unsigned short* __restrict__ haug,
    const float* __restrict__ wout, const float* __restrict__ wadapt,
    const float* __restrict__ wexp, const float* __restrict__ wp,
    unsigned short* __restrict__ wob, unsigned short* __restrict__ wab,
    unsigned short* __restrict__ web, unsigned short* __restrict__ wpT) {
  __shared__ char smem[32768];
  int li = blockIdx.x;
  if (li < 2048) {  // step-2 GEMM
    int bx, by;
    remap_xcd(li, 32, 64, bx, by);
    gemm_body<0>(bx, by, 0, xb, DEMB, wub, DEMB, haug, KAUG, DEMB, 0,
                 (unsigned short*)smem, (unsigned short*)(smem + 16384));
    return;
  }
  int cb = li - 2048;
  if (cb < 2816) {  // linear conversions
    const float* src; unsigned short* dst; int lb; bool strided = false;
    if (cb < 2048)      { src = wout;   dst = wob; lb = cb;        strided = true; }
    else if (cb < 2560) { src = wadapt; dst = wab; lb = cb - 2048; }
    else                { src = wexp;   dst = web; lb = cb - 2560; }
    size_t base = (size_t)lb * 2048;
#pragma unroll
    for (int h = 0; h < 2; ++h) {
      size_t off = base + (size_t)h * 1024 + (size_t)threadIdx.x * 4;
      float4 v = *(const float4*)(src + off);
      ushort4 o;
      o.x = f2bf(v.x); o.y = f2bf(v.y); o.z = f2bf(v.z); o.w = f2bf(v.w);
      size_t doff = strided ? (off >> 12) * KAUG + (off & 4095) : off;
      *(ushort4*)(dst + doff) = o;
    }
    return;
  }
  // Wproj transpose: 64x64 LDS tiles, pad 65 (2-way = free)
  float (*tile)[65] = (float(*)[65])smem;  // 64*65*4 = 16640 B <= 32768
  int wli = cb - 2816;
  const int h0 = (wli & 63) * 64;  // over 4096
  const int a0 = (wli >> 6) * 64;  // over 256
  const int t = threadIdx.x;
  const int r = t >> 4;            // 0..15
  const int c = (t & 15) * 4;      // 0..60
#pragma unroll
  for (int p = 0; p < 4; ++p) {
    int row = p * 16 + r;
    float4 v = *(const float4*)(wp + (size_t)(h0 + row) * ADP + a0 + c);
    tile[c + 0][row] = v.x;
    tile[c + 1][row] = v.y;
    tile[c + 2][row] = v.z;
    tile[c + 3][row] = v.w;
  }
  __syncthreads();
#pragma unroll
  for (int q = 0; q < 2; ++q) {
    int idx = q * 256 + t;
    int al = idx >> 3;             // a local 0..63
    int hg = (idx & 7) * 8;        // h local 0,8,..,56
    unsigned int w0 = (unsigned int)f2bf(tile[al][hg + 0]) |
                      ((unsigned int)f2bf(tile[al][hg + 1]) << 16);
    unsigned int w1 = (unsigned int)f2bf(tile[al][hg + 2]) |
                      ((unsigned int)f2bf(tile[al][hg + 3]) << 16);
    unsigned int w2 = (unsigned int)f2bf(tile[al][hg + 4]) |
                      ((unsigned int)f2bf(tile[al][hg + 5]) << 16);
    unsigned int w3 = (unsigned int)f2bf(tile[al][hg + 6]) |
                      ((unsigned int)f2bf(tile[al][hg + 7]) << 16);
    *(uint4*)(wpT + (size_t)(a0 + al) * HID + h0 + hg) =
        make_uint4(w0, w1, w2, w3);
  }
}

// ---------------------------------------------------------------------------
// Dual GEMM launch (both split-K fp32): blocks [0,nb0) run grid0 (gx0,gy0,z),
// blocks [nb0,..) run grid1. Hides the tiny Wcomb split-K GEMM (128 blocks)
// inside the adapt split-K launch's spare CUs.
// ---------------------------------------------------------------------------
__global__ __launch_bounds__(256, 3) void gemm_dual(
    const unsigned short* __restrict__ A0, int lda0,
    const unsigned short* __restrict__ B0, int ldb0,
    float* __restrict__ C0, int ldc0, int kLen0, long ss0, int gx0, int gy0,
    int nb0,
    const unsigned short* __restrict__ A1, int lda1,
    const unsigned short* __restrict__ B1, int ldb1,
    float* __restrict__ C1, int ldc1, int kLen1, long ss1, int gx1, int gy1) {
  __shared__ unsigned short As[128 * 64];
  __shared__ unsigned short Bs[128 * 64];
  int li = blockIdx.x;
  if (li < nb0) {
    int per = gx0 * gy0;
    int z = li / per, rem = li % per;
    int bx, by;
    remap_xcd(rem, gx0, gy0, bx, by);
    gemm_body<1>(bx, by, z, A0, lda0, B0, ldb0, C0, ldc0, kLen0, ss0, As, Bs);
  } else {
    int wli = li - nb0;
    int per = gx1 * gy1;
    int z = wli / per, rem = wli % per;
    int bx, by;
    remap_xcd(rem, gx1, gy1, bx, by);
    gemm_body<1>(bx, by, z, A1, lda1, B1, ldb1, C1, ldc1, kLen1, ss1, As, Bs);
  }
}

// ===========================================================================
// gemm8p: BM=128/BN=256 8-wave 4-phase kernel with counted vmcnt. Step 7
// (K=4352, 256 blocks = 1/CU): measured ~84 us. Kept for the deep-K
// out-projection.
// ===========================================================================
__device__ __forceinline__ void read_frag4(const unsigned short* base, int lane,
                                           int rowoff, int kk, bf16x8* dst) {
#pragma unroll
  for (int i = 0; i < 4; ++i) {
    int rr = rowoff + i * 16 + (lane & 15);
    int sw = ((kk >> 3) + (lane >> 4)) ^ (lane & 7);  // rr&7 == lane&7
    dst[i] = *(const bf16x8*)&base[rr * 64 + sw * 8];
  }
}

template <int NH>
__device__ __forceinline__ void mfma8(const bf16x8* af, const bf16x8* bf,
                                      f32x4 acc[4][4]) {
#pragma unroll
  for (int mt = 0; mt < 4; ++mt)
#pragma unroll
    for (int q = 0; q < 2; ++q)
      acc[mt][NH * 2 + q] = __builtin_amdgcn_mfma_f32_16x16x32_bf16(
          af[mt], bf[NH * 2 + q], acc[mt][NH * 2 + q], 0, 0, 0);
}

__global__ __launch_bounds__(512, 2) void gemm8p(
    const unsigned short* __restrict__ A, int lda,
    const unsigned short* __restrict__ B, int ldb,
    float* __restrict__ C, int ldc, int kLen) {
  __shared__ unsigned short As[2][128 * 64];
  __shared__ unsigned short Bs[2][256 * 64];
  const int lane = threadIdx.x & 63;
  const int wave = threadIdx.x >> 6;      // 0..7
  const int wm = wave >> 2, wn = wave & 3;
  int li = blockIdx.x + gridDim.x * blockIdx.y;
  int bx, by;
  remap_xcd(li, gridDim.x, gridDim.y, bx, by);
  const long rowBase = (long)by * 128;
  const long colBase = (long)bx * 256;
  const int srow = lane >> 3;
  const int scol = ((lane & 7) ^ (srow & 7)) * 8;  // pre-swizzled global src
  const unsigned short* Ag = A + (rowBase + srow) * (long)lda + scol;
  const unsigned short* Bg = B + (colBase + srow) * (long)ldb + scol;
  const int NT = kLen >> 6;

  auto stA = [&](int buf, int t) {  // whole A tile: 16 chunks, 2/wave
#pragma unroll
    for (int c = 0; c < 2; ++c) {
      int chunk = wave * 2 + c;
      __builtin_amdgcn_global_load_lds(
          (const __attribute__((address_space(1))) unsigned int*)(uintptr_t)(
              Ag + (size_t)chunk * 8 * lda + (size_t)t * 64),
          (__attribute__((address_space(3))) unsigned int*)(uintptr_t)(
              &As[buf][chunk * 512]),
          16, 0, 0);
    }
  };
  auto stB = [&](int buf, int t, int h) {  // B half-tile: 16 chunks, 2/wave
#pragma unroll
    for (int c = 0; c < 2; ++c) {
      int chunk = h * 16 + wave * 2 + c;
      __builtin_amdgcn_global_load_lds(
          (const __attribute__((address_space(1))) unsigned int*)(uintptr_t)(
              Bg + (size_t)chunk * 8 * ldb + (size_t)t * 64),
          (__attribute__((address_space(3))) unsigned int*)(uintptr_t)(
              &Bs[buf][chunk * 512]),
          16, 0, 0);
    }
  };

  f32x4 acc[4][4] = {};
  bf16x8 af0[4], af1[4], bf0[4], bf1[4];

  // prologue: tile0 (B halves + A), then the D(-1) stages for tile1
  stB(0, 0, 0);
  stB(0, 0, 1);
  stA(0, 0);
  if (NT > 1) {
    stA(1, 1);
    stB(1, 1, 0);
    asm volatile("s_waitcnt vmcnt(4)" ::: "memory");  // tile0 landed
  } else {
    asm volatile("s_waitcnt vmcnt(0)" ::: "memory");
  }
  __builtin_amdgcn_s_barrier();
  read_frag4(&As[0][0], lane, wm * 64, 0, af0);

  for (int t = 0; t < NT; ++t) {
    const int b = t & 1;
    // ---- phase A: bfr[t,kk0]; stage Bh[t+1][1]
    read_frag4(&Bs[b][0], lane, wn * 64, 0, bf0);
    if (t + 1 < NT) stB(b ^ 1, t + 1, 1);
    PHASE_MID();
    mfma8<0>(af0, bf0, acc);
    PHASE_END();
    // ---- phase B: af[t,kk1]
    read_frag4(&As[b][0], lane, wm * 64, 32, af1);
    PHASE_MID();
    mfma8<1>(af0, bf0, acc);
    PHASE_END();
    // ---- phase C: bfr[t,kk1]; vmcnt(4) -> A[t+1] landed for phase D's read
    read_frag4(&Bs[b][0], lane, wn * 64, 32, bf1);
    PHASE_MID();
    mfma8<0>(af1, bf1, acc);
    PHASE_END_VM(4);
    // ---- phase D: af[t+1,kk0]; stage A[t+2] + Bh[t+2][0];
    //      vmcnt(4) -> Bh[t+1][0,1] landed for next phase A's read
    if (t + 1 < NT) read_frag4(&As[b ^ 1][0], lane, wm * 64, 0, af0);
    if (t + 2 < NT) { stA(b, t + 2); stB(b, t + 2, 0); }
    PHASE_MID();
    mfma8<1>(af1, bf1, acc);
    PHASE_END_VM(4);
  }

  // Epilogue (fp32 store).
  const int rsub = (lane >> 4) * 4;
  const int csub = lane & 15;
#pragma unroll
  for (int mt = 0; mt < 4; ++mt) {
#pragma unroll
    for (int nt = 0; nt < 4; ++nt) {
      long col = colBase + wn * 64 + nt * 16 + csub;
#pragma unroll
      for (int r = 0; r < 4; ++r) {
        long row = rowBase + wm * 64 + mt * 16 + rsub + r;
        C[row * ldc + col] = acc[mt][nt][r];
      }
    }
  }
}

// ---------------------------------------------------------------------------
// Merged elementwise reductions (block-range dispatch):
//   [0,2048)    : sum 4 split-K fp32 partials of A -> bf16 ab
//   [2048,2304) : sum 8 split-K fp32 partials of Wcomb, x0.1 -> bf16 tail of wob
// ---------------------------------------------------------------------------
__global__ __launch_bounds__(256) void reduce_both(
    const float* __restrict__ P, unsigned short* __restrict__ ab,
    const float* __restrict__ Pw, unsigned short* __restrict__ wob) {
  int b = blockIdx.x;
  if (b < 2048) {
    size_t i = ((size_t)b * 256 + threadIdx.x) * 4;
    const size_t stride = (size_t)TOK * ADP;
    float4 p0 = *(const float4*)(P + i);
    float4 p1 = *(const float4*)(P + stride + i);
    float4 p2 = *(const float4*)(P + 2 * stride + i);
    float4 p3 = *(const float4*)(P + 3 * stride + i);
    ushort4 o;
    o.x = f2bf(p0.x + p1.x + p2.x + p3.x);
    o.y = f2bf(p0.y + p1.y + p2.y + p3.y);
    o.z = f2bf(p0.z + p1.z + p2.z + p3.z);
    o.w = f2bf(p0.w + p1.w + p2.w + p3.w);
    *(ushort4*)(ab + i) = o;
  } else {
    size_t i = ((size_t)(b - 2048) * 256 + threadIdx.x) * 4;  // over 1024*256
    const size_t stride = (size_t)DEMB * ADP;
    float4 s = *(const float4*)(Pw + i);
#pragma unroll
    for (int k = 1; k < 8; ++k) {
      float4 p = *(const float4*)(Pw + k * stride + i);
      s.x += p.x; s.y += p.y; s.z += p.z; s.w += p.w;
    }
    size_t d = i >> 8, a = i & 255;
    ushort4 o;
    o.x = f2bf(0.1f * s.x); o.y = f2bf(0.1f * s.y);
    o.z = f2bf(0.1f * s.z); o.w = f2bf(0.1f * s.w);
    *(ushort4*)(wob + d * KAUG + HID + a) = o;
  }
}

// ===========================================================================
// gemm_exp_ln: fused expert-adapter GEMM + per-token LayerNorm.
// BM=128, BN=256 = ONE expert's full adapter slice per block (bx = expert).
// 8 waves (2m x 4n), per-wave 64x64, m97 single-buffer K-loop (K=256, NT=4).
// After the K-loop each block holds complete 256-wide a_all rows for expert
// bx in registers: rows routed to bx get LN (shfl over 16 lanes + 4-wave LDS
// reduce) and bf16 anorm written straight into Haug tail cols [4096,4352).
// Kills: a_sel fp32 store+load (16 MiB), gamma/beta re-read, one launch.
// ===========================================================================
__global__ __launch_bounds__(512, 2) void gemm_exp_ln(
    const unsigned short* __restrict__ A,     // ab [TOK][ADP]
    const unsigned short* __restrict__ Wexp,  // web [NEXP][ADP][ADP]
    const int* __restrict__ route,
    const float* __restrict__ gamma, const float* __restrict__ beta,
    unsigned short* __restrict__ haug) {
  __shared__ unsigned short As[128 * 64];
  __shared__ unsigned short Bs[256 * 64];
  __shared__ float red1[4][128];
  __shared__ float red2[4][128];
  const int lane = threadIdx.x & 63;
  const int wave = threadIdx.x >> 6;      // 0..7
  const int wm = wave >> 2, wn = wave & 3;
  int li = blockIdx.x + gridDim.x * blockIdx.y;
  int bx, by;
  remap_xcd(li, gridDim.x, gridDim.y, bx, by);
  const long rowBase = (long)by * 128;
  const unsigned short* Ap = A + rowBase * ADP;
  const unsigned short* Bp = Wexp + (size_t)bx * ADP * ADP;
  const int srow = lane >> 3;
  const int scol = ((lane & 7) ^ (srow & 7)) * 8;
  f32x4 acc[4][4] = {};

  for (int kt = 0; kt < ADP; kt += 64) {
    // stage A tile (128x64): 16 chunks, 2/wave
#pragma unroll
    for (int c = 0; c < 2; ++c) {
      int chunk = wave * 2 + c;
      __builtin_amdgcn_global_load_lds(
          (const __attribute__((address_space(1))) unsigned int*)(uintptr_t)(
              Ap + (size_t)(chunk * 8 + srow) * ADP + kt + scol),
          (__attribute__((address_space(3))) unsigned int*)(uintptr_t)(
              As + chunk * 512),
          16, 0, 0);
    }
    // stage B tile (256x64): 32 chunks, 4/wave
#pragma unroll
    for (int c = 0; c < 4; ++c) {
      int chunk = wave * 4 + c;
      __builtin_amdgcn_global_load_lds(
          (const __attribute__((address_space(1))) unsigned int*)(uintptr_t)(
              Bp + (size_t)(chunk * 8 + srow) * ADP + kt + scol),
          (__attribute__((address_space(3))) unsigned int*)(uintptr_t)(
              Bs + chunk * 512),
          16, 0, 0);
    }
    __syncthreads();
#pragma unroll
    for (int kk = 0; kk < 64; kk += 32) {
      const int kb = (kk >> 3) + (lane >> 4);
      const int sw = kb ^ (lane & 7);
      bf16x8 af[4], bfr[4];
#pragma unroll
      for (int mt = 0; mt < 4; ++mt) {
        int m = wm * 64 + mt * 16 + (lane & 15);
        af[mt] = *(const bf16x8*)&As[m * 64 + sw * 8];
      }
#pragma unroll
      for (int nt = 0; nt < 4; ++nt) {
        int n = wn * 64 + nt * 16 + (lane & 15);
        bfr[nt] = *(const bf16x8*)&Bs[n * 64 + sw * 8];
      }
#pragma unroll
      for (int mt = 0; mt < 4; ++mt)
#pragma unroll
        for (int nt = 0; nt < 4; ++nt)
          acc[mt][nt] = __builtin_amdgcn_mfma_f32_16x16x32_bf16(
              af[mt], bfr[nt], acc[mt][nt], 0, 0, 0);
    }
    __syncthreads();
  }

  // ---- in-block LayerNorm over the 256-wide rows ----
  // Lane holds rows mt*16 + (lane>>4)*4 + r (16 rows) x cols wn*64+nt*16+(lane&15).
  float ls1[4][4], ls2[4][4];
#pragma unroll
  for (int mt = 0; mt < 4; ++mt)
#pragma unroll
    for (int r = 0; r < 4; ++r) {
      float s1 = 0.f, s2 = 0.f;
#pragma unroll
      for (int nt = 0; nt < 4; ++nt) {
        float v = acc[mt][nt][r];
        s1 += v; s2 += v * v;
      }
      ls1[mt][r] = s1; ls2[mt][r] = s2;
    }
  // reduce across the 16 lanes sharing the same rows (csub dimension)
#pragma unroll
  for (int m = 1; m < 16; m <<= 1)
#pragma unroll
    for (int mt = 0; mt < 4; ++mt)
#pragma unroll
      for (int r = 0; r < 4; ++r) {
        ls1[mt][r] += __shfl_xor(ls1[mt][r], m);
        ls2[mt][r] += __shfl_xor(ls2[mt][r], m);
      }
  // cross-wave partials: wave-partial (64-col) sums per row -> LDS [wn][row]
  if ((lane & 15) == 0) {
    int g = lane >> 4;
#pragma unroll
    for (int mt = 0; mt < 4; ++mt)
#pragma unroll
      for (int r = 0; r < 4; ++r) {
        int rl = wm * 64 + mt * 16 + g * 4 + r;
        red1[wn][rl] = ls1[mt][r];
        red2[wn][rl] = ls2[mt][r];
      }
  }
  __syncthreads();
  const int rsub = (lane >> 4) * 4;
  const int csub = lane & 15;
  float gv[4], bv[4];
#pragma unroll
  for (int nt = 0; nt < 4; ++nt) {
    int col = wn * 64 + nt * 16 + csub;
    gv[nt] = gamma[bx * ADP + col];
    bv[nt] = beta[bx * ADP + col];
  }
#pragma unroll
  for (int mt = 0; mt < 4; ++mt) {
#pragma unroll
    for (int r = 0; r < 4; ++r) {
      int rl = wm * 64 + mt * 16 + rsub + r;
      long row = rowBase + rl;
      if (route[row] != bx) continue;  // another block owns this token
      float t1 = red1[0][rl] + red1[1][rl] + red1[2][rl] + red1[3][rl];
      float t2 = red2[0][rl] + red2[1][rl] + red2[2][rl] + red2[3][rl];
      float mu = t1 * (1.0f / ADP);
      float var = t2 * (1.0f / ADP) - mu * mu;
      float rstd = rsqrtf(var + 1e-5f);
#pragma unroll
      for (int nt = 0; nt < 4; ++nt) {
        int col = wn * 64 + nt * 16 + csub;
        float val = (acc[mt][nt][r] - mu) * rstd * gv[nt] + bv[nt];
        haug[row * KAUG + HID + col] = f2bf(val);
      }
    }
  }
}

// ---------------------------------------------------------------------------
extern "C" void kernel_launch(void* const* d_in, const int* in_sizes, int n_in,
                              void* d_out, int out_size, void* d_ws, size_t ws_size,
                              hipStream_t stream) {
  const float* x     = (const float*)d_in[0];
  const float* ew    = (const float*)d_in[1];
  const float* W_up  = (const float*)d_in[2];
  const float* W_ad  = (const float*)d_in[3];
  const float* W_ex  = (const float*)d_in[4];
  const float* gam   = (const float*)d_in[5];
  const float* bet   = (const float*)d_in[6];
  const float* W_pr  = (const float*)d_in[7];
  const float* W_out = (const float*)d_in[8];
  float* out = (float*)d_out;

  // workspace layout (~150 MiB total)
  char* ws = (char*)d_ws;
  size_t off = 0;
  auto alloc = [&](size_t n) {
    char* p = ws + off;
    off += (n + 255) & ~(size_t)255;
    return p;
  };
  unsigned short* xb   = (unsigned short*)alloc((size_t)TOK * DEMB * 2);
  unsigned short* wub  = (unsigned short*)alloc((size_t)HID * DEMB * 2);
  unsigned short* wob  = (unsigned short*)alloc((size_t)DEMB * KAUG * 2);  // [Wout | Wcomb]
  unsigned short* wab  = (unsigned short*)alloc((size_t)ADP * HID * 2);
  unsigned short* web  = (unsigned short*)alloc((size_t)NEXP * ADP * ADP * 2);
  unsigned short* wpT  = (unsigned short*)alloc((size_t)ADP * HID * 2);    // Wproj^T bf16
  unsigned short* Haug = (unsigned short*)alloc((size_t)TOK * KAUG * 2);   // [H | anorm]
  float*          P    = (float*)alloc((size_t)4 * TOK * ADP * 4);
  float*          Pw   = (float*)alloc((size_t)8 * DEMB * ADP * 4);
  unsigned short* ab   = (unsigned short*)alloc((size_t)TOK * ADP * 2);
  int*          route  = (int*)alloc((size_t)TOK * 4);

  // 1) bf16 conversion of x + W_up + routing (only what step 2 needs)
  convert_a<<<6176, 256, 0, stream>>>(x, W_up, ew, xb, wub, route);
  // 2) fused: H = silu(x @ W_up^T) -> Haug head  +  remaining weight
  //    conversions (W_out/W_adapt/W_exp/W_proj^T) overlapped on spare CUs
  fused2<<<5120, 256, 0, stream>>>(xb, wub, Haug, W_out, W_ad, W_ex, W_pr,
                                   wob, wab, web, wpT);
  // 3) dual: A = H @ W_adapt^T (split-K=4, 512 blocks)
  //        + Wcomb = W_out @ W_proj (split-K=8, 128 blocks) in one launch
  gemm_dual<<<640, 256, 0, stream>>>(
      Haug, KAUG, wab, HID, P, ADP, HID / 4, (long)TOK * ADP, 2, 64, 512,
      wob, KAUG, wpT, HID, Pw, ADP, HID / 8, (long)DEMB * ADP, 2, 8);
  // 4) merged reductions: a partials -> bf16 ab; Wcomb partials -> wob tail
  reduce_both<<<2304, 256, 0, stream>>>(P, ab, Pw, wob);
  // 5) fused expert GEMM + LayerNorm -> bf16 anorm into Haug tail
  //    (one expert per block: bx = expert, full 256-col slice in registers)
  gemm_exp_ln<<<dim3(NEXP, TOK / 128), 512, 0, stream>>>(
      ab, web, route, gam, bet, Haug);
  // 6) out = H_aug @ [Wout | Wcomb]^T, K=4352  (gemm8p, 256 blocks = 1/CU)
  gemm8p<<<dim3(DEMB / 256, TOK / 128), 512, 0, stream>>>(
      Haug, KAUG, wob, KAUG, out, DEMB, KAUG);
}

// Round 8
// 336.034 us; speedup vs baseline: 1.1560x; 1.0026x over previous
//
#include <hip/hip_runtime.h>
#include <cstdint>

// Problem constants (fixed by reference: B=4, S=2048)
#define TOK  8192   // B*S
#define DEMB 1024   // N_EMBD
#define HID  4096   // HIDDEN
#define ADP  256    // ADAPT
#define NEXP 8
#define KAUG 4352   // HID + ADP (K-augmented out-proj)

typedef __bf16 bf16x8 __attribute__((ext_vector_type(8)));
typedef float  f32x4  __attribute__((ext_vector_type(4)));

__device__ __forceinline__ unsigned short f2bf(float f) {
  // round-to-nearest-even fp32 -> bf16 (matches numpy/jax cast for normal values)
  unsigned int u = __float_as_uint(f);
  u += 0x7fffu + ((u >> 16) & 1u);
  return (unsigned short)(u >> 16);
}
__device__ __forceinline__ float bf2f(unsigned short b) {
  return __uint_as_float(((unsigned int)b) << 16);
}

// ---------------------------------------------------------------------------
// convert_a: the conversions step-2 depends on, nothing else.
//   [0,4096)    : x chunks      [4096,6144) : W_up chunks
//   [6144,6176) : routing (last active expert, -1 if none)
// ---------------------------------------------------------------------------
__global__ __launch_bounds__(256) void convert_a(
    const float* __restrict__ x, const float* __restrict__ wup,
    const float* __restrict__ ew,
    unsigned short* __restrict__ xb, unsigned short* __restrict__ wub,
    int* __restrict__ route) {
  int b = blockIdx.x;
  if (b >= 6144) {  // routing
    int t = (b - 6144) * 256 + threadIdx.x;
    const float* p = ew + (size_t)t * NEXP;
    int r = -1;
#pragma unroll
    for (int e = 0; e < NEXP; ++e)
      if (p[e] > 0.f) r = e;
    route[t] = r;
    return;
  }
  const float* src; unsigned short* dst; int lb;
  if (b < 4096) { src = x;   dst = xb;  lb = b; }
  else          { src = wup; dst = wub; lb = b - 4096; }
  size_t base = (size_t)lb * 2048;
#pragma unroll
  for (int h = 0; h < 2; ++h) {
    size_t off = base + (size_t)h * 1024 + (size_t)threadIdx.x * 4;
    float4 v = *(const float4*)(src + off);
    ushort4 o;
    o.x = f2bf(v.x); o.y = f2bf(v.y); o.z = f2bf(v.z); o.w = f2bf(v.w);
    *(ushort4*)(dst + off) = o;
  }
}

// XCD-aware remap: raw round-robin puts one N-strip per XCD and streams all
// of A through every XCD. Remap gives each XCD a contiguous band of gy/8
// row-tiles with all col-tiles co-resident (requires gy % 8 == 0).
__device__ __forceinline__ void remap_xcd(int li, int gx, int gy,
                                          int& bx, int& by) {
  int xcd = li & 7;
  int slot = li >> 3;
  bx = slot % gx;
  by = xcd * (gy >> 3) + slot / gx;
}

#define PHASE_MID()                                       \
  __builtin_amdgcn_s_barrier();                           \
  asm volatile("s_waitcnt lgkmcnt(0)" ::: "memory");      \
  __builtin_amdgcn_sched_barrier(0);                      \
  __builtin_amdgcn_s_setprio(1)

#define PHASE_END()                                       \
  __builtin_amdgcn_s_setprio(0);                          \
  __builtin_amdgcn_sched_barrier(0);                      \
  __builtin_amdgcn_s_barrier()

#define PHASE_END_VM(N)                                   \
  __builtin_amdgcn_s_setprio(0);                          \
  __builtin_amdgcn_sched_barrier(0);                      \
  asm volatile("s_waitcnt vmcnt(" #N ")" ::: "memory");   \
  __builtin_amdgcn_s_barrier()

// ---------------------------------------------------------------------------
// 128x128x(BK=64) bf16 MFMA GEMM body, C[m,n] = sum_k A[m,k]*B[n,k] (B^T).
// m97 structure: global_load_lds width-16 staging, XOR-swizzled LDS, 4 waves
// in 2x2 grid, 4x4 16x16x32 tiles/wave, multi-block/CU TLP (measured ~875 TF).
// EPI: 0 = silu -> bf16, 1 = fp32 store (+split-K offset).
// ---------------------------------------------------------------------------
__device__ __forceinline__ void stage_tile(const unsigned short* __restrict__ g,
                                           int ldg, unsigned short* lds,
                                           int wave, int lane) {
  int srow = lane >> 3;
  int scol = ((lane & 7) ^ (srow & 7)) * 8;
#pragma unroll
  for (int c = 0; c < 4; ++c) {
    int chunk = wave * 4 + c;
    const unsigned short* gp = g + (size_t)(chunk * 8 + srow) * ldg + scol;
    unsigned short* lp = lds + chunk * 512;
    __builtin_amdgcn_global_load_lds(
        (const __attribute__((address_space(1))) unsigned int*)(uintptr_t)gp,
        (__attribute__((address_space(3))) unsigned int*)(uintptr_t)lp,
        16, 0, 0);
  }
}

template <int EPI>
__device__ __forceinline__ void gemm_body(
    int bxr, int byr, int bz,
    const unsigned short* __restrict__ A, int lda,
    const unsigned short* __restrict__ B, int ldb,
    void* __restrict__ C, int ldc, int kLen, long splitStride,
    unsigned short* As, unsigned short* Bs) {
  const int lane = threadIdx.x & 63;
  const int wave = threadIdx.x >> 6;
  const int wm = wave >> 1, wn = wave & 1;
  const long rowBase = (long)byr * 128;
  const long colBase = (long)bxr * 128;
  const int ks = bz * kLen;
  const unsigned short* Ap = A + rowBase * lda + ks;
  const unsigned short* Bp = B + colBase * ldb + ks;
  f32x4 acc[4][4] = {};

  for (int kt = 0; kt < kLen; kt += 64) {
    stage_tile(Ap + kt, lda, As, wave, lane);
    stage_tile(Bp + kt, ldb, Bs, wave, lane);
    __syncthreads();
#pragma unroll
    for (int kk = 0; kk < 64; kk += 32) {
      const int kb = (kk >> 3) + (lane >> 4);   // k-block 0..7
      const int sw = kb ^ (lane & 7);           // swizzled k-block
      bf16x8 af[4], bfr[4];
#pragma unroll
      for (int mt = 0; mt < 4; ++mt) {
        int m = wm * 64 + mt * 16 + (lane & 15);
        af[mt] = *(const bf16x8*)&As[m * 64 + sw * 8];
      }
#pragma unroll
      for (int nt = 0; nt < 4; ++nt) {
        int n = wn * 64 + nt * 16 + (lane & 15);
        bfr[nt] = *(const bf16x8*)&Bs[n * 64 + sw * 8];
      }
#pragma unroll
      for (int mt = 0; mt < 4; ++mt)
#pragma unroll
        for (int nt = 0; nt < 4; ++nt)
          acc[mt][nt] = __builtin_amdgcn_mfma_f32_16x16x32_bf16(
              af[mt], bfr[nt], acc[mt][nt], 0, 0, 0);
    }
    __syncthreads();
  }

  // Epilogue. C/D layout (m89-verified): col = lane&15, row = (lane>>4)*4 + r.
  const int rsub = (lane >> 4) * 4;
  const int csub = lane & 15;
#pragma unroll
  for (int mt = 0; mt < 4; ++mt) {
#pragma unroll
    for (int nt = 0; nt < 4; ++nt) {
      long col = colBase + wn * 64 + nt * 16 + csub;
#pragma unroll
      for (int r = 0; r < 4; ++r) {
        long row = rowBase + wm * 64 + mt * 16 + rsub + r;
        float v = acc[mt][nt][r];
        if (EPI == 0) {
          float s = __fdividef(v, 1.0f + __expf(-v));  // silu
          ((unsigned short*)C)[row * ldc + col] = f2bf(s);
        } else {
          ((float*)C + splitStride * bz)[row * ldc + col] = v;
        }
      }
    }
  }
}

// ---------------------------------------------------------------------------
// fused2: block-range dispatch, one launch.
//   [0,2048)    : step-2 GEMM  H = silu(x @ W_up^T) -> Haug cols [0,4096)
//   [2048,4096) : W_out fp32 -> bf16 (strided into wob head)
//   [4096,4608) : W_adapt -> wab       [4608,4864) : W_exp -> web
//   [4864,5120) : transpose-convert W_proj -> wpT
// Conversions (~50 MB of traffic) overlap the compute-bound GEMM for free.
// Measured R7: 93 us, 2.95 TB/s, MfmaUtil 32%.
// ---------------------------------------------------------------------------
__global__ __launch_bounds__(256, 3) void fused2(
    const unsigned short* __restrict__ xb, const unsigned short* __restrict__ wub,
    unsigned short* __restrict__ haug,
    const float* __restrict__ wout, const float* __restrict__ wadapt,
    const float* __restrict__ wexp, const float* __restrict__ wp,
    unsigned short* __restrict__ wob, unsigned short* __restrict__ wab,
    unsigned short* __restrict__ web, unsigned short* __restrict__ wpT) {
  __shared__ char smem[32768];
  int li = blockIdx.x;
  if (li < 2048) {  // step-2 GEMM
    int bx, by;
    remap_xcd(li, 32, 64, bx, by);
    gemm_body<0>(bx, by, 0, xb, DEMB, wub, DEMB, haug, KAUG, DEMB, 0,
                 (unsigned short*)smem, (unsigned short*)(smem + 16384));
    return;
  }
  int cb = li - 2048;
  if (cb < 2816) {  // linear conversions
    const float* src; unsigned short* dst; int lb; bool strided = false;
    if (cb < 2048)      { src = wout;   dst = wob; lb = cb;        strided = true; }
    else if (cb < 2560) { src = wadapt; dst = wab; lb = cb - 2048; }
    else                { src = wexp;   dst = web; lb = cb - 2560; }
    size_t base = (size_t)lb * 2048;
#pragma unroll
    for (int h = 0; h < 2; ++h) {
      size_t off = base + (size_t)h * 1024 + (size_t)threadIdx.x * 4;
      float4 v = *(const float4*)(src + off);
      ushort4 o;
      o.x = f2bf(v.x); o.y = f2bf(v.y); o.z = f2bf(v.z); o.w = f2bf(v.w);
      size_t doff = strided ? (off >> 12) * KAUG + (off & 4095) : off;
      *(ushort4*)(dst + doff) = o;
    }
    return;
  }
  // Wproj transpose: 64x64 LDS tiles, pad 65 (2-way = free)
  float (*tile)[65] = (float(*)[65])smem;  // 64*65*4 = 16640 B <= 32768
  int wli = cb - 2816;
  const int h0 = (wli & 63) * 64;  // over 4096
  const int a0 = (wli >> 6) * 64;  // over 256
  const int t = threadIdx.x;
  const int r = t >> 4;            // 0..15
  const int c = (t & 15) * 4;      // 0..60
#pragma unroll
  for (int p = 0; p < 4; ++p) {
    int row = p * 16 + r;
    float4 v = *(const float4*)(wp + (size_t)(h0 + row) * ADP + a0 + c);
    tile[c + 0][row] = v.x;
    tile[c + 1][row] = v.y;
    tile[c + 2][row] = v.z;
    tile[c + 3][row] = v.w;
  }
  __syncthreads();
#pragma unroll
  for (int q = 0; q < 2; ++q) {
    int idx = q * 256 + t;
    int al = idx >> 3;             // a local 0..63
    int hg = (idx & 7) * 8;        // h local 0,8,..,56
    unsigned int w0 = (unsigned int)f2bf(tile[al][hg + 0]) |
                      ((unsigned int)f2bf(tile[al][hg + 1]) << 16);
    unsigned int w1 = (unsigned int)f2bf(tile[al][hg + 2]) |
                      ((unsigned int)f2bf(tile[al][hg + 3]) << 16);
    unsigned int w2 = (unsigned int)f2bf(tile[al][hg + 4]) |
                      ((unsigned int)f2bf(tile[al][hg + 5]) << 16);
    unsigned int w3 = (unsigned int)f2bf(tile[al][hg + 6]) |
                      ((unsigned int)f2bf(tile[al][hg + 7]) << 16);
    *(uint4*)(wpT + (size_t)(a0 + al) * HID + h0 + hg) =
        make_uint4(w0, w1, w2, w3);
  }
}

// ===========================================================================
// gemm_n256: BM=128 x BN=256 (full output width, gx=1 -> A streamed ONCE),
// 8 waves (2m x 4n, per-wave 64x64), m97 single-buffer K-loop, fp32 split-K
// store. Replaces the 128-wide dual body: adapt-path HBM traffic 192->128 MB.
// Block-range dual launch:
//   [0,nb0)   : A-GEMM  P[z] = Haug(head) @ wab^T   (z = li>>6, 64 row-tiles)
//   [nb0,..)  : Wcomb   Pw[z] = wob(head) @ wpT^T   (z = wli>>3, 8 row-tiles)
// ===========================================================================
__global__ __launch_bounds__(512, 4) void gemm_n256(
    const unsigned short* __restrict__ A0, int lda0,
    const unsigned short* __restrict__ B0, int ldb0,
    float* __restrict__ C0, int kLen0, long ss0, int nb0,
    const unsigned short* __restrict__ A1, int lda1,
    const unsigned short* __restrict__ B1, int ldb1,
    float* __restrict__ C1, int kLen1, long ss1) {
  __shared__ unsigned short As[128 * 64];
  __shared__ unsigned short Bs[256 * 64];
  const int lane = threadIdx.x & 63;
  const int wave = threadIdx.x >> 6;      // 0..7
  const int wm = wave >> 2, wn = wave & 3;
  int li = blockIdx.x;
  const unsigned short *A, *B;
  float* C;
  int lda, ldb, kLen, bz;
  long ss, rowBase;
  if (li < nb0) {
    bz = li >> 6;
    int bx, by;
    remap_xcd(li & 63, 1, 64, bx, by);
    A = A0; lda = lda0; B = B0; ldb = ldb0; C = C0; kLen = kLen0; ss = ss0;
    rowBase = (long)by * 128;
  } else {
    int wli = li - nb0;
    bz = wli >> 3;
    A = A1; lda = lda1; B = B1; ldb = ldb1; C = C1; kLen = kLen1; ss = ss1;
    rowBase = (long)(wli & 7) * 128;
  }
  const unsigned short* Ap = A + rowBase * lda + (size_t)bz * kLen;
  const unsigned short* Bp = B + (size_t)bz * kLen;
  const int srow = lane >> 3;
  const int scol = ((lane & 7) ^ (srow & 7)) * 8;
  f32x4 acc[4][4] = {};

  for (int kt = 0; kt < kLen; kt += 64) {
    // stage A tile (128x64): 16 chunks, 2/wave
#pragma unroll
    for (int c = 0; c < 2; ++c) {
      int chunk = wave * 2 + c;
      __builtin_amdgcn_global_load_lds(
          (const __attribute__((address_space(1))) unsigned int*)(uintptr_t)(
              Ap + (size_t)(chunk * 8 + srow) * lda + kt + scol),
          (__attribute__((address_space(3))) unsigned int*)(uintptr_t)(
              As + chunk * 512),
          16, 0, 0);
    }
    // stage B tile (256x64): 32 chunks, 4/wave
#pragma unroll
    for (int c = 0; c < 4; ++c) {
      int chunk = wave * 4 + c;
      __builtin_amdgcn_global_load_lds(
          (const __attribute__((address_space(1))) unsigned int*)(uintptr_t)(
              Bp + (size_t)(chunk * 8 + srow) * ldb + kt + scol),
          (__attribute__((address_space(3))) unsigned int*)(uintptr_t)(
              Bs + chunk * 512),
          16, 0, 0);
    }
    __syncthreads();
#pragma unroll
    for (int kk = 0; kk < 64; kk += 32) {
      const int kb = (kk >> 3) + (lane >> 4);
      const int sw = kb ^ (lane & 7);
      bf16x8 af[4], bfr[4];
#pragma unroll
      for (int mt = 0; mt < 4; ++mt) {
        int m = wm * 64 + mt * 16 + (lane & 15);
        af[mt] = *(const bf16x8*)&As[m * 64 + sw * 8];
      }
#pragma unroll
      for (int nt = 0; nt < 4; ++nt) {
        int n = wn * 64 + nt * 16 + (lane & 15);
        bfr[nt] = *(const bf16x8*)&Bs[n * 64 + sw * 8];
      }
#pragma unroll
      for (int mt = 0; mt < 4; ++mt)
#pragma unroll
        for (int nt = 0; nt < 4; ++nt)
          acc[mt][nt] = __builtin_amdgcn_mfma_f32_16x16x32_bf16(
              af[mt], bfr[nt], acc[mt][nt], 0, 0, 0);
    }
    __syncthreads();
  }

  // Epilogue: fp32 split-K store, ldc = ADP.
  const int rsub = (lane >> 4) * 4;
  const int csub = lane & 15;
  float* Cz = C + ss * bz;
#pragma unroll
  for (int mt = 0; mt < 4; ++mt) {
#pragma unroll
    for (int nt = 0; nt < 4; ++nt) {
      long col = wn * 64 + nt * 16 + csub;
#pragma unroll
      for (int r = 0; r < 4; ++r) {
        long row = rowBase + wm * 64 + mt * 16 + rsub + r;
        Cz[row * ADP + col] = acc[mt][nt][r];
      }
    }
  }
}

// ===========================================================================
// gemm8p: BM=128/BN=256 8-wave 4-phase kernel with counted vmcnt. Step 7
// (K=4352, 256 blocks = 1/CU): measured ~84 us. Kept for the deep-K
// out-projection.
// ===========================================================================
__device__ __forceinline__ void read_frag4(const unsigned short* base, int lane,
                                           int rowoff, int kk, bf16x8* dst) {
#pragma unroll
  for (int i = 0; i < 4; ++i) {
    int rr = rowoff + i * 16 + (lane & 15);
    int sw = ((kk >> 3) + (lane >> 4)) ^ (lane & 7);  // rr&7 == lane&7
    dst[i] = *(const bf16x8*)&base[rr * 64 + sw * 8];
  }
}

template <int NH>
__device__ __forceinline__ void mfma8(const bf16x8* af, const bf16x8* bf,
                                      f32x4 acc[4][4]) {
#pragma unroll
  for (int mt = 0; mt < 4; ++mt)
#pragma unroll
    for (int q = 0; q < 2; ++q)
      acc[mt][NH * 2 + q] = __builtin_amdgcn_mfma_f32_16x16x32_bf16(
          af[mt], bf[NH * 2 + q], acc[mt][NH * 2 + q], 0, 0, 0);
}

__global__ __launch_bounds__(512, 2) void gemm8p(
    const unsigned short* __restrict__ A, int lda,
    const unsigned short* __restrict__ B, int ldb,
    float* __restrict__ C, int ldc, int kLen) {
  __shared__ unsigned short As[2][128 * 64];
  __shared__ unsigned short Bs[2][256 * 64];
  const int lane = threadIdx.x & 63;
  const int wave = threadIdx.x >> 6;      // 0..7
  const int wm = wave >> 2, wn = wave & 3;
  int li = blockIdx.x + gridDim.x * blockIdx.y;
  int bx, by;
  remap_xcd(li, gridDim.x, gridDim.y, bx, by);
  const long rowBase = (long)by * 128;
  const long colBase = (long)bx * 256;
  const int srow = lane >> 3;
  const int scol = ((lane & 7) ^ (srow & 7)) * 8;  // pre-swizzled global src
  const unsigned short* Ag = A + (rowBase + srow) * (long)lda + scol;
  const unsigned short* Bg = B + (colBase + srow) * (long)ldb + scol;
  const int NT = kLen >> 6;

  auto stA = [&](int buf, int t) {  // whole A tile: 16 chunks, 2/wave
#pragma unroll
    for (int c = 0; c < 2; ++c) {
      int chunk = wave * 2 + c;
      __builtin_amdgcn_global_load_lds(
          (const __attribute__((address_space(1))) unsigned int*)(uintptr_t)(
              Ag + (size_t)chunk * 8 * lda + (size_t)t * 64),
          (__attribute__((address_space(3))) unsigned int*)(uintptr_t)(
              &As[buf][chunk * 512]),
          16, 0, 0);
    }
  };
  auto stB = [&](int buf, int t, int h) {  // B half-tile: 16 chunks, 2/wave
#pragma unroll
    for (int c = 0; c < 2; ++c) {
      int chunk = h * 16 + wave * 2 + c;
      __builtin_amdgcn_global_load_lds(
          (const __attribute__((address_space(1))) unsigned int*)(uintptr_t)(
              Bg + (size_t)chunk * 8 * ldb + (size_t)t * 64),
          (__attribute__((address_space(3))) unsigned int*)(uintptr_t)(
              &Bs[buf][chunk * 512]),
          16, 0, 0);
    }
  };

  f32x4 acc[4][4] = {};
  bf16x8 af0[4], af1[4], bf0[4], bf1[4];

  // prologue: tile0 (B halves + A), then the D(-1) stages for tile1
  stB(0, 0, 0);
  stB(0, 0, 1);
  stA(0, 0);
  if (NT > 1) {
    stA(1, 1);
    stB(1, 1, 0);
    asm volatile("s_waitcnt vmcnt(4)" ::: "memory");  // tile0 landed
  } else {
    asm volatile("s_waitcnt vmcnt(0)" ::: "memory");
  }
  __builtin_amdgcn_s_barrier();
  read_frag4(&As[0][0], lane, wm * 64, 0, af0);

  for (int t = 0; t < NT; ++t) {
    const int b = t & 1;
    // ---- phase A: bfr[t,kk0]; stage Bh[t+1][1]
    read_frag4(&Bs[b][0], lane, wn * 64, 0, bf0);
    if (t + 1 < NT) stB(b ^ 1, t + 1, 1);
    PHASE_MID();
    mfma8<0>(af0, bf0, acc);
    PHASE_END();
    // ---- phase B: af[t,kk1]
    read_frag4(&As[b][0], lane, wm * 64, 32, af1);
    PHASE_MID();
    mfma8<1>(af0, bf0, acc);
    PHASE_END();
    // ---- phase C: bfr[t,kk1]; vmcnt(4) -> A[t+1] landed for phase D's read
    read_frag4(&Bs[b][0], lane, wn * 64, 32, bf1);
    PHASE_MID();
    mfma8<0>(af1, bf1, acc);
    PHASE_END_VM(4);
    // ---- phase D: af[t+1,kk0]; stage A[t+2] + Bh[t+2][0];
    //      vmcnt(4) -> Bh[t+1][0,1] landed for next phase A's read
    if (t + 1 < NT) read_frag4(&As[b ^ 1][0], lane, wm * 64, 0, af0);
    if (t + 2 < NT) { stA(b, t + 2); stB(b, t + 2, 0); }
    PHASE_MID();
    mfma8<1>(af1, bf1, acc);
    PHASE_END_VM(4);
  }

  // Epilogue (fp32 store).
  const int rsub = (lane >> 4) * 4;
  const int csub = lane & 15;
#pragma unroll
  for (int mt = 0; mt < 4; ++mt) {
#pragma unroll
    for (int nt = 0; nt < 4; ++nt) {
      long col = colBase + wn * 64 + nt * 16 + csub;
#pragma unroll
      for (int r = 0; r < 4; ++r) {
        long row = rowBase + wm * 64 + mt * 16 + rsub + r;
        C[row * ldc + col] = acc[mt][nt][r];
      }
    }
  }
}

// ---------------------------------------------------------------------------
// Merged elementwise reductions (block-range dispatch):
//   [0,2048)    : sum 4 split-K fp32 partials of A -> bf16 ab
//   [2048,2304) : sum 8 split-K fp32 partials of Wcomb, x0.1 -> bf16 tail of wob
// ---------------------------------------------------------------------------
__global__ __launch_bounds__(256) void reduce_both(
    const float* __restrict__ P, unsigned short* __restrict__ ab,
    const float* __restrict__ Pw, unsigned short* __restrict__ wob) {
  int b = blockIdx.x;
  if (b < 2048) {
    size_t i = ((size_t)b * 256 + threadIdx.x) * 4;
    const size_t stride = (size_t)TOK * ADP;
    float4 p0 = *(const float4*)(P + i);
    float4 p1 = *(const float4*)(P + stride + i);
    float4 p2 = *(const float4*)(P + 2 * stride + i);
    float4 p3 = *(const float4*)(P + 3 * stride + i);
    ushort4 o;
    o.x = f2bf(p0.x + p1.x + p2.x + p3.x);
    o.y = f2bf(p0.y + p1.y + p2.y + p3.y);
    o.z = f2bf(p0.z + p1.z + p2.z + p3.z);
    o.w = f2bf(p0.w + p1.w + p2.w + p3.w);
    *(ushort4*)(ab + i) = o;
  } else {
    size_t i = ((size_t)(b - 2048) * 256 + threadIdx.x) * 4;  // over 1024*256
    const size_t stride = (size_t)DEMB * ADP;
    float4 s = *(const float4*)(Pw + i);
#pragma unroll
    for (int k = 1; k < 8; ++k) {
      float4 p = *(const float4*)(Pw + k * stride + i);
      s.x += p.x; s.y += p.y; s.z += p.z; s.w += p.w;
    }
    size_t d = i >> 8, a = i & 255;
    ushort4 o;
    o.x = f2bf(0.1f * s.x); o.y = f2bf(0.1f * s.y);
    o.z = f2bf(0.1f * s.z); o.w = f2bf(0.1f * s.w);
    *(ushort4*)(wob + d * KAUG + HID + a) = o;
  }
}

// ===========================================================================
// gemm_exp_ln: fused expert-adapter GEMM + per-token LayerNorm.
// BM=128, BN=256 = ONE expert's full adapter slice per block (bx = expert).
// 8 waves (2m x 4n), per-wave 64x64, m97 single-buffer K-loop (K=256, NT=4).
// After the K-loop each block holds complete 256-wide a_all rows for expert
// bx in registers: rows routed to bx get LN (shfl over 16 lanes + 4-wave LDS
// reduce) and bf16 anorm written straight into Haug tail cols [4096,4352).
// (512,4): LDS 52KB -> 2 blocks/CU resident (512-block grid in one round).
// ===========================================================================
__global__ __launch_bounds__(512, 4) void gemm_exp_ln(
    const unsigned short* __restrict__ A,     // ab [TOK][ADP]
    const unsigned short* __restrict__ Wexp,  // web [NEXP][ADP][ADP]
    const int* __restrict__ route,
    const float* __restrict__ gamma, const float* __restrict__ beta,
    unsigned short* __restrict__ haug) {
  __shared__ unsigned short As[128 * 64];
  __shared__ unsigned short Bs[256 * 64];
  __shared__ float red1[4][128];
  __shared__ float red2[4][128];
  const int lane = threadIdx.x & 63;
  const int wave = threadIdx.x >> 6;      // 0..7
  const int wm = wave >> 2, wn = wave & 3;
  int li = blockIdx.x + gridDim.x * blockIdx.y;
  int bx, by;
  remap_xcd(li, gridDim.x, gridDim.y, bx, by);
  const long rowBase = (long)by * 128;
  const unsigned short* Ap = A + rowBase * ADP;
  const unsigned short* Bp = Wexp + (size_t)bx * ADP * ADP;
  const int srow = lane >> 3;
  const int scol = ((lane & 7) ^ (srow & 7)) * 8;
  f32x4 acc[4][4] = {};

  for (int kt = 0; kt < ADP; kt += 64) {
    // stage A tile (128x64): 16 chunks, 2/wave
#pragma unroll
    for (int c = 0; c < 2; ++c) {
      int chunk = wave * 2 + c;
      __builtin_amdgcn_global_load_lds(
          (const __attribute__((address_space(1))) unsigned int*)(uintptr_t)(
              Ap + (size_t)(chunk * 8 + srow) * ADP + kt + scol),
          (__attribute__((address_space(3))) unsigned int*)(uintptr_t)(
              As + chunk * 512),
          16, 0, 0);
    }
    // stage B tile (256x64): 32 chunks, 4/wave
#pragma unroll
    for (int c = 0; c < 4; ++c) {
      int chunk = wave * 4 + c;
      __builtin_amdgcn_global_load_lds(
          (const __attribute__((address_space(1))) unsigned int*)(uintptr_t)(
              Bp + (size_t)(chunk * 8 + srow) * ADP + kt + scol),
          (__attribute__((address_space(3))) unsigned int*)(uintptr_t)(
              Bs + chunk * 512),
          16, 0, 0);
    }
    __syncthreads();
#pragma unroll
    for (int kk = 0; kk < 64; kk += 32) {
      const int kb = (kk >> 3) + (lane >> 4);
      const int sw = kb ^ (lane & 7);
      bf16x8 af[4], bfr[4];
#pragma unroll
      for (int mt = 0; mt < 4; ++mt) {
        int m = wm * 64 + mt * 16 + (lane & 15);
        af[mt] = *(const bf16x8*)&As[m * 64 + sw * 8];
      }
#pragma unroll
      for (int nt = 0; nt < 4; ++nt) {
        int n = wn * 64 + nt * 16 + (lane & 15);
        bfr[nt] = *(const bf16x8*)&Bs[n * 64 + sw * 8];
      }
#pragma unroll
      for (int mt = 0; mt < 4; ++mt)
#pragma unroll
        for (int nt = 0; nt < 4; ++nt)
          acc[mt][nt] = __builtin_amdgcn_mfma_f32_16x16x32_bf16(
              af[mt], bfr[nt], acc[mt][nt], 0, 0, 0);
    }
    __syncthreads();
  }

  // ---- in-block LayerNorm over the 256-wide rows ----
  // Lane holds rows mt*16 + (lane>>4)*4 + r (16 rows) x cols wn*64+nt*16+(lane&15).
  float ls1[4][4], ls2[4][4];
#pragma unroll
  for (int mt = 0; mt < 4; ++mt)
#pragma unroll
    for (int r = 0; r < 4; ++r) {
      float s1 = 0.f, s2 = 0.f;
#pragma unroll
      for (int nt = 0; nt < 4; ++nt) {
        float v = acc[mt][nt][r];
        s1 += v; s2 += v * v;
      }
      ls1[mt][r] = s1; ls2[mt][r] = s2;
    }
  // reduce across the 16 lanes sharing the same rows (csub dimension)
#pragma unroll
  for (int m = 1; m < 16; m <<= 1)
#pragma unroll
    for (int mt = 0; mt < 4; ++mt)
#pragma unroll
      for (int r = 0; r < 4; ++r) {
        ls1[mt][r] += __shfl_xor(ls1[mt][r], m);
        ls2[mt][r] += __shfl_xor(ls2[mt][r], m);
      }
  // cross-wave partials: wave-partial (64-col) sums per row -> LDS [wn][row]
  if ((lane & 15) == 0) {
    int g = lane >> 4;
#pragma unroll
    for (int mt = 0; mt < 4; ++mt)
#pragma unroll
      for (int r = 0; r < 4; ++r) {
        int rl = wm * 64 + mt * 16 + g * 4 + r;
        red1[wn][rl] = ls1[mt][r];
        red2[wn][rl] = ls2[mt][r];
      }
  }
  __syncthreads();
  const int rsub = (lane >> 4) * 4;
  const int csub = lane & 15;
  float gv[4], bv[4];
#pragma unroll
  for (int nt = 0; nt < 4; ++nt) {
    int col = wn * 64 + nt * 16 + csub;
    gv[nt] = gamma[bx * ADP + col];
    bv[nt] = beta[bx * ADP + col];
  }
#pragma unroll
  for (int mt = 0; mt < 4; ++mt) {
#pragma unroll
    for (int r = 0; r < 4; ++r) {
      int rl = wm * 64 + mt * 16 + rsub + r;
      long row = rowBase + rl;
      if (route[row] != bx) continue;  // another block owns this token
      float t1 = red1[0][rl] + red1[1][rl] + red1[2][rl] + red1[3][rl];
      float t2 = red2[0][rl] + red2[1][rl] + red2[2][rl] + red2[3][rl];
      float mu = t1 * (1.0f / ADP);
      float var = t2 * (1.0f / ADP) - mu * mu;
      float rstd = rsqrtf(var + 1e-5f);
#pragma unroll
      for (int nt = 0; nt < 4; ++nt) {
        int col = wn * 64 + nt * 16 + csub;
        float val = (acc[mt][nt][r] - mu) * rstd * gv[nt] + bv[nt];
        haug[row * KAUG + HID + col] = f2bf(val);
      }
    }
  }
}

// ---------------------------------------------------------------------------
extern "C" void kernel_launch(void* const* d_in, const int* in_sizes, int n_in,
                              void* d_out, int out_size, void* d_ws, size_t ws_size,
                              hipStream_t stream) {
  const float* x     = (const float*)d_in[0];
  const float* ew    = (const float*)d_in[1];
  const float* W_up  = (const float*)d_in[2];
  const float* W_ad  = (const float*)d_in[3];
  const float* W_ex  = (const float*)d_in[4];
  const float* gam   = (const float*)d_in[5];
  const float* bet   = (const float*)d_in[6];
  const float* W_pr  = (const float*)d_in[7];
  const float* W_out = (const float*)d_in[8];
  float* out = (float*)d_out;

  // workspace layout (~150 MiB total)
  char* ws = (char*)d_ws;
  size_t off = 0;
  auto alloc = [&](size_t n) {
    char* p = ws + off;
    off += (n + 255) & ~(size_t)255;
    return p;
  };
  unsigned short* xb   = (unsigned short*)alloc((size_t)TOK * DEMB * 2);
  unsigned short* wub  = (unsigned short*)alloc((size_t)HID * DEMB * 2);
  unsigned short* wob  = (unsigned short*)alloc((size_t)DEMB * KAUG * 2);  // [Wout | Wcomb]
  unsigned short* wab  = (unsigned short*)alloc((size_t)ADP * HID * 2);
  unsigned short* web  = (unsigned short*)alloc((size_t)NEXP * ADP * ADP * 2);
  unsigned short* wpT  = (unsigned short*)alloc((size_t)ADP * HID * 2);    // Wproj^T bf16
  unsigned short* Haug = (unsigned short*)alloc((size_t)TOK * KAUG * 2);   // [H | anorm]
  float*          P    = (float*)alloc((size_t)4 * TOK * ADP * 4);
  float*          Pw   = (float*)alloc((size_t)8 * DEMB * ADP * 4);
  unsigned short* ab   = (unsigned short*)alloc((size_t)TOK * ADP * 2);
  int*          route  = (int*)alloc((size_t)TOK * 4);

  // 1) bf16 conversion of x + W_up + routing (only what step 2 needs)
  convert_a<<<6176, 256, 0, stream>>>(x, W_up, ew, xb, wub, route);
  // 2) fused: H = silu(x @ W_up^T) -> Haug head  +  remaining weight
  //    conversions (W_out/W_adapt/W_exp/W_proj^T) overlapped on spare CUs
  fused2<<<5120, 256, 0, stream>>>(xb, wub, Haug, W_out, W_ad, W_ex, W_pr,
                                   wob, wab, web, wpT);
  // 3) dual (BN=256, A streamed once): P = Haug @ wab^T (split-K=4, 256 blk)
  //    + Pw = wob @ wpT^T (split-K=8, 64 blk) in one 320-block launch
  gemm_n256<<<320, 512, 0, stream>>>(
      Haug, KAUG, wab, HID, P, HID / 4, (long)TOK * ADP, 256,
      wob, KAUG, wpT, HID, Pw, HID / 8, (long)DEMB * ADP);
  // 4) merged reductions: a partials -> bf16 ab; Wcomb partials -> wob tail
  reduce_both<<<2304, 256, 0, stream>>>(P, ab, Pw, wob);
  // 5) fused expert GEMM + LayerNorm -> bf16 anorm into Haug tail
  //    (one expert per block: bx = expert, full 256-col slice in registers)
  gemm_exp_ln<<<dim3(NEXP, TOK / 128), 512, 0, stream>>>(
      ab, web, route, gam, bet, Haug);
  // 6) out = H_aug @ [Wout | Wcomb]^T, K=4352  (gemm8p, 256 blocks = 1/CU)
  gemm8p<<<dim3(DEMB / 256, TOK / 128), 512, 0, stream>>>(
      Haug, KAUG, wob, KAUG, out, DEMB, KAUG);
}

// Round 10
// 325.917 us; speedup vs baseline: 1.1919x; 1.0310x over previous
//
#include <hip/hip_runtime.h>
#include <cstdint>

// Problem constants (fixed by reference: B=4, S=2048)
#define TOK  8192   // B*S
#define DEMB 1024   // N_EMBD
#define HID  4096   // HIDDEN
#define ADP  256    // ADAPT
#define NEXP 8
#define KAUG 4352   // HID + ADP (K-augmented out-proj)

typedef __bf16 bf16x8 __attribute__((ext_vector_type(8)));
typedef float  f32x4  __attribute__((ext_vector_type(4)));

__device__ __forceinline__ unsigned short f2bf(float f) {
  // round-to-nearest-even fp32 -> bf16 (matches numpy/jax cast for normal values)
  unsigned int u = __float_as_uint(f);
  u += 0x7fffu + ((u >> 16) & 1u);
  return (unsigned short)(u >> 16);
}
__device__ __forceinline__ float bf2f(unsigned short b) {
  return __uint_as_float(((unsigned int)b) << 16);
}

// ---------------------------------------------------------------------------
// convert_a: the conversions step-2 depends on, nothing else.
//   [0,4096)    : x chunks      [4096,6144) : W_up chunks
//   [6144,6176) : routing (last active expert, -1 if none)
// ---------------------------------------------------------------------------
__global__ __launch_bounds__(256) void convert_a(
    const float* __restrict__ x, const float* __restrict__ wup,
    const float* __restrict__ ew,
    unsigned short* __restrict__ xb, unsigned short* __restrict__ wub,
    int* __restrict__ route) {
  int b = blockIdx.x;
  if (b >= 6144) {  // routing
    int t = (b - 6144) * 256 + threadIdx.x;
    const float* p = ew + (size_t)t * NEXP;
    int r = -1;
#pragma unroll
    for (int e = 0; e < NEXP; ++e)
      if (p[e] > 0.f) r = e;
    route[t] = r;
    return;
  }
  const float* src; unsigned short* dst; int lb;
  if (b < 4096) { src = x;   dst = xb;  lb = b; }
  else          { src = wup; dst = wub; lb = b - 4096; }
  size_t base = (size_t)lb * 2048;
#pragma unroll
  for (int h = 0; h < 2; ++h) {
    size_t off = base + (size_t)h * 1024 + (size_t)threadIdx.x * 4;
    float4 v = *(const float4*)(src + off);
    ushort4 o;
    o.x = f2bf(v.x); o.y = f2bf(v.y); o.z = f2bf(v.z); o.w = f2bf(v.w);
    *(ushort4*)(dst + off) = o;
  }
}

// XCD-aware remap: raw round-robin puts one N-strip per XCD and streams all
// of A through every XCD. Remap gives each XCD a contiguous band of gy/8
// row-tiles with all col-tiles co-resident (requires gy % 8 == 0).
__device__ __forceinline__ void remap_xcd(int li, int gx, int gy,
                                          int& bx, int& by) {
  int xcd = li & 7;
  int slot = li >> 3;
  bx = slot % gx;
  by = xcd * (gy >> 3) + slot / gx;
}

#define PHASE_MID()                                       \
  __builtin_amdgcn_s_barrier();                           \
  asm volatile("s_waitcnt lgkmcnt(0)" ::: "memory");      \
  __builtin_amdgcn_sched_barrier(0);                      \
  __builtin_amdgcn_s_setprio(1)

#define PHASE_END_VM(N)                                   \
  __builtin_amdgcn_s_setprio(0);                          \
  __builtin_amdgcn_sched_barrier(0);                      \
  asm volatile("s_waitcnt vmcnt(" #N ")" ::: "memory");   \
  __builtin_amdgcn_s_barrier()

// ---------------------------------------------------------------------------
// 128x128x(BK=64) bf16 MFMA GEMM body, C[m,n] = sum_k A[m,k]*B[n,k] (B^T).
// m97 structure: global_load_lds width-16 staging, XOR-swizzled LDS, 4 waves
// in 2x2 grid, 4x4 16x16x32 tiles/wave, multi-block/CU TLP (measured ~875 TF).
// EPI: 0 = silu -> bf16, 1 = fp32 store (+split-K offset).
// ---------------------------------------------------------------------------
__device__ __forceinline__ void stage_tile(const unsigned short* __restrict__ g,
                                           int ldg, unsigned short* lds,
                                           int wave, int lane) {
  int srow = lane >> 3;
  int scol = ((lane & 7) ^ (srow & 7)) * 8;
#pragma unroll
  for (int c = 0; c < 4; ++c) {
    int chunk = wave * 4 + c;
    const unsigned short* gp = g + (size_t)(chunk * 8 + srow) * ldg + scol;
    unsigned short* lp = lds + chunk * 512;
    __builtin_amdgcn_global_load_lds(
        (const __attribute__((address_space(1))) unsigned int*)(uintptr_t)gp,
        (__attribute__((address_space(3))) unsigned int*)(uintptr_t)lp,
        16, 0, 0);
  }
}

template <int EPI>
__device__ __forceinline__ void gemm_body(
    int bxr, int byr, int bz,
    const unsigned short* __restrict__ A, int lda,
    const unsigned short* __restrict__ B, int ldb,
    void* __restrict__ C, int ldc, int kLen, long splitStride,
    unsigned short* As, unsigned short* Bs) {
  const int lane = threadIdx.x & 63;
  const int wave = threadIdx.x >> 6;
  const int wm = wave >> 1, wn = wave & 1;
  const long rowBase = (long)byr * 128;
  const long colBase = (long)bxr * 128;
  const int ks = bz * kLen;
  const unsigned short* Ap = A + rowBase * lda + ks;
  const unsigned short* Bp = B + colBase * ldb + ks;
  f32x4 acc[4][4] = {};

  for (int kt = 0; kt < kLen; kt += 64) {
    stage_tile(Ap + kt, lda, As, wave, lane);
    stage_tile(Bp + kt, ldb, Bs, wave, lane);
    __syncthreads();
#pragma unroll
    for (int kk = 0; kk < 64; kk += 32) {
      const int kb = (kk >> 3) + (lane >> 4);   // k-block 0..7
      const int sw = kb ^ (lane & 7);           // swizzled k-block
      bf16x8 af[4], bfr[4];
#pragma unroll
      for (int mt = 0; mt < 4; ++mt) {
        int m = wm * 64 + mt * 16 + (lane & 15);
        af[mt] = *(const bf16x8*)&As[m * 64 + sw * 8];
      }
#pragma unroll
      for (int nt = 0; nt < 4; ++nt) {
        int n = wn * 64 + nt * 16 + (lane & 15);
        bfr[nt] = *(const bf16x8*)&Bs[n * 64 + sw * 8];
      }
#pragma unroll
      for (int mt = 0; mt < 4; ++mt)
#pragma unroll
        for (int nt = 0; nt < 4; ++nt)
          acc[mt][nt] = __builtin_amdgcn_mfma_f32_16x16x32_bf16(
              af[mt], bfr[nt], acc[mt][nt], 0, 0, 0);
    }
    __syncthreads();
  }

  // Epilogue. C/D layout (m89-verified): col = lane&15, row = (lane>>4)*4 + r.
  const int rsub = (lane >> 4) * 4;
  const int csub = lane & 15;
#pragma unroll
  for (int mt = 0; mt < 4; ++mt) {
#pragma unroll
    for (int nt = 0; nt < 4; ++nt) {
      long col = colBase + wn * 64 + nt * 16 + csub;
#pragma unroll
      for (int r = 0; r < 4; ++r) {
        long row = rowBase + wm * 64 + mt * 16 + rsub + r;
        float v = acc[mt][nt][r];
        if (EPI == 0) {
          float s = __fdividef(v, 1.0f + __expf(-v));  // silu
          ((unsigned short*)C)[row * ldc + col] = f2bf(s);
        } else {
          ((float*)C + splitStride * bz)[row * ldc + col] = v;
        }
      }
    }
  }
}

// ---------------------------------------------------------------------------
// fused2: block-range dispatch, one launch.
//   [0,2048)    : step-2 GEMM  H = silu(x @ W_up^T) -> Haug cols [0,4096)
//   [2048,4096) : W_out fp32 -> bf16 (strided into wob head)
//   [4096,4608) : W_adapt -> wab       [4608,4864) : W_exp -> web
//   [4864,5120) : transpose-convert W_proj -> wpT
// Conversions (~50 MB of traffic) overlap the compute-bound GEMM for free.
// Measured R8: 90.3 us, 3.05 TB/s, MfmaUtil 33%.
// ---------------------------------------------------------------------------
__global__ __launch_bounds__(256, 3) void fused2(
    const unsigned short* __restrict__ xb, const unsigned short* __restrict__ wub,
    unsigned short* __restrict__ haug,
    const float* __restrict__ wout, const float* __restrict__ wadapt,
    const float* __restrict__ wexp, const float* __restrict__ wp,
    unsigned short* __restrict__ wob, unsigned short* __restrict__ wab,
    unsigned short* __restrict__ web, unsigned short* __restrict__ wpT) {
  __shared__ char smem[32768];
  int li = blockIdx.x;
  if (li < 2048) {  // step-2 GEMM
    int bx, by;
    remap_xcd(li, 32, 64, bx, by);
    gemm_body<0>(bx, by, 0, xb, DEMB, wub, DEMB, haug, KAUG, DEMB, 0,
                 (unsigned short*)smem, (unsigned short*)(smem + 16384));
    return;
  }
  int cb = li - 2048;
  if (cb < 2816) {  // linear conversions
    const float* src; unsigned short* dst; int lb; bool strided = false;
    if (cb < 2048)      { src = wout;   dst = wob; lb = cb;        strided = true; }
    else if (cb < 2560) { src = wadapt; dst = wab; lb = cb - 2048; }
    else                { src = wexp;   dst = web; lb = cb - 2560; }
    size_t base = (size_t)lb * 2048;
#pragma unroll
    for (int h = 0; h < 2; ++h) {
      size_t off = base + (size_t)h * 1024 + (size_t)threadIdx.x * 4;
      float4 v = *(const float4*)(src + off);
      ushort4 o;
      o.x = f2bf(v.x); o.y = f2bf(v.y); o.z = f2bf(v.z); o.w = f2bf(v.w);
      size_t doff = strided ? (off >> 12) * KAUG + (off & 4095) : off;
      *(ushort4*)(dst + doff) = o;
    }
    return;
  }
  // Wproj transpose: 64x64 LDS tiles, pad 65 (2-way = free)
  float (*tile)[65] = (float(*)[65])smem;  // 64*65*4 = 16640 B <= 32768
  int wli = cb - 2816;
  const int h0 = (wli & 63) * 64;  // over 4096
  const int a0 = (wli >> 6) * 64;  // over 256
  const int t = threadIdx.x;
  const int r = t >> 4;            // 0..15
  const int c = (t & 15) * 4;      // 0..60
#pragma unroll
  for (int p = 0; p < 4; ++p) {
    int row = p * 16 + r;
    float4 v = *(const float4*)(wp + (size_t)(h0 + row) * ADP + a0 + c);
    tile[c + 0][row] = v.x;
    tile[c + 1][row] = v.y;
    tile[c + 2][row] = v.z;
    tile[c + 3][row] = v.w;
  }
  __syncthreads();
#pragma unroll
  for (int q = 0; q < 2; ++q) {
    int idx = q * 256 + t;
    int al = idx >> 3;             // a local 0..63
    int hg = (idx & 7) * 8;        // h local 0,8,..,56
    unsigned int w0 = (unsigned int)f2bf(tile[al][hg + 0]) |
                      ((unsigned int)f2bf(tile[al][hg + 1]) << 16);
    unsigned int w1 = (unsigned int)f2bf(tile[al][hg + 2]) |
                      ((unsigned int)f2bf(tile[al][hg + 3]) << 16);
    unsigned int w2 = (unsigned int)f2bf(tile[al][hg + 4]) |
                      ((unsigned int)f2bf(tile[al][hg + 5]) << 16);
    unsigned int w3 = (unsigned int)f2bf(tile[al][hg + 6]) |
                      ((unsigned int)f2bf(tile[al][hg + 7]) << 16);
    *(uint4*)(wpT + (size_t)(a0 + al) * HID + h0 + hg) =
        make_uint4(w0, w1, w2, w3);
  }
}

// ===========================================================================
// gemm_n256: BM=128 x BN=256 (full output width, gx=1 -> A streamed ONCE),
// 8 waves (2m x 4n, per-wave 64x64), m97 single-buffer K-loop, fp32 split-K
// store. Block-range dual launch:
//   [0,nb0)   : A-GEMM  P[z] = Haug(head) @ wab^T   (z = li>>6, 64 row-tiles)
//   [nb0,..)  : Wcomb   Pw[z] = wob(head) @ wpT^T   (z = wli>>3, 8 row-tiles)
// ===========================================================================
__global__ __launch_bounds__(512, 4) void gemm_n256(
    const unsigned short* __restrict__ A0, int lda0,
    const unsigned short* __restrict__ B0, int ldb0,
    float* __restrict__ C0, int kLen0, long ss0, int nb0,
    const unsigned short* __restrict__ A1, int lda1,
    const unsigned short* __restrict__ B1, int ldb1,
    float* __restrict__ C1, int kLen1, long ss1) {
  __shared__ unsigned short As[128 * 64];
  __shared__ unsigned short Bs[256 * 64];
  const int lane = threadIdx.x & 63;
  const int wave = threadIdx.x >> 6;      // 0..7
  const int wm = wave >> 2, wn = wave & 3;
  int li = blockIdx.x;
  const unsigned short *A, *B;
  float* C;
  int lda, ldb, kLen, bz;
  long ss, rowBase;
  if (li < nb0) {
    bz = li >> 6;
    int bx, by;
    remap_xcd(li & 63, 1, 64, bx, by);
    A = A0; lda = lda0; B = B0; ldb = ldb0; C = C0; kLen = kLen0; ss = ss0;
    rowBase = (long)by * 128;
  } else {
    int wli = li - nb0;
    bz = wli >> 3;
    A = A1; lda = lda1; B = B1; ldb = ldb1; C = C1; kLen = kLen1; ss = ss1;
    rowBase = (long)(wli & 7) * 128;
  }
  const unsigned short* Ap = A + rowBase * lda + (size_t)bz * kLen;
  const unsigned short* Bp = B + (size_t)bz * kLen;
  const int srow = lane >> 3;
  const int scol = ((lane & 7) ^ (srow & 7)) * 8;
  f32x4 acc[4][4] = {};

  for (int kt = 0; kt < kLen; kt += 64) {
    // stage A tile (128x64): 16 chunks, 2/wave
#pragma unroll
    for (int c = 0; c < 2; ++c) {
      int chunk = wave * 2 + c;
      __builtin_amdgcn_global_load_lds(
          (const __attribute__((address_space(1))) unsigned int*)(uintptr_t)(
              Ap + (size_t)(chunk * 8 + srow) * lda + kt + scol),
          (__attribute__((address_space(3))) unsigned int*)(uintptr_t)(
              As + chunk * 512),
          16, 0, 0);
    }
    // stage B tile (256x64): 32 chunks, 4/wave
#pragma unroll
    for (int c = 0; c < 4; ++c) {
      int chunk = wave * 4 + c;
      __builtin_amdgcn_global_load_lds(
          (const __attribute__((address_space(1))) unsigned int*)(uintptr_t)(
              Bp + (size_t)(chunk * 8 + srow) * ldb + kt + scol),
          (__attribute__((address_space(3))) unsigned int*)(uintptr_t)(
              Bs + chunk * 512),
          16, 0, 0);
    }
    __syncthreads();
#pragma unroll
    for (int kk = 0; kk < 64; kk += 32) {
      const int kb = (kk >> 3) + (lane >> 4);
      const int sw = kb ^ (lane & 7);
      bf16x8 af[4], bfr[4];
#pragma unroll
      for (int mt = 0; mt < 4; ++mt) {
        int m = wm * 64 + mt * 16 + (lane & 15);
        af[mt] = *(const bf16x8*)&As[m * 64 + sw * 8];
      }
#pragma unroll
      for (int nt = 0; nt < 4; ++nt) {
        int n = wn * 64 + nt * 16 + (lane & 15);
        bfr[nt] = *(const bf16x8*)&Bs[n * 64 + sw * 8];
      }
#pragma unroll
      for (int mt = 0; mt < 4; ++mt)
#pragma unroll
        for (int nt = 0; nt < 4; ++nt)
          acc[mt][nt] = __builtin_amdgcn_mfma_f32_16x16x32_bf16(
              af[mt], bfr[nt], acc[mt][nt], 0, 0, 0);
    }
    __syncthreads();
  }

  // Epilogue: fp32 split-K store, ldc = ADP.
  const int rsub = (lane >> 4) * 4;
  const int csub = lane & 15;
  float* Cz = C + ss * bz;
#pragma unroll
  for (int mt = 0; mt < 4; ++mt) {
#pragma unroll
    for (int nt = 0; nt < 4; ++nt) {
      long col = wn * 64 + nt * 16 + csub;
#pragma unroll
      for (int r = 0; r < 4; ++r) {
        long row = rowBase + wm * 64 + mt * 16 + rsub + r;
        Cz[row * ADP + col] = acc[mt][nt][r];
      }
    }
  }
}

// ===========================================================================
// gemm8h: step-6 out-projection (K=4352, N=1024). BM=128, BN=128, 8 waves
// (2m x 4n, per-wave 64x32, acc[4][2]), double-buffered LDS 64 KB ->
// (512,4) = 2 blocks/CU TLP (the gemm128/m114 mechanism) PLUS counted-vmcnt
// prefetch (the gemm8p mechanism). Grid 8x64 = 512 blocks = exactly 2/CU.
//
// Schedule (2 phases per K-tile t, buf b=t&1). vmcnt ledger (2 loads/stage):
//  steady P0 end: {A(t+1)x2, B(t+1)x2} -> vmcnt(2) retires A(t+1).
//  steady P1 end: {B(t+1)x2, A(t+2)x2} -> vmcnt(2) retires B(t+1).
//  TAIL (t=NT-2): P1 issues no A-stage -> only B(NT-1)x2 outstanding;
//  vmcnt(2) would NOT retire it (the R9 race) -> use vmcnt(0) when no
//  stage was issued this phase. t=NT-1: both vmcnt no-ops (0 outstanding).
// Region safety: every LDS region's last read is sealed by that phase's
// MID lgkmcnt(0) + END barrier, >= 1 barrier before its restage.
// ===========================================================================
__device__ __forceinline__ void read_frag4(const unsigned short* base, int lane,
                                           int rowoff, int kk, bf16x8* dst) {
#pragma unroll
  for (int i = 0; i < 4; ++i) {
    int rr = rowoff + i * 16 + (lane & 15);
    int sw = ((kk >> 3) + (lane >> 4)) ^ (lane & 7);  // rr&7 == lane&7
    dst[i] = *(const bf16x8*)&base[rr * 64 + sw * 8];
  }
}

__device__ __forceinline__ void read_frag2(const unsigned short* base, int lane,
                                           int rowoff, int kk, bf16x8* dst) {
#pragma unroll
  for (int i = 0; i < 2; ++i) {
    int rr = rowoff + i * 16 + (lane & 15);
    int sw = ((kk >> 3) + (lane >> 4)) ^ (lane & 7);
    dst[i] = *(const bf16x8*)&base[rr * 64 + sw * 8];
  }
}

__global__ __launch_bounds__(512, 4) void gemm8h(
    const unsigned short* __restrict__ A, int lda,
    const unsigned short* __restrict__ B, int ldb,
    float* __restrict__ C, int ldc, int kLen) {
  __shared__ unsigned short As[2][128 * 64];
  __shared__ unsigned short Bs[2][128 * 64];
  const int lane = threadIdx.x & 63;
  const int wave = threadIdx.x >> 6;      // 0..7
  const int wm = wave >> 2, wn = wave & 3;
  int li = blockIdx.x + gridDim.x * blockIdx.y;
  int bx, by;
  remap_xcd(li, gridDim.x, gridDim.y, bx, by);
  const long rowBase = (long)by * 128;
  const long colBase = (long)bx * 128;
  const int srow = lane >> 3;
  const int scol = ((lane & 7) ^ (srow & 7)) * 8;  // pre-swizzled global src
  const unsigned short* Ag = A + (rowBase + srow) * (long)lda + scol;
  const unsigned short* Bg = B + (colBase + srow) * (long)ldb + scol;
  const int NT = kLen >> 6;  // 68 for K=4352

  auto st = [&](unsigned short* lds, const unsigned short* g, int t) {
    // one 128x64 tile: 16 chunks, 2/wave
#pragma unroll
    for (int c = 0; c < 2; ++c) {
      int chunk = wave * 2 + c;
      __builtin_amdgcn_global_load_lds(
          (const __attribute__((address_space(1))) unsigned int*)(uintptr_t)(
              g + (size_t)chunk * 8 * lda + (size_t)t * 64),
          (__attribute__((address_space(3))) unsigned int*)(uintptr_t)(
              lds + chunk * 512),
          16, 0, 0);
    }
  };
  auto stB2 = [&](unsigned short* lds, int t) {
#pragma unroll
    for (int c = 0; c < 2; ++c) {
      int chunk = wave * 2 + c;
      __builtin_amdgcn_global_load_lds(
          (const __attribute__((address_space(1))) unsigned int*)(uintptr_t)(
              Bg + (size_t)chunk * 8 * ldb + (size_t)t * 64),
          (__attribute__((address_space(3))) unsigned int*)(uintptr_t)(
              lds + chunk * 512),
          16, 0, 0);
    }
  };

  f32x4 acc[4][2] = {};
  bf16x8 af0[4], af1[4], bf0[2], bf1[2];

  // prologue: B(0), A(0), A(1); tile-0 landed (A(1) may fly); pre-read af0(0)
  stB2(Bs[0], 0);
  st(As[0], Ag, 0);
  if (NT > 1) {
    st(As[1], Ag, 1);
    asm volatile("s_waitcnt vmcnt(2)" ::: "memory");
  } else {
    asm volatile("s_waitcnt vmcnt(0)" ::: "memory");
  }
  __builtin_amdgcn_s_barrier();
  read_frag4(&As[0][0], lane, wm * 64, 0, af0);

  for (int t = 0; t < NT; ++t) {
    const int b = t & 1;
    // ---- P0
    read_frag2(&Bs[b][0], lane, wn * 32, 0, bf0);
    read_frag4(&As[b][0], lane, wm * 64, 32, af1);
    if (t + 1 < NT) stB2(Bs[b ^ 1], t + 1);
    PHASE_MID();
#pragma unroll
    for (int mt = 0; mt < 4; ++mt)
#pragma unroll
      for (int nt = 0; nt < 2; ++nt)
        acc[mt][nt] = __builtin_amdgcn_mfma_f32_16x16x32_bf16(
            af0[mt], bf0[nt], acc[mt][nt], 0, 0, 0);
    if (t + 1 < NT) { PHASE_END_VM(2); } else { PHASE_END_VM(0); }
    // ---- P1
    read_frag2(&Bs[b][0], lane, wn * 32, 32, bf1);
    if (t + 1 < NT) read_frag4(&As[b ^ 1][0], lane, wm * 64, 0, af0);
    if (t + 2 < NT) st(As[b], Ag, t + 2);
    PHASE_MID();
#pragma unroll
    for (int mt = 0; mt < 4; ++mt)
#pragma unroll
      for (int nt = 0; nt < 2; ++nt)
        acc[mt][nt] = __builtin_amdgcn_mfma_f32_16x16x32_bf16(
            af1[mt], bf1[nt], acc[mt][nt], 0, 0, 0);
    // TAIL FIX: when no A-stage was issued this phase, only B(t+1)x2 are in
    // flight and vmcnt(2) would not retire them before next P0's read.
    if (t + 2 < NT) { PHASE_END_VM(2); } else { PHASE_END_VM(0); }
  }

  // Epilogue (fp32 store). C/D layout: col = lane&15, row = (lane>>4)*4 + r.
  const int rsub = (lane >> 4) * 4;
  const int csub = lane & 15;
#pragma unroll
  for (int mt = 0; mt < 4; ++mt) {
#pragma unroll
    for (int nt = 0; nt < 2; ++nt) {
      long col = colBase + wn * 32 + nt * 16 + csub;
#pragma unroll
      for (int r = 0; r < 4; ++r) {
        long row = rowBase + wm * 64 + mt * 16 + rsub + r;
        C[row * ldc + col] = acc[mt][nt][r];
      }
    }
  }
}

// ---------------------------------------------------------------------------
// Merged elementwise reductions (block-range dispatch):
//   [0,2048)    : sum 4 split-K fp32 partials of A -> bf16 ab
//   [2048,2304) : sum 8 split-K fp32 partials of Wcomb, x0.1 -> bf16 tail of wob
// ---------------------------------------------------------------------------
__global__ __launch_bounds__(256) void reduce_both(
    const float* __restrict__ P, unsigned short* __restrict__ ab,
    const float* __restrict__ Pw, unsigned short* __restrict__ wob) {
  int b = blockIdx.x;
  if (b < 2048) {
    size_t i = ((size_t)b * 256 + threadIdx.x) * 4;
    const size_t stride = (size_t)TOK * ADP;
    float4 p0 = *(const float4*)(P + i);
    float4 p1 = *(const float4*)(P + stride + i);
    float4 p2 = *(const float4*)(P + 2 * stride + i);
    float4 p3 = *(const float4*)(P + 3 * stride + i);
    ushort4 o;
    o.x = f2bf(p0.x + p1.x + p2.x + p3.x);
    o.y = f2bf(p0.y + p1.y + p2.y + p3.y);
    o.z = f2bf(p0.z + p1.z + p2.z + p3.z);
    o.w = f2bf(p0.w + p1.w + p2.w + p3.w);
    *(ushort4*)(ab + i) = o;
  } else {
    size_t i = ((size_t)(b - 2048) * 256 + threadIdx.x) * 4;  // over 1024*256
    const size_t stride = (size_t)DEMB * ADP;
    float4 s = *(const float4*)(Pw + i);
#pragma unroll
    for (int k = 1; k < 8; ++k) {
      float4 p = *(const float4*)(Pw + k * stride + i);
      s.x += p.x; s.y += p.y; s.z += p.z; s.w += p.w;
    }
    size_t d = i >> 8, a = i & 255;
    ushort4 o;
    o.x = f2bf(0.1f * s.x); o.y = f2bf(0.1f * s.y);
    o.z = f2bf(0.1f * s.z); o.w = f2bf(0.1f * s.w);
    *(ushort4*)(wob + d * KAUG + HID + a) = o;
  }
}

// ===========================================================================
// gemm_exp_ln: fused expert-adapter GEMM + per-token LayerNorm.
// BM=128, BN=256 = ONE expert's full adapter slice per block (bx = expert).
// 8 waves (2m x 4n), per-wave 64x64, m97 single-buffer K-loop (K=256, NT=4).
// LN reduction is STREAMED per (mt,r) (8 live floats, not 32-float arrays)
// so the kernel fits the 128-VGPR cap of (512,4) = 2 blocks/CU without spill.
// ===========================================================================
__global__ __launch_bounds__(512, 4) void gemm_exp_ln(
    const unsigned short* __restrict__ A,     // ab [TOK][ADP]
    const unsigned short* __restrict__ Wexp,  // web [NEXP][ADP][ADP]
    const int* __restrict__ route,
    const float* __restrict__ gamma, const float* __restrict__ beta,
    unsigned short* __restrict__ haug) {
  __shared__ unsigned short As[128 * 64];
  __shared__ unsigned short Bs[256 * 64];
  __shared__ float red1[4][128];
  __shared__ float red2[4][128];
  const int lane = threadIdx.x & 63;
  const int wave = threadIdx.x >> 6;      // 0..7
  const int wm = wave >> 2, wn = wave & 3;
  int li = blockIdx.x + gridDim.x * blockIdx.y;
  int bx, by;
  remap_xcd(li, gridDim.x, gridDim.y, bx, by);
  const long rowBase = (long)by * 128;
  const unsigned short* Ap = A + rowBase * ADP;
  const unsigned short* Bp = Wexp + (size_t)bx * ADP * ADP;
  const int srow = lane >> 3;
  const int scol = ((lane & 7) ^ (srow & 7)) * 8;
  f32x4 acc[4][4] = {};

  for (int kt = 0; kt < ADP; kt += 64) {
    // stage A tile (128x64): 16 chunks, 2/wave
#pragma unroll
    for (int c = 0; c < 2; ++c) {
      int chunk = wave * 2 + c;
      __builtin_amdgcn_global_load_lds(
          (const __attribute__((address_space(1))) unsigned int*)(uintptr_t)(
              Ap + (size_t)(chunk * 8 + srow) * ADP + kt + scol),
          (__attribute__((address_space(3))) unsigned int*)(uintptr_t)(
              As + chunk * 512),
          16, 0, 0);
    }
    // stage B tile (256x64): 32 chunks, 4/wave
#pragma unroll
    for (int c = 0; c < 4; ++c) {
      int chunk = wave * 4 + c;
      __builtin_amdgcn_global_load_lds(
          (const __attribute__((address_space(1))) unsigned int*)(uintptr_t)(
              Bp + (size_t)(chunk * 8 + srow) * ADP + kt + scol),
          (__attribute__((address_space(3))) unsigned int*)(uintptr_t)(
              Bs + chunk * 512),
          16, 0, 0);
    }
    __syncthreads();
#pragma unroll
    for (int kk = 0; kk < 64; kk += 32) {
      const int kb = (kk >> 3) + (lane >> 4);
      const int sw = kb ^ (lane & 7);
      bf16x8 af[4], bfr[4];
#pragma unroll
      for (int mt = 0; mt < 4; ++mt) {
        int m = wm * 64 + mt * 16 + (lane & 15);
        af[mt] = *(const bf16x8*)&As[m * 64 + sw * 8];
      }
#pragma unroll
      for (int nt = 0; nt < 4; ++nt) {
        int n = wn * 64 + nt * 16 + (lane & 15);
        bfr[nt] = *(const bf16x8*)&Bs[n * 64 + sw * 8];
      }
#pragma unroll
      for (int mt = 0; mt < 4; ++mt)
#pragma unroll
        for (int nt = 0; nt < 4; ++nt)
          acc[mt][nt] = __builtin_amdgcn_mfma_f32_16x16x32_bf16(
              af[mt], bfr[nt], acc[mt][nt], 0, 0, 0);
    }
    __syncthreads();
  }

  // ---- in-block LayerNorm over the 256-wide rows (streamed reduction) ----
#pragma unroll
  for (int mt = 0; mt < 4; ++mt) {
#pragma unroll
    for (int r = 0; r < 4; ++r) {
      float s1 = 0.f, s2 = 0.f;
#pragma unroll
      for (int nt = 0; nt < 4; ++nt) {
        float v = acc[mt][nt][r];
        s1 += v; s2 += v * v;
      }
#pragma unroll
      for (int m = 1; m < 16; m <<= 1) {
        s1 += __shfl_xor(s1, m);
        s2 += __shfl_xor(s2, m);
      }
      if ((lane & 15) == 0) {
        int rl = wm * 64 + mt * 16 + (lane >> 4) * 4 + r;
        red1[wn][rl] = s1;
        red2[wn][rl] = s2;
      }
    }
  }
  __syncthreads();
  const int rsub = (lane >> 4) * 4;
  const int csub = lane & 15;
  float gv[4], bv[4];
#pragma unroll
  for (int nt = 0; nt < 4; ++nt) {
    int col = wn * 64 + nt * 16 + csub;
    gv[nt] = gamma[bx * ADP + col];
    bv[nt] = beta[bx * ADP + col];
  }
#pragma unroll
  for (int mt = 0; mt < 4; ++mt) {
#pragma unroll
    for (int r = 0; r < 4; ++r) {
      int rl = wm * 64 + mt * 16 + rsub + r;
      long row = rowBase + rl;
      if (route[row] != bx) continue;  // another block owns this token
      float t1 = red1[0][rl] + red1[1][rl] + red1[2][rl] + red1[3][rl];
      float t2 = red2[0][rl] + red2[1][rl] + red2[2][rl] + red2[3][rl];
      float mu = t1 * (1.0f / ADP);
      float var = t2 * (1.0f / ADP) - mu * mu;
      float rstd = rsqrtf(var + 1e-5f);
#pragma unroll
      for (int nt = 0; nt < 4; ++nt) {
        int col = wn * 64 + nt * 16 + csub;
        float val = (acc[mt][nt][r] - mu) * rstd * gv[nt] + bv[nt];
        haug[row * KAUG + HID + col] = f2bf(val);
      }
    }
  }
}

// ---------------------------------------------------------------------------
extern "C" void kernel_launch(void* const* d_in, const int* in_sizes, int n_in,
                              void* d_out, int out_size, void* d_ws, size_t ws_size,
                              hipStream_t stream) {
  const float* x     = (const float*)d_in[0];
  const float* ew    = (const float*)d_in[1];
  const float* W_up  = (const float*)d_in[2];
  const float* W_ad  = (const float*)d_in[3];
  const float* W_ex  = (const float*)d_in[4];
  const float* gam   = (const float*)d_in[5];
  const float* bet   = (const float*)d_in[6];
  const float* W_pr  = (const float*)d_in[7];
  const float* W_out = (const float*)d_in[8];
  float* out = (float*)d_out;

  // workspace layout (~150 MiB total)
  char* ws = (char*)d_ws;
  size_t off = 0;
  auto alloc = [&](size_t n) {
    char* p = ws + off;
    off += (n + 255) & ~(size_t)255;
    return p;
  };
  unsigned short* xb   = (unsigned short*)alloc((size_t)TOK * DEMB * 2);
  unsigned short* wub  = (unsigned short*)alloc((size_t)HID * DEMB * 2);
  unsigned short* wob  = (unsigned short*)alloc((size_t)DEMB * KAUG * 2);  // [Wout | Wcomb]
  unsigned short* wab  = (unsigned short*)alloc((size_t)ADP * HID * 2);
  unsigned short* web  = (unsigned short*)alloc((size_t)NEXP * ADP * ADP * 2);
  unsigned short* wpT  = (unsigned short*)alloc((size_t)ADP * HID * 2);    // Wproj^T bf16
  unsigned short* Haug = (unsigned short*)alloc((size_t)TOK * KAUG * 2);   // [H | anorm]
  float*          P    = (float*)alloc((size_t)4 * TOK * ADP * 4);
  float*          Pw   = (float*)alloc((size_t)8 * DEMB * ADP * 4);
  unsigned short* ab   = (unsigned short*)alloc((size_t)TOK * ADP * 2);
  int*          route  = (int*)alloc((size_t)TOK * 4);

  // 1) bf16 conversion of x + W_up + routing (only what step 2 needs)
  convert_a<<<6176, 256, 0, stream>>>(x, W_up, ew, xb, wub, route);
  // 2) fused: H = silu(x @ W_up^T) -> Haug head  +  remaining weight
  //    conversions (W_out/W_adapt/W_exp/W_proj^T) overlapped on spare CUs
  fused2<<<5120, 256, 0, stream>>>(xb, wub, Haug, W_out, W_ad, W_ex, W_pr,
                                   wob, wab, web, wpT);
  // 3) dual (BN=256, A streamed once): P = Haug @ wab^T (split-K=4, 256 blk)
  //    + Pw = wob @ wpT^T (split-K=8, 64 blk) in one 320-block launch
  gemm_n256<<<320, 512, 0, stream>>>(
      Haug, KAUG, wab, HID, P, HID / 4, (long)TOK * ADP, 256,
      wob, KAUG, wpT, HID, Pw, HID / 8, (long)DEMB * ADP);
  // 4) merged reductions: a partials -> bf16 ab; Wcomb partials -> wob tail
  reduce_both<<<2304, 256, 0, stream>>>(P, ab, Pw, wob);
  // 5) fused expert GEMM + LayerNorm -> bf16 anorm into Haug tail
  gemm_exp_ln<<<dim3(NEXP, TOK / 128), 512, 0, stream>>>(
      ab, web, route, gam, bet, Haug);
  // 6) out = H_aug @ [Wout | Wcomb]^T, K=4352  (gemm8h: 512 blocks, 2/CU,
  //    counted-vmcnt double-buffer + TLP; tail-race fixed)
  gemm8h<<<dim3(DEMB / 128, TOK / 128), 512, 0, stream>>>(
      Haug, KAUG, wob, KAUG, out, DEMB, KAUG);
}